// Round 5
// baseline (5879.147 us; speedup 1.0000x reference)
//
#include <hip/hip_runtime.h>
#include <stdint.h>

#define DEV __device__ __forceinline__

typedef uint16_t u16;
typedef __bf16 bf16x8 __attribute__((ext_vector_type(8)));
typedef float f32x4 __attribute__((ext_vector_type(4)));
typedef u16 u16x8 __attribute__((ext_vector_type(8)));

DEV float bf2f(u16 v) { return __uint_as_float(((uint32_t)v) << 16); }
DEV u16 f2bf(float f) {
  uint32_t u = __float_as_uint(f);
  u += 0x7fffu + ((u >> 16) & 1u);
  return (u16)(u >> 16);
}
DEV float gelu_f(float x) { return 0.5f * x * (1.0f + erff(x * 0.7071067811865475f)); }

// ---- all scratch in a static device global: independent of ws_size (R4 fix) ----
struct Scratch {
  float POSb[64 * 512];
  float meanv[1024];
  float stdv[1024];
  float mh[1024 * 192];
  int idxC[1024];
  float hmeanC[128 * 512];
  float gatelC[8192 * 2];
  float qflatC[128 * 512];
  u16 WqT[512 * 512];
  u16 WkT[512 * 512];
  u16 WvT[512 * 512];
  u16 WoT[512 * 512];
  u16 Wm1T[1024 * 512];
  u16 Wg1T[512 * 1024];
  u16 WhT[256 * 32768];          // rows 0..191 valid, 192..255 zero-filled
  u16 memdupB[8192 * 2048];      // [mh|mh|ml|ml] hi/lo split of mem_bank, 32 MB
  u16 embC[128 * 64 * 512];      // 8 MB per-chunk emb (bf16)
  u16 T0[4 * 1024 * 1024];       // 8 MB
  u16 T1[4 * 1024 * 1024];       // 8 MB
  u16 T2[4 * 1024 * 1024];       // 8 MB
};
__device__ Scratch g_s;

// ---------------- fills ----------------
__global__ __launch_bounds__(256) void zerof_kernel(float* __restrict__ p, int n) {
  int t = blockIdx.x * 256 + threadIdx.x;
  if (t < n) p[t] = 0.f;
}
__global__ __launch_bounds__(256) void zerou_kernel(u16* __restrict__ p, int n) {
  int t = blockIdx.x * 256 + threadIdx.x;
  if (t < n) p[t] = 0;
}

// ---------------- POS embedding ----------------
__global__ __launch_bounds__(256) void pos_kernel(float* __restrict__ POS) {
  int n = blockIdx.x;
  int i = threadIdx.x;
  float div = expf((float)(2 * i) * (-9.210340371976184f / 512.0f));
  float arg = (float)n * div;
  POS[n * 512 + 2 * i] = sinf(arg);
  POS[n * 512 + 2 * i + 1] = cosf(arg);
}

// ---------------- instance-norm stats (f32 input) ----------------
__global__ __launch_bounds__(256) void stats_kernel(const float* __restrict__ x_enc,
                                                    float* __restrict__ meanv,
                                                    float* __restrict__ stdv) {
  int b = blockIdx.x;
  int v = threadIdx.x & 63;
  int g = threadIdx.x >> 6;
  float s = 0.f, s2 = 0.f;
  for (int l = g; l < 512; l += 4) {
    float x = x_enc[((long)b * 512 + l) * 64 + v];
    s += x; s2 += x * x;
  }
  __shared__ float sh[2][4][64];
  sh[0][g][v] = s; sh[1][g][v] = s2;
  __syncthreads();
  if (g == 0) {
    s = sh[0][0][v] + sh[0][1][v] + sh[0][2][v] + sh[0][3][v];
    s2 = sh[1][0][v] + sh[1][1][v] + sh[1][2][v] + sh[1][3][v];
    float mu = s * (1.f / 512.f);
    float var = s2 * (1.f / 512.f) - mu * mu;
    meanv[b * 64 + v] = mu;
    stdv[b * 64 + v] = sqrtf(var + 1e-5f) * 2.5f;  // sqrt(var+eps)/0.4
  }
}

// ---------------- transpose f32 [R,C] -> bf16 [C,R] ----------------
__global__ __launch_bounds__(256) void transpose_kernel(const float* __restrict__ in,
                                                        u16* __restrict__ out, int R, int C) {
  __shared__ u16 t[32][33];
  int bx = blockIdx.x * 32;  // col
  int by = blockIdx.y * 32;  // row
  int tx = threadIdx.x & 31, ty = threadIdx.x >> 5;
  for (int i = ty; i < 32; i += 8) t[i][tx] = f2bf(in[(long)(by + i) * C + bx + tx]);
  __syncthreads();
  for (int i = ty; i < 32; i += 8) out[(long)(bx + i) * R + by + tx] = t[tx][i];
}

// ---------------- patch embed + qflat (chunk of 128 bn), f32 in, bf16 emb out ----
__global__ __launch_bounds__(256) void emb_kernel(const float* __restrict__ x_enc,
                                                  const float* __restrict__ W_val,
                                                  const float* __restrict__ POS,
                                                  const float* __restrict__ meanv,
                                                  const float* __restrict__ stdv,
                                                  u16* __restrict__ embC,
                                                  float* __restrict__ qflatC, int bn0) {
  int bnl = blockIdx.x;
  int bn = bn0 + bnl;
  int b = bn >> 6, v = bn & 63;
  int tid = threadIdx.x;
  __shared__ __align__(16) float wv[16 * 512];
  __shared__ __align__(16) float pt[64 * 16];
  for (int i = tid; i < 8192; i += 256) wv[i] = W_val[i];
  float mu = meanv[bn];
  float inv = 1.f / stdv[bn];
  for (int i = tid; i < 1024; i += 256) {
    int n = i >> 4, p = i & 15;
    int l = n * 8 + p; if (l > 511) l = 511;  // replication pad
    pt[i] = (x_enc[((long)b * 512 + l) * 64 + v] - mu) * inv;
  }
  __syncthreads();
  float qs0 = 0.f, qs1 = 0.f;
  int d0 = tid, d1 = tid + 256;
  for (int n = 0; n < 64; ++n) {
    float a0 = POS[n * 512 + d0], a1 = POS[n * 512 + d1];
#pragma unroll
    for (int p = 0; p < 16; ++p) {
      float pv = pt[n * 16 + p];
      a0 += pv * wv[p * 512 + d0];
      a1 += pv * wv[p * 512 + d1];
    }
    long base = ((long)bnl * 64 + n) * 512;
    embC[base + d0] = f2bf(a0);
    embC[base + d1] = f2bf(a1);
    qs0 += a0; qs1 += a1;
  }
  qflatC[(long)bnl * 512 + d0] = qs0 * (1.f / 64.f);
  qflatC[(long)bnl * 512 + d1] = qs1 * (1.f / 64.f);
}

// ---------------- qflat f32 -> [qh|ql|qh|ql] bf16 row of 2048 ----------------
__global__ __launch_bounds__(256) void qsplit_kernel(const float* __restrict__ qflatC,
                                                     u16* __restrict__ qsC) {
  int t = blockIdx.x * 256 + threadIdx.x;  // < 65536
  int bnl = t >> 9, d = t & 511;
  float q = qflatC[t];
  u16 hi = f2bf(q);
  u16 lo = f2bf(q - bf2f(hi));
  long base = (long)bnl * 2048;
  qsC[base + d] = hi;
  qsC[base + 512 + d] = lo;
  qsC[base + 1024 + d] = hi;
  qsC[base + 1536 + d] = lo;
}

// ---------------- mem_bank f32 -> [mh|mh|ml|ml] bf16 row of 2048 ----------------
__global__ __launch_bounds__(256) void memdup_kernel(const float* __restrict__ mb,
                                                     u16* __restrict__ md) {
  int t = blockIdx.x * 256 + threadIdx.x;  // < 4194304
  int n = t >> 9, k = t & 511;
  float m = mb[t];
  u16 hi = f2bf(m);
  u16 lo = f2bf(m - bf2f(hi));
  long base = (long)n * 2048;
  md[base + k] = hi;
  md[base + 512 + k] = hi;
  md[base + 1024 + k] = lo;
  md[base + 1536 + k] = lo;
}

// ---------------- generic NT MFMA GEMM (register-staged LDS) ----------------
// C[M,N] = A[M,K] * Bt[N,K]^T.
// EPI: 0 = bias+bf16, 1 = bias+gelu+bf16, 2 = f32 atomicAdd, 3 = f32 plain store
template <int EPI>
__global__ __launch_bounds__(256) void gemm_nt(const u16* __restrict__ Ag,
                                               const u16* __restrict__ Bt,
                                               const float* __restrict__ bias,
                                               void* __restrict__ C,
                                               int lda, int ldb, int K, int Nreal, int ldc) {
  __shared__ __align__(16) u16 As[128 * 32];
  __shared__ __align__(16) u16 Bs[128 * 32];
  const int tid = threadIdx.x;
  const long bm = (long)blockIdx.x * 128;
  const long bnn = (long)blockIdx.y * 128;
  const long koff = (long)blockIdx.z * K;
  const int lane = tid & 63;
  const int wid = tid >> 6;
  const int wm = (wid & 1) * 64;
  const int wn = (wid >> 1) * 64;
  const int r16 = lane & 15;
  const int q4 = lane >> 4;

  f32x4 acc[4][4] = {};

  const int row0 = tid >> 2;
  const int cg = (tid & 3) * 8;
  const int row1 = row0 + 64;
  const u16* a0 = Ag + (bm + row0) * lda + koff + cg;
  const u16* a1 = Ag + (bm + row1) * lda + koff + cg;
  const u16* b0 = Bt + (bnn + row0) * ldb + koff + cg;
  const u16* b1 = Bt + (bnn + row1) * ldb + koff + cg;

  for (int k0 = 0; k0 < K; k0 += 32) {
    u16x8 ra0 = *(const u16x8*)(a0 + k0);
    u16x8 ra1 = *(const u16x8*)(a1 + k0);
    u16x8 rb0 = *(const u16x8*)(b0 + k0);
    u16x8 rb1 = *(const u16x8*)(b1 + k0);
    __syncthreads();
    *(u16x8*)(As + tid * 8) = ra0;
    *(u16x8*)(As + (tid + 256) * 8) = ra1;
    *(u16x8*)(Bs + tid * 8) = rb0;
    *(u16x8*)(Bs + (tid + 256) * 8) = rb1;
    __syncthreads();
    bf16x8 av[4], bv[4];
#pragma unroll
    for (int i = 0; i < 4; ++i)
      av[i] = *reinterpret_cast<const bf16x8*>(As + (wm + i * 16 + r16) * 32 + q4 * 8);
#pragma unroll
    for (int j = 0; j < 4; ++j)
      bv[j] = *reinterpret_cast<const bf16x8*>(Bs + (wn + j * 16 + r16) * 32 + q4 * 8);
#pragma unroll
    for (int i = 0; i < 4; ++i)
#pragma unroll
      for (int j = 0; j < 4; ++j)
        acc[i][j] = __builtin_amdgcn_mfma_f32_16x16x32_bf16(av[i], bv[j], acc[i][j], 0, 0, 0);
  }

#pragma unroll
  for (int i = 0; i < 4; ++i)
#pragma unroll
    for (int j = 0; j < 4; ++j)
#pragma unroll
      for (int r = 0; r < 4; ++r) {
        long grow = bm + wm + i * 16 + q4 * 4 + r;
        int gcol = (int)bnn + wn + j * 16 + r16;
        float v = acc[i][j][r];
        if (gcol < Nreal) {
          if (EPI == 0 || EPI == 1) {
            v += bias[gcol];
            if (EPI == 1) v = gelu_f(v);
            ((u16*)C)[grow * ldc + gcol] = f2bf(v);
          } else if (EPI == 2) {
            atomicAdd((float*)C + grow * ldc + gcol, v);
          } else {
            ((float*)C)[grow * ldc + gcol] = v;
          }
        }
      }
}

// ---------------- top-8 per row of simC [128, 8192] ----------------
__global__ __launch_bounds__(256) void topk_kernel(const float* __restrict__ sim,
                                                   int* __restrict__ idxout) {
  const int bn = blockIdx.x;
  const int tid = threadIdx.x;
  const float* row = sim + (long)bn * 8192;
  float bv[8]; int bi[8];
#pragma unroll
  for (int r = 0; r < 8; ++r) { bv[r] = -3.0e38f; bi[r] = 0x7fffffff; }
  for (int n = tid; n < 8192; n += 256) {
    float v = row[n];
    if (v > bv[7] || (v == bv[7] && n < bi[7])) {
      bv[7] = v; bi[7] = n;
      for (int r = 7; r > 0; --r) {
        bool sw = (bv[r] > bv[r - 1]) || (bv[r] == bv[r - 1] && bi[r] < bi[r - 1]);
        if (!sw) break;
        float tv = bv[r]; bv[r] = bv[r - 1]; bv[r - 1] = tv;
        int ti = bi[r]; bi[r] = bi[r - 1]; bi[r - 1] = ti;
      }
    }
  }
  __shared__ float lv[2048];
  __shared__ int li[2048];
#pragma unroll
  for (int r = 0; r < 8; ++r) { lv[tid * 8 + r] = bv[r]; li[tid * 8 + r] = bi[r]; }
  __syncthreads();
  if (tid == 0) {
#pragma unroll
    for (int r = 0; r < 8; ++r) { bv[r] = -3.0e38f; bi[r] = 0x7fffffff; }
    for (int c = 0; c < 2048; ++c) {
      float v = lv[c]; int n = li[c];
      if (v > bv[7] || (v == bv[7] && n < bi[7])) {
        bv[7] = v; bi[7] = n;
        for (int r = 7; r > 0; --r) {
          bool sw = (bv[r] > bv[r - 1]) || (bv[r] == bv[r - 1] && bi[r] < bi[r - 1]);
          if (!sw) break;
          float tv = bv[r]; bv[r] = bv[r - 1]; bv[r - 1] = tv;
          int ti = bi[r]; bi[r] = bi[r - 1]; bi[r - 1] = ti;
        }
      }
    }
#pragma unroll
    for (int r = 0; r < 8; ++r) idxout[bn * 8 + r] = bi[r];
  }
}

// ---------------- gather retrieved rows, f32 -> bf16, clamped ----------------
__global__ __launch_bounds__(256) void gather_kernel(const float* __restrict__ mb,
                                                     const int* __restrict__ idx,
                                                     u16* __restrict__ retrC) {
  int t = blockIdx.x * 256 + threadIdx.x;  // < 65536
  int m = t >> 6;
  int c8 = (t & 63) * 8;
  long r = idx[m];
  if (r < 0) r = 0;
  if (r > 8191) r = 8191;
  const float* src = mb + r * 512 + c8;
  u16* dst = retrC + (long)m * 512 + c8;
#pragma unroll
  for (int z = 0; z < 8; ++z) dst[z] = f2bf(src[z]);
}

// ---------------- mean over K of gelu-hidden (chunk) ----------------
__global__ __launch_bounds__(256) void gmean_kernel(const u16* __restrict__ hid,
                                                    float* __restrict__ gmeanC) {
  int t = blockIdx.x * 256 + threadIdx.x;  // < 131072
  int bnl = t >> 10, j = t & 1023;
  float s = 0.f;
#pragma unroll
  for (int k = 0; k < 8; ++k) s += bf2f(hid[(long)(bnl * 8 + k) * 1024 + j]);
  gmeanC[t] = s * 0.125f;
}

// ---------------- NN GEMM f32 A, f32 B: hmeanC = gmeanC @ W_m2 + b_m2 ----------------
__global__ __launch_bounds__(256) void gemm_nn_f32(const float* __restrict__ Ag,
                                                   const float* __restrict__ Bg,
                                                   const float* __restrict__ bias,
                                                   float* __restrict__ C, int N, int K) {
  __shared__ float As[64][17];
  __shared__ float Bs[16][65];
  int bx = blockIdx.x * 64;
  int by = blockIdx.y * 64;
  int tid = threadIdx.x;
  int tx = tid & 15, ty = tid >> 4;
  float acc[4][4] = {};
  for (int k0 = 0; k0 < K; k0 += 16) {
    for (int i = tid; i < 1024; i += 256) {
      int r = i >> 4, kk = i & 15;
      As[r][kk] = Ag[(long)(by + r) * K + k0 + kk];
    }
    for (int i = tid; i < 1024; i += 256) {
      int kr = i >> 6, n = i & 63;
      Bs[kr][n] = Bg[(long)(k0 + kr) * N + bx + n];
    }
    __syncthreads();
    for (int kk = 0; kk < 16; ++kk) {
      float a[4], b[4];
#pragma unroll
      for (int r = 0; r < 4; ++r) a[r] = As[ty * 4 + r][kk];
#pragma unroll
      for (int c = 0; c < 4; ++c) b[c] = Bs[kk][tx * 4 + c];
#pragma unroll
      for (int r = 0; r < 4; ++r)
#pragma unroll
        for (int c = 0; c < 4; ++c) acc[r][c] += a[r] * b[c];
    }
    __syncthreads();
  }
#pragma unroll
  for (int r = 0; r < 4; ++r)
#pragma unroll
    for (int c = 0; c < 4; ++c) {
      int gm = by + ty * 4 + r, gn = bx + tx * 4 + c;
      C[(long)gm * N + gn] = acc[r][c] + bias[gn];
    }
}

// ---------------- attention: one block per (bnLocal, head); atto over q ----------------
__global__ __launch_bounds__(256) void attn_kernel(u16* __restrict__ qb,
                                                   const u16* __restrict__ kb,
                                                   const u16* __restrict__ vb) {
  const int bn = blockIdx.x;
  const int h = blockIdx.y;
  const int tid = threadIdx.x;
  __shared__ __align__(16) u16 qs[64 * 130];
  __shared__ __align__(16) u16 ks[64 * 130];
  __shared__ float ss[64 * 64];
  const long base = (long)bn * 64 * 512 + h * 128;
  for (int c = tid; c < 1024; c += 256) {
    int r = c >> 4, c8 = (c & 15) * 8;
    u16x8 vq = *(const u16x8*)(qb + base + (long)r * 512 + c8);
    u16x8 vk = *(const u16x8*)(kb + base + (long)r * 512 + c8);
#pragma unroll
    for (int z = 0; z < 8; ++z) {
      qs[r * 130 + c8 + z] = vq[z];
      ks[r * 130 + c8 + z] = vk[z];
    }
  }
  __syncthreads();
  const float scale = 0.08838834764831845f;  // 1/sqrt(128)
  for (int e = tid; e < 4096; e += 256) {
    int i = e >> 6, j = e & 63;
    const u16* qr = qs + i * 130;
    const u16* kr = ks + j * 130;
    float a = 0.f;
#pragma unroll 8
    for (int d = 0; d < 128; ++d) a += bf2f(qr[d]) * bf2f(kr[d]);
    ss[i * 64 + j] = a * scale;
  }
  __syncthreads();
  for (int c = tid; c < 1024; c += 256) {
    int r = c >> 4, c8 = (c & 15) * 8;
    u16x8 vv = *(const u16x8*)(vb + base + (long)r * 512 + c8);
#pragma unroll
    for (int z = 0; z < 8; ++z) qs[r * 130 + c8 + z] = vv[z];
  }
  if (tid < 64) {
    float* row = ss + tid * 64;
    float mx = row[0];
    for (int j = 1; j < 64; ++j) mx = fmaxf(mx, row[j]);
    float s = 0.f;
    for (int j = 0; j < 64; ++j) { float e = expf(row[j] - mx); row[j] = e; s += e; }
    float inv = 1.f / s;
    for (int j = 0; j < 64; ++j) row[j] *= inv;
  }
  __syncthreads();
  for (int e = tid; e < 8192; e += 256) {
    int i = e >> 7, d = e & 127;
    float a = 0.f;
#pragma unroll 8
    for (int j = 0; j < 64; ++j) a += ss[i * 64 + j] * bf2f(qs[j * 130 + d]);
    qb[base + (long)i * 512 + d] = f2bf(a);
  }
}

// ---------------- local = emb + hmeanC (in-place over emb chunk) ----------------
__global__ __launch_bounds__(256) void local_kernel(u16* __restrict__ embC,
                                                    const float* __restrict__ hmeanC) {
  long t = (long)blockIdx.x * 256 + threadIdx.x;  // < 4194304
  long m = t >> 9;
  int d = (int)(t & 511);
  int bnl = (int)(m >> 6);
  embC[t] = f2bf(hmeanC[(long)bnl * 512 + d] + bf2f(embC[t]));
}

// ---------------- concat-K NT GEMM: C = gelu([A1|A2] @ Wg1T^T + bias) ----------------
__global__ __launch_bounds__(256) void gemm_cat(const u16* __restrict__ A1,
                                                const u16* __restrict__ A2,
                                                const u16* __restrict__ Bt,
                                                const float* __restrict__ bias,
                                                u16* __restrict__ C) {
  __shared__ __align__(16) u16 As[128 * 32];
  __shared__ __align__(16) u16 Bs[128 * 32];
  const int tid = threadIdx.x;
  const long bm = (long)blockIdx.x * 128;
  const long bnn = (long)blockIdx.y * 128;
  const int lane = tid & 63;
  const int wid = tid >> 6;
  const int wm = (wid & 1) * 64;
  const int wn = (wid >> 1) * 64;
  const int r16 = lane & 15;
  const int q4 = lane >> 4;

  f32x4 acc[4][4] = {};

  const int row0 = tid >> 2;
  const int cg = (tid & 3) * 8;
  const int row1 = row0 + 64;
  const u16* a10 = A1 + (bm + row0) * 512 + cg;
  const u16* a11 = A1 + (bm + row1) * 512 + cg;
  const u16* a20 = A2 + (bm + row0) * 512 + cg;
  const u16* a21 = A2 + (bm + row1) * 512 + cg;
  const u16* b0 = Bt + (bnn + row0) * 1024 + cg;
  const u16* b1 = Bt + (bnn + row1) * 1024 + cg;

  for (int k0 = 0; k0 < 1024; k0 += 32) {
    u16x8 ra0, ra1;
    if (k0 < 512) {
      ra0 = *(const u16x8*)(a10 + k0);
      ra1 = *(const u16x8*)(a11 + k0);
    } else {
      ra0 = *(const u16x8*)(a20 + (k0 - 512));
      ra1 = *(const u16x8*)(a21 + (k0 - 512));
    }
    u16x8 rb0 = *(const u16x8*)(b0 + k0);
    u16x8 rb1 = *(const u16x8*)(b1 + k0);
    __syncthreads();
    *(u16x8*)(As + tid * 8) = ra0;
    *(u16x8*)(As + (tid + 256) * 8) = ra1;
    *(u16x8*)(Bs + tid * 8) = rb0;
    *(u16x8*)(Bs + (tid + 256) * 8) = rb1;
    __syncthreads();
    bf16x8 av[4], bv[4];
#pragma unroll
    for (int i = 0; i < 4; ++i)
      av[i] = *reinterpret_cast<const bf16x8*>(As + (wm + i * 16 + r16) * 32 + q4 * 8);
#pragma unroll
    for (int j = 0; j < 4; ++j)
      bv[j] = *reinterpret_cast<const bf16x8*>(Bs + (wn + j * 16 + r16) * 32 + q4 * 8);
#pragma unroll
    for (int i = 0; i < 4; ++i)
#pragma unroll
      for (int j = 0; j < 4; ++j)
        acc[i][j] = __builtin_amdgcn_mfma_f32_16x16x32_bf16(av[i], bv[j], acc[i][j], 0, 0, 0);
  }

#pragma unroll
  for (int i = 0; i < 4; ++i)
#pragma unroll
    for (int j = 0; j < 4; ++j)
#pragma unroll
      for (int r = 0; r < 4; ++r) {
        long grow = bm + wm + i * 16 + q4 * 4 + r;
        int gcol = (int)bnn + wn + j * 16 + r16;
        float v = acc[i][j][r] + bias[gcol];
        C[grow * 512 + gcol] = f2bf(gelu_f(v));
      }
}

// ---------------- gate logits + softmax(2) (chunk), f32 W_g2 ----------------
__global__ __launch_bounds__(256) void g2_kernel(const u16* __restrict__ h1b,
                                                 const float* __restrict__ W_g2,
                                                 const float* __restrict__ b_g2,
                                                 float* __restrict__ gatelC) {
  int m = blockIdx.x * 4 + (threadIdx.x >> 6);
  int lane = threadIdx.x & 63;
  const u16* row = h1b + (long)m * 512;
  float a0 = 0.f, a1 = 0.f;
  for (int i = lane; i < 512; i += 64) {
    float h = bf2f(row[i]);
    a0 += h * W_g2[i * 2];
    a1 += h * W_g2[i * 2 + 1];
  }
  for (int off = 32; off; off >>= 1) {
    a0 += __shfl_down(a0, off);
    a1 += __shfl_down(a1, off);
  }
  if (lane == 0) {
    a0 += b_g2[0];
    a1 += b_g2[1];
    float mx = fmaxf(a0, a1);
    float e0 = expf(a0 - mx), e1 = expf(a1 - mx);
    float inv = 1.f / (e0 + e1);
    gatelC[(long)m * 2] = e0 * inv;
    gatelC[(long)m * 2 + 1] = e1 * inv;
  }
}

// ---------------- mem = g0*local + g1*glob (chunk) ----------------
__global__ __launch_bounds__(256) void memc_kernel(const u16* __restrict__ localC,
                                                   const u16* __restrict__ globC,
                                                   const float* __restrict__ gatelC,
                                                   u16* __restrict__ memC) {
  long t = (long)blockIdx.x * 256 + threadIdx.x;  // < 4194304
  long m = t >> 9;
  float loc = bf2f(localC[t]);
  float gl = bf2f(globC[t]);
  float g0 = gatelC[m * 2], g1 = gatelC[m * 2 + 1];
  memC[t] = f2bf(g0 * loc + g1 * gl);
}

// ---------------- fusion head + denorm + transpose store (all f32) ----------------
__global__ __launch_bounds__(256) void fusion_kernel(const float* __restrict__ mh,
                                                     const float* __restrict__ b_h,
                                                     const float* __restrict__ W_f1,
                                                     const float* __restrict__ b_f1,
                                                     const float* __restrict__ W_f2,
                                                     const float* __restrict__ b_f2,
                                                     const float* __restrict__ meanv,
                                                     const float* __restrict__ stdv,
                                                     float* __restrict__ out) {
  int bn = blockIdx.x;
  int tid = threadIdx.x;
  __shared__ float mrow[192];
  __shared__ float h1[384];
  if (tid < 192) mrow[tid] = mh[(long)bn * 192 + tid] + b_h[tid];
  __syncthreads();
  for (int j = tid; j < 384; j += 256) {
    float a = b_f1[j];
    for (int i = 0; i < 192; ++i) a += mrow[i] * W_f1[i * 384 + j];
    h1[j] = gelu_f(a);
  }
  __syncthreads();
  if (tid < 192) {
    float a = b_f2[tid];
    for (int j = 0; j < 384; ++j) a += h1[j] * W_f2[j * 192 + tid];
    float o = gelu_f(a) + mrow[tid];
    int b = bn >> 6, v = bn & 63;
    out[((long)b * 192 + tid) * 64 + v] = o * stdv[bn] + meanv[bn];
  }
}

extern "C" void kernel_launch(void* const* d_in, const int* in_sizes, int n_in,
                              void* d_out, int out_size, void* d_ws, size_t ws_size,
                              hipStream_t stream) {
  (void)in_sizes; (void)n_in; (void)out_size; (void)d_ws; (void)ws_size;
  // ALL inputs are float32 per the reference (R4 finding)
  const float* x_enc = (const float*)d_in[0];
  const float* W_val = (const float*)d_in[1];
  const float* mem_bank = (const float*)d_in[2];
  const float* W_m1 = (const float*)d_in[3];
  const float* b_m1 = (const float*)d_in[4];
  const float* W_m2 = (const float*)d_in[5];
  const float* b_m2 = (const float*)d_in[6];
  const float* W_q = (const float*)d_in[7];
  const float* b_q = (const float*)d_in[8];
  const float* W_k = (const float*)d_in[9];
  const float* b_k = (const float*)d_in[10];
  const float* W_v = (const float*)d_in[11];
  const float* b_v = (const float*)d_in[12];
  const float* W_o = (const float*)d_in[13];
  const float* b_o = (const float*)d_in[14];
  const float* W_g1 = (const float*)d_in[15];
  const float* b_g1 = (const float*)d_in[16];
  const float* W_g2 = (const float*)d_in[17];
  const float* b_g2 = (const float*)d_in[18];
  const float* W_h = (const float*)d_in[19];
  const float* b_h = (const float*)d_in[20];
  const float* W_f1 = (const float*)d_in[21];
  const float* b_f1 = (const float*)d_in[22];
  const float* W_f2 = (const float*)d_in[23];
  const float* b_f2 = (const float*)d_in[24];

  void* sp = nullptr;
  hipGetSymbolAddress(&sp, HIP_SYMBOL(g_s));
  Scratch* S = (Scratch*)sp;
  // sim-phase views of T regions
  u16* qsC = S->T0;               // 512 KB  [128 x 2048]
  float* simC = (float*)S->T1;    // 4 MB    [128 x 8192]
  u16* retrC = S->T2;             // 1 MB
  u16* hiddenC = S->T0;           // 2 MB (qsC dead)
  float* gmeanC = (float*)S->T1;  // 512 KB (simC dead)
  // qkv-phase views
  u16* qc = S->T0;
  u16* kc = S->T1;
  u16* vc = S->T2;

  pos_kernel<<<64, 256, 0, stream>>>(S->POSb);
  stats_kernel<<<16, 256, 0, stream>>>(x_enc, S->meanv, S->stdv);
  zerof_kernel<<<768, 256, 0, stream>>>(S->mh, 1024 * 192);
  // zero WhT pad rows (192..255) — read by the W_h GEMM's B tile
  zerou_kernel<<<8192, 256, 0, stream>>>(S->WhT + (size_t)192 * 32768, 64 * 32768);
  transpose_kernel<<<dim3(16, 16), 256, 0, stream>>>(W_q, S->WqT, 512, 512);
  transpose_kernel<<<dim3(16, 16), 256, 0, stream>>>(W_k, S->WkT, 512, 512);
  transpose_kernel<<<dim3(16, 16), 256, 0, stream>>>(W_v, S->WvT, 512, 512);
  transpose_kernel<<<dim3(16, 16), 256, 0, stream>>>(W_o, S->WoT, 512, 512);
  transpose_kernel<<<dim3(32, 16), 256, 0, stream>>>(W_m1, S->Wm1T, 512, 1024);
  transpose_kernel<<<dim3(16, 32), 256, 0, stream>>>(W_g1, S->Wg1T, 1024, 512);
  transpose_kernel<<<dim3(6, 1024), 256, 0, stream>>>(W_h, S->WhT, 32768, 192);
  memdup_kernel<<<16384, 256, 0, stream>>>(mem_bank, S->memdupB);

  for (int c = 0; c < 8; ++c) {
    int bn0 = c * 128;
    emb_kernel<<<128, 256, 0, stream>>>(x_enc, W_val, S->POSb, S->meanv, S->stdv,
                                        S->embC, S->qflatC, bn0);
    // retrieval: hi/lo split sim (fp32-exact products) -> topk -> gather -> MLP
    qsplit_kernel<<<256, 256, 0, stream>>>(S->qflatC, qsC);
    gemm_nt<3><<<dim3(1, 64), 256, 0, stream>>>(qsC, S->memdupB, nullptr, simC,
                                                2048, 2048, 2048, 8192, 8192);
    topk_kernel<<<128, 256, 0, stream>>>(simC, S->idxC);
    gather_kernel<<<256, 256, 0, stream>>>(mem_bank, S->idxC, retrC);
    gemm_nt<1><<<dim3(8, 8), 256, 0, stream>>>(retrC, S->Wm1T, b_m1, hiddenC,
                                               512, 512, 512, 1024, 1024);
    gmean_kernel<<<512, 256, 0, stream>>>(hiddenC, gmeanC);
    gemm_nn_f32<<<dim3(8, 2), 256, 0, stream>>>(gmeanC, W_m2, b_m2, S->hmeanC, 512, 1024);
    // QKV projections (M = 8192)
    gemm_nt<0><<<dim3(64, 4), 256, 0, stream>>>(S->embC, S->WqT, b_q, qc, 512, 512, 512, 512, 512);
    gemm_nt<0><<<dim3(64, 4), 256, 0, stream>>>(S->embC, S->WkT, b_k, kc, 512, 512, 512, 512, 512);
    gemm_nt<0><<<dim3(64, 4), 256, 0, stream>>>(S->embC, S->WvT, b_v, vc, 512, 512, 512, 512, 512);
    // local = emb + hmean (in place; QKV already consumed emb)
    local_kernel<<<16384, 256, 0, stream>>>(S->embC, S->hmeanC);
    // attention (atto over qc)
    attn_kernel<<<dim3(128, 4), 256, 0, stream>>>(qc, kc, vc);
    // glob = atto @ W_o + b_o -> kc
    gemm_nt<0><<<dim3(64, 4), 256, 0, stream>>>(qc, S->WoT, b_o, kc, 512, 512, 512, 512, 512);
    // h1 = gelu([local|glob] @ W_g1 + b_g1) -> vc
    gemm_cat<<<dim3(64, 4), 256, 0, stream>>>(S->embC, kc, S->Wg1T, b_g1, vc);
    g2_kernel<<<2048, 256, 0, stream>>>(vc, W_g2, b_g2, S->gatelC);
    // mem = g0*local + g1*glob -> qc
    memc_kernel<<<16384, 256, 0, stream>>>(S->embC, kc, S->gatelC, qc);
    // mh rows: [128, 32768] @ WhT^T, split-K x64, f32 atomics
    gemm_nt<2><<<dim3(1, 2, 64), 256, 0, stream>>>(qc, S->WhT, nullptr,
                                                   S->mh + (size_t)bn0 * 192,
                                                   32768, 32768, 512, 192, 192);
  }
  fusion_kernel<<<1024, 256, 0, stream>>>(S->mh, b_h, W_f1, b_f1, W_f2, b_f2,
                                          S->meanv, S->stdv, (float*)d_out);
}

// Round 6
// 1527.333 us; speedup vs baseline: 3.8493x; 3.8493x over previous
//
#include <hip/hip_runtime.h>
#include <stdint.h>

#define DEV __device__ __forceinline__

typedef uint16_t u16;
typedef __bf16 bf16x8 __attribute__((ext_vector_type(8)));
typedef float f32x4 __attribute__((ext_vector_type(4)));
typedef u16 u16x8 __attribute__((ext_vector_type(8)));
typedef u16 u16x4 __attribute__((ext_vector_type(4)));

DEV float bf2f(u16 v) { return __uint_as_float(((uint32_t)v) << 16); }
DEV u16 f2bf(float f) {
  uint32_t u = __float_as_uint(f);
  u += 0x7fffu + ((u >> 16) & 1u);
  return (u16)(u >> 16);
}
DEV float gelu_f(float x) { return 0.5f * x * (1.0f + erff(x * 0.7071067811865475f)); }

DEV void gload_lds16(const u16* g, u16* l) {
  __builtin_amdgcn_global_load_lds(
      (const __attribute__((address_space(1))) void*)g,
      (__attribute__((address_space(3))) void*)l, 16, 0, 0);
}

// ---- all scratch in a static device global (R4: never trust ws_size) ----
struct __align__(16) Scratch {
  float POSb[64 * 512];
  float meanv[1024];
  float stdv[1024];
  float mh[1024 * 192];
  int idxB[8192];
  float qflat[1024 * 512];
  float gatel[65536 * 2];
  u16 hmeanB[1024 * 512];
  u16 gmeanB[1024 * 1024];
  u16 WqT[512 * 512];
  u16 WkT[512 * 512];
  u16 WvT[512 * 512];
  u16 WoT[512 * 512];
  u16 Wm1T[1024 * 512];
  u16 Wm2T[512 * 1024];
  u16 Wg1T[512 * 1024];
  u16 WhT[256 * 32768];        // rows 192..255 zero-filled
  u16 memdupB[8192 * 2048];    // [mh|mh|ml|ml] 32 MB
  u16 embh[65536 * 512];       // 64 MB (becomes `local` in place)
  u16 qb[65536 * 512];         // 64 MB (sim phase: simB f32 alias)
  u16 kb[65536 * 512];         // 64 MB (sim phase: retrB + hiddenB alias)
  u16 vb[65536 * 512];         // 64 MB (sim phase: qsC alias)
};
__device__ Scratch g_s;  // ~253 MB

// ---------------- fills ----------------
__global__ __launch_bounds__(256) void zerof_kernel(float* __restrict__ p, int n) {
  int t = blockIdx.x * 256 + threadIdx.x;
  if (t < n) p[t] = 0.f;
}
__global__ __launch_bounds__(256) void zerou_kernel(u16* __restrict__ p, int n) {
  int t = blockIdx.x * 256 + threadIdx.x;
  if (t < n) p[t] = 0;
}

// ---------------- POS embedding ----------------
__global__ __launch_bounds__(256) void pos_kernel(float* __restrict__ POS) {
  int n = blockIdx.x;
  int i = threadIdx.x;
  float div = expf((float)(2 * i) * (-9.210340371976184f / 512.0f));
  float arg = (float)n * div;
  POS[n * 512 + 2 * i] = sinf(arg);
  POS[n * 512 + 2 * i + 1] = cosf(arg);
}

// ---------------- instance-norm stats ----------------
__global__ __launch_bounds__(256) void stats_kernel(const float* __restrict__ x_enc,
                                                    float* __restrict__ meanv,
                                                    float* __restrict__ stdv) {
  int b = blockIdx.x;
  int v = threadIdx.x & 63;
  int g = threadIdx.x >> 6;
  float s = 0.f, s2 = 0.f;
  for (int l = g; l < 512; l += 4) {
    float x = x_enc[((long)b * 512 + l) * 64 + v];
    s += x; s2 += x * x;
  }
  __shared__ float sh[2][4][64];
  sh[0][g][v] = s; sh[1][g][v] = s2;
  __syncthreads();
  if (g == 0) {
    s = sh[0][0][v] + sh[0][1][v] + sh[0][2][v] + sh[0][3][v];
    s2 = sh[1][0][v] + sh[1][1][v] + sh[1][2][v] + sh[1][3][v];
    float mu = s * (1.f / 512.f);
    float var = s2 * (1.f / 512.f) - mu * mu;
    meanv[b * 64 + v] = mu;
    stdv[b * 64 + v] = sqrtf(var + 1e-5f) * 2.5f;  // sqrt(var+eps)/0.4
  }
}

// ---------------- transpose f32 [R,C] -> bf16 [C,R] ----------------
__global__ __launch_bounds__(256) void transpose_kernel(const float* __restrict__ in,
                                                        u16* __restrict__ out, int R, int C) {
  __shared__ u16 t[32][33];
  int bx = blockIdx.x * 32;
  int by = blockIdx.y * 32;
  int tx = threadIdx.x & 31, ty = threadIdx.x >> 5;
  for (int i = ty; i < 32; i += 8) t[i][tx] = f2bf(in[(long)(by + i) * C + bx + tx]);
  __syncthreads();
  for (int i = ty; i < 32; i += 8) out[(long)(bx + i) * R + by + tx] = t[tx][i];
}

// ---------------- patch embed + qflat (full: 1024 blocks) ----------------
__global__ __launch_bounds__(256) void emb_kernel(const float* __restrict__ x_enc,
                                                  const float* __restrict__ W_val,
                                                  const float* __restrict__ POS,
                                                  const float* __restrict__ meanv,
                                                  const float* __restrict__ stdv,
                                                  u16* __restrict__ embh,
                                                  float* __restrict__ qflat) {
  int bn = blockIdx.x;
  int b = bn >> 6, v = bn & 63;
  int tid = threadIdx.x;
  __shared__ __align__(16) float wv[16 * 512];
  __shared__ __align__(16) float pt[64 * 16];
  for (int i = tid; i < 8192; i += 256) wv[i] = W_val[i];
  float mu = meanv[bn];
  float inv = 1.f / stdv[bn];
  for (int i = tid; i < 1024; i += 256) {
    int n = i >> 4, p = i & 15;
    int l = n * 8 + p; if (l > 511) l = 511;  // replication pad
    pt[i] = (x_enc[((long)b * 512 + l) * 64 + v] - mu) * inv;
  }
  __syncthreads();
  float qs0 = 0.f, qs1 = 0.f;
  int d0 = tid, d1 = tid + 256;
  for (int n = 0; n < 64; ++n) {
    float a0 = POS[n * 512 + d0], a1 = POS[n * 512 + d1];
#pragma unroll
    for (int p = 0; p < 16; ++p) {
      float pv = pt[n * 16 + p];
      a0 += pv * wv[p * 512 + d0];
      a1 += pv * wv[p * 512 + d1];
    }
    long base = ((long)bn * 64 + n) * 512;
    embh[base + d0] = f2bf(a0);
    embh[base + d1] = f2bf(a1);
    qs0 += a0; qs1 += a1;
  }
  qflat[(long)bn * 512 + d0] = qs0 * (1.f / 64.f);
  qflat[(long)bn * 512 + d1] = qs1 * (1.f / 64.f);
}

// ---------------- qflat f32 -> [qh|ql|qh|ql] bf16 row of 2048 ----------------
__global__ __launch_bounds__(256) void qsplit_kernel(const float* __restrict__ qflat,
                                                     u16* __restrict__ qsC) {
  int t = blockIdx.x * 256 + threadIdx.x;  // < 524288
  int bn = t >> 9, d = t & 511;
  float q = qflat[t];
  u16 hi = f2bf(q);
  u16 lo = f2bf(q - bf2f(hi));
  long base = (long)bn * 2048;
  qsC[base + d] = hi;
  qsC[base + 512 + d] = lo;
  qsC[base + 1024 + d] = hi;
  qsC[base + 1536 + d] = lo;
}

// ---------------- mem_bank f32 -> [mh|mh|ml|ml] bf16 row of 2048 ----------------
__global__ __launch_bounds__(256) void memdup_kernel(const float* __restrict__ mb,
                                                     u16* __restrict__ md) {
  int t = blockIdx.x * 256 + threadIdx.x;  // < 4194304
  int n = t >> 9, k = t & 511;
  float m = mb[t];
  u16 hi = f2bf(m);
  u16 lo = f2bf(m - bf2f(hi));
  long base = (long)n * 2048;
  md[base + k] = hi;
  md[base + 512 + k] = hi;
  md[base + 1024 + k] = lo;
  md[base + 1536 + k] = lo;
}

// ---------------- NT MFMA GEMM, m97-style global_load_lds staging ----------------
// C[M,N] = A[M,K] * Bt[N,K]^T.
// EPI: 0 bias+bf16 | 1 bias+gelu+bf16 | 2 f32 atomicAdd | 3 f32 store
template <int EPI>
__global__ __launch_bounds__(256) void gemm_nt(const u16* __restrict__ Ag,
                                               const u16* __restrict__ Bt,
                                               const float* __restrict__ bias,
                                               void* __restrict__ C,
                                               int lda, int ldb, int K, int Nreal, int ldc) {
  __shared__ __align__(16) u16 As[128 * 32];
  __shared__ __align__(16) u16 Bs[128 * 32];
  const int tid = threadIdx.x;
  const long bm = (long)blockIdx.x * 128;
  const long bnn = (long)blockIdx.y * 128;
  const long koff = (long)blockIdx.z * K;
  const int lane = tid & 63;
  const int wid = tid >> 6;
  const int wm = (wid & 1) * 64;
  const int wn = (wid >> 1) * 64;
  const int r16 = lane & 15;
  const int q4 = lane >> 4;

  f32x4 acc[4][4] = {};

  const int row0 = tid >> 2;
  const int cg = (tid & 3) * 8;
  const int row1 = row0 + 64;
  const u16* a0 = Ag + (bm + row0) * lda + koff + cg;
  const u16* a1 = Ag + (bm + row1) * lda + koff + cg;
  const u16* b0 = Bt + (bnn + row0) * ldb + koff + cg;
  const u16* b1 = Bt + (bnn + row1) * ldb + koff + cg;

  for (int k0 = 0; k0 < K; k0 += 32) {
    gload_lds16(a0 + k0, As + tid * 8);
    gload_lds16(a1 + k0, As + (tid + 256) * 8);
    gload_lds16(b0 + k0, Bs + tid * 8);
    gload_lds16(b1 + k0, Bs + (tid + 256) * 8);
    __syncthreads();
    bf16x8 av[4], bv[4];
#pragma unroll
    for (int i = 0; i < 4; ++i)
      av[i] = *reinterpret_cast<const bf16x8*>(As + (wm + i * 16 + r16) * 32 + q4 * 8);
#pragma unroll
    for (int j = 0; j < 4; ++j)
      bv[j] = *reinterpret_cast<const bf16x8*>(Bs + (wn + j * 16 + r16) * 32 + q4 * 8);
#pragma unroll
    for (int i = 0; i < 4; ++i)
#pragma unroll
      for (int j = 0; j < 4; ++j)
        acc[i][j] = __builtin_amdgcn_mfma_f32_16x16x32_bf16(av[i], bv[j], acc[i][j], 0, 0, 0);
    __syncthreads();
  }

#pragma unroll
  for (int i = 0; i < 4; ++i)
#pragma unroll
    for (int j = 0; j < 4; ++j)
#pragma unroll
      for (int r = 0; r < 4; ++r) {
        long grow = bm + wm + i * 16 + q4 * 4 + r;
        int gcol = (int)bnn + wn + j * 16 + r16;
        float v = acc[i][j][r];
        if (gcol < Nreal) {
          if (EPI == 0 || EPI == 1) {
            v += bias[gcol];
            if (EPI == 1) v = gelu_f(v);
            ((u16*)C)[grow * ldc + gcol] = f2bf(v);
          } else if (EPI == 2) {
            atomicAdd((float*)C + grow * ldc + gcol, v);
          } else {
            ((float*)C)[grow * ldc + gcol] = v;
          }
        }
      }
}

// ---------------- top-8 per row, parallel tree merge ----------------
DEV bool better(float v1, int i1, float v2, int i2) {
  return v1 > v2 || (v1 == v2 && i1 < i2);
}
__global__ __launch_bounds__(256) void topk_kernel(const float* __restrict__ sim,
                                                   int* __restrict__ idxout) {
  const int bn = blockIdx.x;
  const int tid = threadIdx.x;
  const float* row = sim + (long)bn * 8192;
  float bv[8]; int bi[8];
#pragma unroll
  for (int r = 0; r < 8; ++r) { bv[r] = -3.0e38f; bi[r] = 0x7fffffff; }
  for (int n = tid; n < 8192; n += 256) {
    float v = row[n];
    if (better(v, n, bv[7], bi[7])) {
      bv[7] = v; bi[7] = n;
      for (int r = 7; r > 0; --r) {
        if (!better(bv[r], bi[r], bv[r - 1], bi[r - 1])) break;
        float tv = bv[r]; bv[r] = bv[r - 1]; bv[r - 1] = tv;
        int ti = bi[r]; bi[r] = bi[r - 1]; bi[r - 1] = ti;
      }
    }
  }
  __shared__ float lv[256 * 8];
  __shared__ int li[256 * 8];
#pragma unroll
  for (int r = 0; r < 8; ++r) { lv[tid * 8 + r] = bv[r]; li[tid * 8 + r] = bi[r]; }
  __syncthreads();
  for (int step = 128; step >= 1; step >>= 1) {
    if (tid < step) {
      float av[8], xv[8]; int ai[8], xi[8];
#pragma unroll
      for (int r = 0; r < 8; ++r) {
        av[r] = lv[tid * 8 + r]; ai[r] = li[tid * 8 + r];
        xv[r] = lv[(tid + step) * 8 + r]; xi[r] = li[(tid + step) * 8 + r];
      }
      int ia = 0, ib = 0;
      float mv[8]; int mi[8];
#pragma unroll
      for (int r = 0; r < 8; ++r) {
        if (better(av[ia], ai[ia], xv[ib], xi[ib])) { mv[r] = av[ia]; mi[r] = ai[ia]; ++ia; }
        else { mv[r] = xv[ib]; mi[r] = xi[ib]; ++ib; }
      }
#pragma unroll
      for (int r = 0; r < 8; ++r) { lv[tid * 8 + r] = mv[r]; li[tid * 8 + r] = mi[r]; }
    }
    __syncthreads();
  }
  if (tid < 8) idxout[bn * 8 + tid] = li[tid];
}

// ---------------- gather retrieved rows, f32 -> bf16, clamped ----------------
__global__ __launch_bounds__(256) void gather_kernel(const float* __restrict__ mb,
                                                     const int* __restrict__ idx,
                                                     u16* __restrict__ retrB) {
  int t = blockIdx.x * 256 + threadIdx.x;  // < 524288
  int m = t >> 6;
  int c8 = (t & 63) * 8;
  long r = idx[m];
  if (r < 0) r = 0;
  if (r > 8191) r = 8191;
  const float* src = mb + r * 512 + c8;
  u16* dst = retrB + (long)m * 512 + c8;
#pragma unroll
  for (int z = 0; z < 8; ++z) dst[z] = f2bf(src[z]);
}

// ---------------- mean over K of gelu-hidden -> bf16 ----------------
__global__ __launch_bounds__(256) void gmean_kernel(const u16* __restrict__ hid,
                                                    u16* __restrict__ gmeanB) {
  int t = blockIdx.x * 256 + threadIdx.x;  // < 1048576
  int bn = t >> 10, j = t & 1023;
  float s = 0.f;
#pragma unroll
  for (int k = 0; k < 8; ++k) s += bf2f(hid[(long)(bn * 8 + k) * 1024 + j]);
  gmeanB[t] = f2bf(s * 0.125f);
}

// ---------------- attention: one block per (bn, head); atto over q ----------------
__global__ __launch_bounds__(256) void attn_kernel(u16* __restrict__ qb,
                                                   const u16* __restrict__ kb,
                                                   const u16* __restrict__ vb) {
  const int bn = blockIdx.x;
  const int h = blockIdx.y;
  const int tid = threadIdx.x;
  __shared__ __align__(16) u16 qs[64 * 132];  // stride 66 dwords -> 2-way alias (free)
  __shared__ __align__(16) u16 ks[64 * 132];
  __shared__ float ss[64 * 64];
  const long base = (long)bn * 64 * 512 + h * 128;
  for (int c = tid; c < 1024; c += 256) {
    int r = c >> 4, c8 = (c & 15) * 8;
    u16x8 vq = *(const u16x8*)(qb + base + (long)r * 512 + c8);
    u16x8 vk = *(const u16x8*)(kb + base + (long)r * 512 + c8);
    *(u16x4*)(qs + r * 132 + c8) = u16x4{vq[0], vq[1], vq[2], vq[3]};
    *(u16x4*)(qs + r * 132 + c8 + 4) = u16x4{vq[4], vq[5], vq[6], vq[7]};
    *(u16x4*)(ks + r * 132 + c8) = u16x4{vk[0], vk[1], vk[2], vk[3]};
    *(u16x4*)(ks + r * 132 + c8 + 4) = u16x4{vk[4], vk[5], vk[6], vk[7]};
  }
  __syncthreads();
  const float scale = 0.08838834764831845f;  // 1/sqrt(128)
  for (int e = tid; e < 4096; e += 256) {
    int i = e >> 6, j = e & 63;
    const u16* qr = qs + i * 132;
    const u16* kr = ks + j * 132;
    float a = 0.f;
#pragma unroll
    for (int d = 0; d < 128; d += 4) {
      u16x4 qv = *(const u16x4*)(qr + d);
      u16x4 kv = *(const u16x4*)(kr + d);
      a += bf2f(qv[0]) * bf2f(kv[0]) + bf2f(qv[1]) * bf2f(kv[1]) +
           bf2f(qv[2]) * bf2f(kv[2]) + bf2f(qv[3]) * bf2f(kv[3]);
    }
    ss[i * 64 + j] = a * scale;
  }
  __syncthreads();
  // stage V into qs region
  for (int c = tid; c < 1024; c += 256) {
    int r = c >> 4, c8 = (c & 15) * 8;
    u16x8 vv = *(const u16x8*)(vb + base + (long)r * 512 + c8);
    *(u16x4*)(qs + r * 132 + c8) = u16x4{vv[0], vv[1], vv[2], vv[3]};
    *(u16x4*)(qs + r * 132 + c8 + 4) = u16x4{vv[4], vv[5], vv[6], vv[7]};
  }
  if (tid < 64) {
    float* row = ss + tid * 64;
    float mx = row[0];
    for (int j = 1; j < 64; ++j) mx = fmaxf(mx, row[j]);
    float s = 0.f;
    for (int j = 0; j < 64; ++j) { float e = expf(row[j] - mx); row[j] = e; s += e; }
    float inv = 1.f / s;
    for (int j = 0; j < 64; ++j) row[j] *= inv;
  }
  __syncthreads();
  // PV: 2048 tasks of (i, 4-wide d-group), 8 per thread
  for (int e = tid; e < 2048; e += 256) {
    int i = e >> 5, dg = (e & 31) * 4;
    float a0 = 0.f, a1 = 0.f, a2 = 0.f, a3 = 0.f;
#pragma unroll 8
    for (int j = 0; j < 64; ++j) {
      float p = ss[i * 64 + j];
      u16x4 vv = *(const u16x4*)(qs + j * 132 + dg);
      a0 += p * bf2f(vv[0]); a1 += p * bf2f(vv[1]);
      a2 += p * bf2f(vv[2]); a3 += p * bf2f(vv[3]);
    }
    *(u16x4*)(qb + base + (long)i * 512 + dg) = u16x4{f2bf(a0), f2bf(a1), f2bf(a2), f2bf(a3)};
  }
}

// ---------------- local = emb + hmean (in-place over embh) ----------------
__global__ __launch_bounds__(256) void local_kernel(u16* __restrict__ embh,
                                                    const u16* __restrict__ hmeanB) {
  long t = (long)blockIdx.x * 256 + threadIdx.x;  // < 33554432
  long m = t >> 9;
  int d = (int)(t & 511);
  int bn = (int)(m >> 6);
  embh[t] = f2bf(bf2f(hmeanB[(long)bn * 512 + d]) + bf2f(embh[t]));
}

// ---------------- concat-K NT GEMM: C = gelu([A1|A2] @ Wg1T^T + bias) ----------------
__global__ __launch_bounds__(256) void gemm_cat(const u16* __restrict__ A1,
                                                const u16* __restrict__ A2,
                                                const u16* __restrict__ Bt,
                                                const float* __restrict__ bias,
                                                u16* __restrict__ C) {
  __shared__ __align__(16) u16 As[128 * 32];
  __shared__ __align__(16) u16 Bs[128 * 32];
  const int tid = threadIdx.x;
  const long bm = (long)blockIdx.x * 128;
  const long bnn = (long)blockIdx.y * 128;
  const int lane = tid & 63;
  const int wid = tid >> 6;
  const int wm = (wid & 1) * 64;
  const int wn = (wid >> 1) * 64;
  const int r16 = lane & 15;
  const int q4 = lane >> 4;

  f32x4 acc[4][4] = {};

  const int row0 = tid >> 2;
  const int cg = (tid & 3) * 8;
  const int row1 = row0 + 64;
  const u16* a10 = A1 + (bm + row0) * 512 + cg;
  const u16* a11 = A1 + (bm + row1) * 512 + cg;
  const u16* a20 = A2 + (bm + row0) * 512 + cg;
  const u16* a21 = A2 + (bm + row1) * 512 + cg;
  const u16* b0 = Bt + (bnn + row0) * 1024 + cg;
  const u16* b1 = Bt + (bnn + row1) * 1024 + cg;

  for (int k0 = 0; k0 < 1024; k0 += 32) {
    if (k0 < 512) {
      gload_lds16(a10 + k0, As + tid * 8);
      gload_lds16(a11 + k0, As + (tid + 256) * 8);
    } else {
      gload_lds16(a20 + (k0 - 512), As + tid * 8);
      gload_lds16(a21 + (k0 - 512), As + (tid + 256) * 8);
    }
    gload_lds16(b0 + k0, Bs + tid * 8);
    gload_lds16(b1 + k0, Bs + (tid + 256) * 8);
    __syncthreads();
    bf16x8 av[4], bv[4];
#pragma unroll
    for (int i = 0; i < 4; ++i)
      av[i] = *reinterpret_cast<const bf16x8*>(As + (wm + i * 16 + r16) * 32 + q4 * 8);
#pragma unroll
    for (int j = 0; j < 4; ++j)
      bv[j] = *reinterpret_cast<const bf16x8*>(Bs + (wn + j * 16 + r16) * 32 + q4 * 8);
#pragma unroll
    for (int i = 0; i < 4; ++i)
#pragma unroll
      for (int j = 0; j < 4; ++j)
        acc[i][j] = __builtin_amdgcn_mfma_f32_16x16x32_bf16(av[i], bv[j], acc[i][j], 0, 0, 0);
    __syncthreads();
  }

#pragma unroll
  for (int i = 0; i < 4; ++i)
#pragma unroll
    for (int j = 0; j < 4; ++j)
#pragma unroll
      for (int r = 0; r < 4; ++r) {
        long grow = bm + wm + i * 16 + q4 * 4 + r;
        int gcol = (int)bnn + wn + j * 16 + r16;
        float v = acc[i][j][r] + bias[gcol];
        C[grow * 512 + gcol] = f2bf(gelu_f(v));
      }
}

// ---------------- gate logits + softmax(2) ----------------
__global__ __launch_bounds__(256) void g2_kernel(const u16* __restrict__ h1b,
                                                 const float* __restrict__ W_g2,
                                                 const float* __restrict__ b_g2,
                                                 float* __restrict__ gatel) {
  int m = blockIdx.x * 4 + (threadIdx.x >> 6);
  int lane = threadIdx.x & 63;
  const u16* row = h1b + (long)m * 512;
  float a0 = 0.f, a1 = 0.f;
  for (int i = lane; i < 512; i += 64) {
    float h = bf2f(row[i]);
    a0 += h * W_g2[i * 2];
    a1 += h * W_g2[i * 2 + 1];
  }
  for (int off = 32; off; off >>= 1) {
    a0 += __shfl_down(a0, off);
    a1 += __shfl_down(a1, off);
  }
  if (lane == 0) {
    a0 += b_g2[0];
    a1 += b_g2[1];
    float mx = fmaxf(a0, a1);
    float e0 = expf(a0 - mx), e1 = expf(a1 - mx);
    float inv = 1.f / (e0 + e1);
    gatel[(long)m * 2] = e0 * inv;
    gatel[(long)m * 2 + 1] = e1 * inv;
  }
}

// ---------------- mem = g0*local + g1*glob ----------------
__global__ __launch_bounds__(256) void memc_kernel(const u16* __restrict__ localB,
                                                   const u16* __restrict__ globB,
                                                   const float* __restrict__ gatel,
                                                   u16* __restrict__ memB) {
  long t = (long)blockIdx.x * 256 + threadIdx.x;  // < 33554432
  long m = t >> 9;
  float loc = bf2f(localB[t]);
  float gl = bf2f(globB[t]);
  float g0 = gatel[m * 2], g1 = gatel[m * 2 + 1];
  memB[t] = f2bf(g0 * loc + g1 * gl);
}

// ---------------- fusion head + denorm + transpose store (f32) ----------------
__global__ __launch_bounds__(256) void fusion_kernel(const float* __restrict__ mh,
                                                     const float* __restrict__ b_h,
                                                     const float* __restrict__ W_f1,
                                                     const float* __restrict__ b_f1,
                                                     const float* __restrict__ W_f2,
                                                     const float* __restrict__ b_f2,
                                                     const float* __restrict__ meanv,
                                                     const float* __restrict__ stdv,
                                                     float* __restrict__ out) {
  int bn = blockIdx.x;
  int tid = threadIdx.x;
  __shared__ float mrow[192];
  __shared__ float h1[384];
  if (tid < 192) mrow[tid] = mh[(long)bn * 192 + tid] + b_h[tid];
  __syncthreads();
  for (int j = tid; j < 384; j += 256) {
    float a = b_f1[j];
    for (int i = 0; i < 192; ++i) a += mrow[i] * W_f1[i * 384 + j];
    h1[j] = gelu_f(a);
  }
  __syncthreads();
  if (tid < 192) {
    float a = b_f2[tid];
    for (int j = 0; j < 384; ++j) a += h1[j] * W_f2[j * 192 + tid];
    float o = gelu_f(a) + mrow[tid];
    int b = bn >> 6, v = bn & 63;
    out[((long)b * 192 + tid) * 64 + v] = o * stdv[bn] + meanv[bn];
  }
}

extern "C" void kernel_launch(void* const* d_in, const int* in_sizes, int n_in,
                              void* d_out, int out_size, void* d_ws, size_t ws_size,
                              hipStream_t stream) {
  (void)in_sizes; (void)n_in; (void)out_size; (void)d_ws; (void)ws_size;
  const float* x_enc = (const float*)d_in[0];
  const float* W_val = (const float*)d_in[1];
  const float* mem_bank = (const float*)d_in[2];
  const float* W_m1 = (const float*)d_in[3];
  const float* b_m1 = (const float*)d_in[4];
  const float* W_m2 = (const float*)d_in[5];
  const float* b_m2 = (const float*)d_in[6];
  const float* W_q = (const float*)d_in[7];
  const float* b_q = (const float*)d_in[8];
  const float* W_k = (const float*)d_in[9];
  const float* b_k = (const float*)d_in[10];
  const float* W_v = (const float*)d_in[11];
  const float* b_v = (const float*)d_in[12];
  const float* W_o = (const float*)d_in[13];
  const float* b_o = (const float*)d_in[14];
  const float* W_g1 = (const float*)d_in[15];
  const float* b_g1 = (const float*)d_in[16];
  const float* W_g2 = (const float*)d_in[17];
  const float* b_g2 = (const float*)d_in[18];
  const float* W_h = (const float*)d_in[19];
  const float* b_h = (const float*)d_in[20];
  const float* W_f1 = (const float*)d_in[21];
  const float* b_f1 = (const float*)d_in[22];
  const float* W_f2 = (const float*)d_in[23];
  const float* b_f2 = (const float*)d_in[24];

  void* sp = nullptr;
  hipGetSymbolAddress(&sp, HIP_SYMBOL(g_s));
  Scratch* S = (Scratch*)sp;
  // sim-phase aliases (all dead before QKV writes)
  u16* qsC = S->vb;                                  // 4 MB
  float* simB = (float*)S->qb;                       // 32 MB
  u16* retrB = S->kb;                                // 8 MB
  u16* hiddenB = S->kb + (size_t)4 * 1024 * 1024;    // 16 MB

  // setup
  pos_kernel<<<64, 256, 0, stream>>>(S->POSb);
  stats_kernel<<<16, 256, 0, stream>>>(x_enc, S->meanv, S->stdv);
  zerof_kernel<<<768, 256, 0, stream>>>(S->mh, 1024 * 192);
  zerou_kernel<<<8192, 256, 0, stream>>>(S->WhT + (size_t)192 * 32768, 64 * 32768);
  transpose_kernel<<<dim3(16, 16), 256, 0, stream>>>(W_q, S->WqT, 512, 512);
  transpose_kernel<<<dim3(16, 16), 256, 0, stream>>>(W_k, S->WkT, 512, 512);
  transpose_kernel<<<dim3(16, 16), 256, 0, stream>>>(W_v, S->WvT, 512, 512);
  transpose_kernel<<<dim3(16, 16), 256, 0, stream>>>(W_o, S->WoT, 512, 512);
  transpose_kernel<<<dim3(32, 16), 256, 0, stream>>>(W_m1, S->Wm1T, 512, 1024);
  transpose_kernel<<<dim3(16, 32), 256, 0, stream>>>(W_m2, S->Wm2T, 1024, 512);
  transpose_kernel<<<dim3(16, 32), 256, 0, stream>>>(W_g1, S->Wg1T, 1024, 512);
  transpose_kernel<<<dim3(6, 1024), 256, 0, stream>>>(W_h, S->WhT, 32768, 192);
  memdup_kernel<<<16384, 256, 0, stream>>>(mem_bank, S->memdupB);

  // embedding
  emb_kernel<<<1024, 256, 0, stream>>>(x_enc, W_val, S->POSb, S->meanv, S->stdv,
                                       S->embh, S->qflat);
  // retrieval
  qsplit_kernel<<<2048, 256, 0, stream>>>(S->qflat, qsC);
  gemm_nt<3><<<dim3(8, 64), 256, 0, stream>>>(qsC, S->memdupB, nullptr, simB,
                                              2048, 2048, 2048, 8192, 8192);
  topk_kernel<<<1024, 256, 0, stream>>>(simB, S->idxB);
  gather_kernel<<<2048, 256, 0, stream>>>(mem_bank, S->idxB, retrB);
  gemm_nt<1><<<dim3(64, 8), 256, 0, stream>>>(retrB, S->Wm1T, b_m1, hiddenB,
                                              512, 512, 512, 1024, 1024);
  gmean_kernel<<<4096, 256, 0, stream>>>(hiddenB, S->gmeanB);
  gemm_nt<0><<<dim3(8, 4), 256, 0, stream>>>(S->gmeanB, S->Wm2T, b_m2, S->hmeanB,
                                             1024, 1024, 1024, 512, 512);
  // QKV (M = 65536)
  gemm_nt<0><<<dim3(512, 4), 256, 0, stream>>>(S->embh, S->WqT, b_q, S->qb,
                                               512, 512, 512, 512, 512);
  gemm_nt<0><<<dim3(512, 4), 256, 0, stream>>>(S->embh, S->WkT, b_k, S->kb,
                                               512, 512, 512, 512, 512);
  gemm_nt<0><<<dim3(512, 4), 256, 0, stream>>>(S->embh, S->WvT, b_v, S->vb,
                                               512, 512, 512, 512, 512);
  // local = emb + hmean (in place; QKV consumed emb)
  local_kernel<<<131072, 256, 0, stream>>>(S->embh, S->hmeanB);
  // attention (atto over qb)
  attn_kernel<<<dim3(1024, 4), 256, 0, stream>>>(S->qb, S->kb, S->vb);
  // glob = atto @ W_o + b_o -> kb
  gemm_nt<0><<<dim3(512, 4), 256, 0, stream>>>(S->qb, S->WoT, b_o, S->kb,
                                               512, 512, 512, 512, 512);
  // h1 = gelu([local|glob] @ W_g1 + b_g1) -> vb
  gemm_cat<<<dim3(512, 4), 256, 0, stream>>>(S->embh, S->kb, S->Wg1T, b_g1, S->vb);
  g2_kernel<<<16384, 256, 0, stream>>>(S->vb, W_g2, b_g2, S->gatel);
  // mem = g0*local + g1*glob -> qb
  memc_kernel<<<131072, 256, 0, stream>>>(S->embh, S->kb, S->gatel, S->qb);
  // mh = mem_flat [1024,32768] @ WhT^T, split-K x16, f32 atomics
  gemm_nt<2><<<dim3(8, 2, 16), 256, 0, stream>>>(S->qb, S->WhT, nullptr, S->mh,
                                                 32768, 32768, 2048, 192, 192);
  fusion_kernel<<<1024, 256, 0, stream>>>(S->mh, b_h, W_f1, b_f1, W_f2, b_f2,
                                          S->meanv, S->stdv, (float*)d_out);
}

// Round 7
// 1276.910 us; speedup vs baseline: 4.6042x; 1.1961x over previous
//
#include <hip/hip_runtime.h>
#include <stdint.h>

#define DEV __device__ __forceinline__

typedef uint16_t u16;
typedef __bf16 bf16x8 __attribute__((ext_vector_type(8)));
typedef float f32x4 __attribute__((ext_vector_type(4)));
typedef u16 u16x8 __attribute__((ext_vector_type(8)));
typedef u16 u16x4 __attribute__((ext_vector_type(4)));

DEV float bf2f(u16 v) { return __uint_as_float(((uint32_t)v) << 16); }
DEV u16 f2bf(float f) {
  uint32_t u = __float_as_uint(f);
  u += 0x7fffu + ((u >> 16) & 1u);
  return (u16)(u >> 16);
}
DEV float gelu_f(float x) { return 0.5f * x * (1.0f + erff(x * 0.7071067811865475f)); }

DEV void gload_lds16(const u16* g, u16* l) {
  __builtin_amdgcn_global_load_lds(
      (const __attribute__((address_space(1))) void*)g,
      (__attribute__((address_space(3))) void*)l, 16, 0, 0);
}

// ---- all scratch in a static device global (R4: never trust ws_size) ----
struct __align__(16) Scratch {
  float POSb[64 * 512];
  float meanv[1024];
  float stdv[1024];
  float mh[1024 * 192];
  int idxB[8192];
  float qflat[1024 * 512];
  float gatel[65536 * 2];
  u16 hmeanB[1024 * 512];
  u16 gmeanB[1024 * 1024];
  u16 WqT[512 * 512];
  u16 WkT[512 * 512];
  u16 WvT[512 * 512];
  u16 WoT[512 * 512];
  u16 Wm1T[1024 * 512];
  u16 Wm2T[512 * 1024];
  u16 Wg1T[512 * 1024];
  u16 WhT[256 * 32768];        // rows 192..255 zero-filled
  u16 memdupB[8192 * 1536];    // [mh|mh|ml] 24 MB
  u16 embh[65536 * 512];       // 64 MB (becomes `local` in place)
  u16 qb[65536 * 512];         // 64 MB (sim phase: simB f32 alias)
  u16 kb[65536 * 512];         // 64 MB (sim phase: retrB + hiddenB alias)
  u16 vb[65536 * 512];         // 64 MB (sim phase: qsC alias)
};
__device__ Scratch g_s;

// ---------------- fills ----------------
__global__ __launch_bounds__(256) void zerof_kernel(float* __restrict__ p, int n) {
  int t = blockIdx.x * 256 + threadIdx.x;
  if (t < n) p[t] = 0.f;
}
__global__ __launch_bounds__(256) void zerou_kernel(u16* __restrict__ p, int n) {
  int t = blockIdx.x * 256 + threadIdx.x;
  if (t < n) p[t] = 0;
}

// ---------------- POS embedding ----------------
__global__ __launch_bounds__(256) void pos_kernel(float* __restrict__ POS) {
  int n = blockIdx.x;
  int i = threadIdx.x;
  float div = expf((float)(2 * i) * (-9.210340371976184f / 512.0f));
  float arg = (float)n * div;
  POS[n * 512 + 2 * i] = sinf(arg);
  POS[n * 512 + 2 * i + 1] = cosf(arg);
}

// ---------------- instance-norm stats ----------------
__global__ __launch_bounds__(256) void stats_kernel(const float* __restrict__ x_enc,
                                                    float* __restrict__ meanv,
                                                    float* __restrict__ stdv) {
  int b = blockIdx.x;
  int v = threadIdx.x & 63;
  int g = threadIdx.x >> 6;
  float s = 0.f, s2 = 0.f;
  for (int l = g; l < 512; l += 4) {
    float x = x_enc[((long)b * 512 + l) * 64 + v];
    s += x; s2 += x * x;
  }
  __shared__ float sh[2][4][64];
  sh[0][g][v] = s; sh[1][g][v] = s2;
  __syncthreads();
  if (g == 0) {
    s = sh[0][0][v] + sh[0][1][v] + sh[0][2][v] + sh[0][3][v];
    s2 = sh[1][0][v] + sh[1][1][v] + sh[1][2][v] + sh[1][3][v];
    float mu = s * (1.f / 512.f);
    float var = s2 * (1.f / 512.f) - mu * mu;
    meanv[b * 64 + v] = mu;
    stdv[b * 64 + v] = sqrtf(var + 1e-5f) * 2.5f;  // sqrt(var+eps)/0.4
  }
}

// ---------------- transpose f32 [R,C] -> bf16 [C,R] ----------------
__global__ __launch_bounds__(256) void transpose_kernel(const float* __restrict__ in,
                                                        u16* __restrict__ out, int R, int C) {
  __shared__ u16 t[32][33];
  int bx = blockIdx.x * 32;
  int by = blockIdx.y * 32;
  int tx = threadIdx.x & 31, ty = threadIdx.x >> 5;
  for (int i = ty; i < 32; i += 8) t[i][tx] = f2bf(in[(long)(by + i) * C + bx + tx]);
  __syncthreads();
  for (int i = ty; i < 32; i += 8) out[(long)(bx + i) * R + by + tx] = t[tx][i];
}

// ---------------- patch embed + qflat ----------------
__global__ __launch_bounds__(256) void emb_kernel(const float* __restrict__ x_enc,
                                                  const float* __restrict__ W_val,
                                                  const float* __restrict__ POS,
                                                  const float* __restrict__ meanv,
                                                  const float* __restrict__ stdv,
                                                  u16* __restrict__ embh,
                                                  float* __restrict__ qflat) {
  int bn = blockIdx.x;
  int b = bn >> 6, v = bn & 63;
  int tid = threadIdx.x;
  __shared__ __align__(16) float wv[16 * 512];
  __shared__ __align__(16) float pt[64 * 16];
  for (int i = tid; i < 8192; i += 256) wv[i] = W_val[i];
  float mu = meanv[bn];
  float inv = 1.f / stdv[bn];
  for (int i = tid; i < 1024; i += 256) {
    int n = i >> 4, p = i & 15;
    int l = n * 8 + p; if (l > 511) l = 511;  // replication pad
    pt[i] = (x_enc[((long)b * 512 + l) * 64 + v] - mu) * inv;
  }
  __syncthreads();
  float qs0 = 0.f, qs1 = 0.f;
  int d0 = tid, d1 = tid + 256;
  for (int n = 0; n < 64; ++n) {
    float a0 = POS[n * 512 + d0], a1 = POS[n * 512 + d1];
#pragma unroll
    for (int p = 0; p < 16; ++p) {
      float pv = pt[n * 16 + p];
      a0 += pv * wv[p * 512 + d0];
      a1 += pv * wv[p * 512 + d1];
    }
    long base = ((long)bn * 64 + n) * 512;
    embh[base + d0] = f2bf(a0);
    embh[base + d1] = f2bf(a1);
    qs0 += a0; qs1 += a1;
  }
  qflat[(long)bn * 512 + d0] = qs0 * (1.f / 64.f);
  qflat[(long)bn * 512 + d1] = qs1 * (1.f / 64.f);
}

// ---------------- qflat f32 -> [qh|ql|qh] bf16 row of 1536 ----------------
__global__ __launch_bounds__(256) void qsplit_kernel(const float* __restrict__ qflat,
                                                     u16* __restrict__ qsC) {
  int t = blockIdx.x * 256 + threadIdx.x;  // < 524288
  int bn = t >> 9, d = t & 511;
  float q = qflat[t];
  u16 hi = f2bf(q);
  u16 lo = f2bf(q - bf2f(hi));
  long base = (long)bn * 1536;
  qsC[base + d] = hi;
  qsC[base + 512 + d] = lo;
  qsC[base + 1024 + d] = hi;
}

// ---------------- mem_bank f32 -> [mh|mh|ml] bf16 row of 1536 ----------------
__global__ __launch_bounds__(256) void memdup_kernel(const float* __restrict__ mb,
                                                     u16* __restrict__ md) {
  int t = blockIdx.x * 256 + threadIdx.x;  // < 4194304
  int n = t >> 9, k = t & 511;
  float m = mb[t];
  u16 hi = f2bf(m);
  u16 lo = f2bf(m - bf2f(hi));
  long base = (long)n * 1536;
  md[base + k] = hi;
  md[base + 512 + k] = hi;
  md[base + 1024 + k] = lo;
}

// ---------------- NT MFMA GEMM, m97-style global_load_lds staging ----------------
// EPI: 0 bias+bf16 | 1 bias+gelu+bf16 | 2 f32 atomicAdd | 3 f32 store
template <int EPI>
__global__ __launch_bounds__(256) void gemm_nt(const u16* __restrict__ Ag,
                                               const u16* __restrict__ Bt,
                                               const float* __restrict__ bias,
                                               void* __restrict__ C,
                                               int lda, int ldb, int K, int Nreal, int ldc) {
  __shared__ __align__(16) u16 As[128 * 32];
  __shared__ __align__(16) u16 Bs[128 * 32];
  const int tid = threadIdx.x;
  const long bm = (long)blockIdx.x * 128;
  const long bnn = (long)blockIdx.y * 128;
  const long koff = (long)blockIdx.z * K;
  const int lane = tid & 63;
  const int wid = tid >> 6;
  const int wm = (wid & 1) * 64;
  const int wn = (wid >> 1) * 64;
  const int r16 = lane & 15;
  const int q4 = lane >> 4;

  f32x4 acc[4][4] = {};

  const int row0 = tid >> 2;
  const int cg = (tid & 3) * 8;
  const int row1 = row0 + 64;
  const u16* a0 = Ag + (bm + row0) * lda + koff + cg;
  const u16* a1 = Ag + (bm + row1) * lda + koff + cg;
  const u16* b0 = Bt + (bnn + row0) * ldb + koff + cg;
  const u16* b1 = Bt + (bnn + row1) * ldb + koff + cg;

  for (int k0 = 0; k0 < K; k0 += 32) {
    gload_lds16(a0 + k0, As + tid * 8);
    gload_lds16(a1 + k0, As + (tid + 256) * 8);
    gload_lds16(b0 + k0, Bs + tid * 8);
    gload_lds16(b1 + k0, Bs + (tid + 256) * 8);
    __syncthreads();
    bf16x8 av[4], bv[4];
#pragma unroll
    for (int i = 0; i < 4; ++i)
      av[i] = *reinterpret_cast<const bf16x8*>(As + (wm + i * 16 + r16) * 32 + q4 * 8);
#pragma unroll
    for (int j = 0; j < 4; ++j)
      bv[j] = *reinterpret_cast<const bf16x8*>(Bs + (wn + j * 16 + r16) * 32 + q4 * 8);
#pragma unroll
    for (int i = 0; i < 4; ++i)
#pragma unroll
      for (int j = 0; j < 4; ++j)
        acc[i][j] = __builtin_amdgcn_mfma_f32_16x16x32_bf16(av[i], bv[j], acc[i][j], 0, 0, 0);
    __syncthreads();
  }

#pragma unroll
  for (int i = 0; i < 4; ++i)
#pragma unroll
    for (int j = 0; j < 4; ++j)
#pragma unroll
      for (int r = 0; r < 4; ++r) {
        long grow = bm + wm + i * 16 + q4 * 4 + r;
        int gcol = (int)bnn + wn + j * 16 + r16;
        float v = acc[i][j][r];
        if (gcol < Nreal) {
          if (EPI == 0 || EPI == 1) {
            v += bias[gcol];
            if (EPI == 1) v = gelu_f(v);
            ((u16*)C)[grow * ldc + gcol] = f2bf(v);
          } else if (EPI == 2) {
            atomicAdd((float*)C + grow * ldc + gcol, v);
          } else {
            ((float*)C)[grow * ldc + gcol] = v;
          }
        }
      }
}

// ---------------- top-8 per row, parallel tree merge ----------------
DEV bool better(float v1, int i1, float v2, int i2) {
  return v1 > v2 || (v1 == v2 && i1 < i2);
}
__global__ __launch_bounds__(256) void topk_kernel(const float* __restrict__ sim,
                                                   int* __restrict__ idxout) {
  const int bn = blockIdx.x;
  const int tid = threadIdx.x;
  const float* row = sim + (long)bn * 8192;
  float bv[8]; int bi[8];
#pragma unroll
  for (int r = 0; r < 8; ++r) { bv[r] = -3.0e38f; bi[r] = 0x7fffffff; }
  for (int n = tid; n < 8192; n += 256) {
    float v = row[n];
    if (better(v, n, bv[7], bi[7])) {
      bv[7] = v; bi[7] = n;
      for (int r = 7; r > 0; --r) {
        if (!better(bv[r], bi[r], bv[r - 1], bi[r - 1])) break;
        float tv = bv[r]; bv[r] = bv[r - 1]; bv[r - 1] = tv;
        int ti = bi[r]; bi[r] = bi[r - 1]; bi[r - 1] = ti;
      }
    }
  }
  __shared__ float lv[256 * 8];
  __shared__ int li[256 * 8];
#pragma unroll
  for (int r = 0; r < 8; ++r) { lv[tid * 8 + r] = bv[r]; li[tid * 8 + r] = bi[r]; }
  __syncthreads();
  for (int step = 128; step >= 1; step >>= 1) {
    if (tid < step) {
      float av[8], xv[8]; int ai[8], xi[8];
#pragma unroll
      for (int r = 0; r < 8; ++r) {
        av[r] = lv[tid * 8 + r]; ai[r] = li[tid * 8 + r];
        xv[r] = lv[(tid + step) * 8 + r]; xi[r] = li[(tid + step) * 8 + r];
      }
      int ia = 0, ib = 0;
      float mv[8]; int mi[8];
#pragma unroll
      for (int r = 0; r < 8; ++r) {
        if (better(av[ia], ai[ia], xv[ib], xi[ib])) { mv[r] = av[ia]; mi[r] = ai[ia]; ++ia; }
        else { mv[r] = xv[ib]; mi[r] = xi[ib]; ++ib; }
      }
#pragma unroll
      for (int r = 0; r < 8; ++r) { lv[tid * 8 + r] = mv[r]; li[tid * 8 + r] = mi[r]; }
    }
    __syncthreads();
  }
  if (tid < 8) idxout[bn * 8 + tid] = li[tid];
}

// ---------------- gather retrieved rows, f32 -> bf16, clamped ----------------
__global__ __launch_bounds__(256) void gather_kernel(const float* __restrict__ mb,
                                                     const int* __restrict__ idx,
                                                     u16* __restrict__ retrB) {
  int t = blockIdx.x * 256 + threadIdx.x;  // < 524288
  int m = t >> 6;
  int c8 = (t & 63) * 8;
  long r = idx[m];
  if (r < 0) r = 0;
  if (r > 8191) r = 8191;
  const float* src = mb + r * 512 + c8;
  u16* dst = retrB + (long)m * 512 + c8;
#pragma unroll
  for (int z = 0; z < 8; ++z) dst[z] = f2bf(src[z]);
}

// ---------------- mean over K of gelu-hidden -> bf16 ----------------
__global__ __launch_bounds__(256) void gmean_kernel(const u16* __restrict__ hid,
                                                    u16* __restrict__ gmeanB) {
  int t = blockIdx.x * 256 + threadIdx.x;  // < 1048576
  int bn = t >> 10, j = t & 1023;
  float s = 0.f;
#pragma unroll
  for (int k = 0; k < 8; ++k) s += bf2f(hid[(long)(bn * 8 + k) * 1024 + j]);
  gmeanB[t] = f2bf(s * 0.125f);
}

// ---------------- MFMA attention: one block per (bn, head); atto over q ----------------
// LDS layout (53504 B): Qs[64][136] @0 (ps[64][72] overlays) | Ks[64][136] @17408
// (ss f32 [64][66] overlays) | Vb 16 tiles x 520 @34816 | red 512 f32 @51456
__global__ __launch_bounds__(256) void attn_kernel(u16* __restrict__ qb,
                                                   const u16* __restrict__ kb,
                                                   const u16* __restrict__ vb) {
  __shared__ __align__(16) u16 smem[26752];
  u16* Qs = smem;
  u16* Ks = smem + 8704;              // 17408 B / 2
  float* ss = (float*)(smem + 8704);  // overlay Ks
  u16* ps = smem;                     // overlay Qs
  u16* Vb = smem + 17408;             // 34816 B / 2
  float* red = (float*)(smem + 25728);// 51456 B / 2
  const int bn = blockIdx.x, h = blockIdx.y;
  const int tid = threadIdx.x;
  const int lane = tid & 63, w = tid >> 6;
  const int r16 = lane & 15, q4 = lane >> 4;
  const long base = (long)bn * 64 * 512 + h * 128;

  // ---- stage Q, K row-major (stride 136); V in B-fragment order ----
  for (int c = tid; c < 1024; c += 256) {
    int r = c >> 4, c8 = (c & 15) * 8;
    u16x8 vq = *(const u16x8*)(qb + base + (long)r * 512 + c8);
    u16x8 vk = *(const u16x8*)(kb + base + (long)r * 512 + c8);
    u16x8 vv = *(const u16x8*)(vb + base + (long)r * 512 + c8);
    *(u16x8*)(Qs + r * 136 + c8) = vq;
    *(u16x8*)(Ks + r * 136 + c8) = vk;
    int kt = r >> 5, q4t = (r >> 3) & 3, e = r & 7;
    int nt = c8 >> 4, rb = c8 & 15;
    int vbase = (nt * 2 + kt) * 520 + (q4t * 16 + rb) * 8 + e;
#pragma unroll
    for (int z = 0; z < 8; ++z) Vb[vbase + z * 8] = vv[z];
  }
  __syncthreads();

  // ---- QK^T: wave w owns rows m0..m0+15 ----
  const int m0 = w * 16;
  f32x4 accS[4] = {};
#pragma unroll
  for (int k0 = 0; k0 < 128; k0 += 32) {
    bf16x8 av = *(const bf16x8*)(Qs + (m0 + r16) * 136 + k0 + q4 * 8);
#pragma unroll
    for (int j = 0; j < 4; ++j) {
      bf16x8 bvf = *(const bf16x8*)(Ks + (j * 16 + r16) * 136 + k0 + q4 * 8);
      accS[j] = __builtin_amdgcn_mfma_f32_16x16x32_bf16(av, bvf, accS[j], 0, 0, 0);
    }
  }
  __syncthreads();  // all Ks reads done before ss overlay
  const float scale = 0.08838834764831845f;  // 1/sqrt(128)
#pragma unroll
  for (int j = 0; j < 4; ++j)
#pragma unroll
    for (int r = 0; r < 4; ++r)
      ss[(m0 + q4 * 4 + r) * 66 + j * 16 + r16] = accS[j][r] * scale;
  __syncthreads();

  // ---- softmax: 4 threads per row ----
  {
    int r = tid >> 2, p = tid & 3;
    float* row = ss + r * 66 + p * 16;
    float mx = -3.0e38f;
#pragma unroll
    for (int c2 = 0; c2 < 16; ++c2) mx = fmaxf(mx, row[c2]);
    red[r * 4 + p] = mx;
    __syncthreads();
    float m4 = fmaxf(fmaxf(red[r * 4], red[r * 4 + 1]),
                     fmaxf(red[r * 4 + 2], red[r * 4 + 3]));
    float s = 0.f;
#pragma unroll
    for (int c2 = 0; c2 < 16; ++c2) {
      float e = expf(row[c2] - m4);
      row[c2] = e;
      s += e;
    }
    red[256 + r * 4 + p] = s;
    __syncthreads();
    float inv = 1.f / (red[256 + r * 4] + red[256 + r * 4 + 1] +
                       red[256 + r * 4 + 2] + red[256 + r * 4 + 3]);
    u16x8 o0, o1;
#pragma unroll
    for (int z = 0; z < 8; ++z) {
      o0[z] = f2bf(row[z] * inv);
      o1[z] = f2bf(row[8 + z] * inv);
    }
    *(u16x8*)(ps + r * 72 + p * 16) = o0;      // ps overlays Qs (dead)
    *(u16x8*)(ps + r * 72 + p * 16 + 8) = o1;
  }
  __syncthreads();

  // ---- PV: O[m0..m0+15][128] ----
  bf16x8 av0 = *(const bf16x8*)(ps + (m0 + r16) * 72 + q4 * 8);
  bf16x8 av1 = *(const bf16x8*)(ps + (m0 + r16) * 72 + 32 + q4 * 8);
#pragma unroll
  for (int nt = 0; nt < 8; ++nt) {
    f32x4 accO = {};
    bf16x8 bv0 = *(const bf16x8*)(Vb + (nt * 2 + 0) * 520 + lane * 8);
    bf16x8 bv1 = *(const bf16x8*)(Vb + (nt * 2 + 1) * 520 + lane * 8);
    accO = __builtin_amdgcn_mfma_f32_16x16x32_bf16(av0, bv0, accO, 0, 0, 0);
    accO = __builtin_amdgcn_mfma_f32_16x16x32_bf16(av1, bv1, accO, 0, 0, 0);
    int d = nt * 16 + r16;
#pragma unroll
    for (int r = 0; r < 4; ++r) {
      int i = m0 + q4 * 4 + r;
      qb[base + (long)i * 512 + d] = f2bf(accO[r]);
    }
  }
}

// ---------------- local = emb + hmean (in-place over embh) ----------------
__global__ __launch_bounds__(256) void local_kernel(u16* __restrict__ embh,
                                                    const u16* __restrict__ hmeanB) {
  long t = (long)blockIdx.x * 256 + threadIdx.x;  // < 33554432
  long m = t >> 9;
  int d = (int)(t & 511);
  int bn = (int)(m >> 6);
  embh[t] = f2bf(bf2f(hmeanB[(long)bn * 512 + d]) + bf2f(embh[t]));
}

// ---------------- concat-K NT GEMM: C = gelu([A1|A2] @ Wg1T^T + bias) ----------------
__global__ __launch_bounds__(256) void gemm_cat(const u16* __restrict__ A1,
                                                const u16* __restrict__ A2,
                                                const u16* __restrict__ Bt,
                                                const float* __restrict__ bias,
                                                u16* __restrict__ C) {
  __shared__ __align__(16) u16 As[128 * 32];
  __shared__ __align__(16) u16 Bs[128 * 32];
  const int tid = threadIdx.x;
  const long bm = (long)blockIdx.x * 128;
  const long bnn = (long)blockIdx.y * 128;
  const int lane = tid & 63;
  const int wid = tid >> 6;
  const int wm = (wid & 1) * 64;
  const int wn = (wid >> 1) * 64;
  const int r16 = lane & 15;
  const int q4 = lane >> 4;

  f32x4 acc[4][4] = {};

  const int row0 = tid >> 2;
  const int cg = (tid & 3) * 8;
  const int row1 = row0 + 64;
  const u16* a10 = A1 + (bm + row0) * 512 + cg;
  const u16* a11 = A1 + (bm + row1) * 512 + cg;
  const u16* a20 = A2 + (bm + row0) * 512 + cg;
  const u16* a21 = A2 + (bm + row1) * 512 + cg;
  const u16* b0 = Bt + (bnn + row0) * 1024 + cg;
  const u16* b1 = Bt + (bnn + row1) * 1024 + cg;

  for (int k0 = 0; k0 < 1024; k0 += 32) {
    if (k0 < 512) {
      gload_lds16(a10 + k0, As + tid * 8);
      gload_lds16(a11 + k0, As + (tid + 256) * 8);
    } else {
      gload_lds16(a20 + (k0 - 512), As + tid * 8);
      gload_lds16(a21 + (k0 - 512), As + (tid + 256) * 8);
    }
    gload_lds16(b0 + k0, Bs + tid * 8);
    gload_lds16(b1 + k0, Bs + (tid + 256) * 8);
    __syncthreads();
    bf16x8 av[4], bv[4];
#pragma unroll
    for (int i = 0; i < 4; ++i)
      av[i] = *reinterpret_cast<const bf16x8*>(As + (wm + i * 16 + r16) * 32 + q4 * 8);
#pragma unroll
    for (int j = 0; j < 4; ++j)
      bv[j] = *reinterpret_cast<const bf16x8*>(Bs + (wn + j * 16 + r16) * 32 + q4 * 8);
#pragma unroll
    for (int i = 0; i < 4; ++i)
#pragma unroll
      for (int j = 0; j < 4; ++j)
        acc[i][j] = __builtin_amdgcn_mfma_f32_16x16x32_bf16(av[i], bv[j], acc[i][j], 0, 0, 0);
    __syncthreads();
  }

#pragma unroll
  for (int i = 0; i < 4; ++i)
#pragma unroll
    for (int j = 0; j < 4; ++j)
#pragma unroll
      for (int r = 0; r < 4; ++r) {
        long grow = bm + wm + i * 16 + q4 * 4 + r;
        int gcol = (int)bnn + wn + j * 16 + r16;
        float v = acc[i][j][r] + bias[gcol];
        C[grow * 512 + gcol] = f2bf(gelu_f(v));
      }
}

// ---------------- gate logits + softmax(2) ----------------
__global__ __launch_bounds__(256) void g2_kernel(const u16* __restrict__ h1b,
                                                 const float* __restrict__ W_g2,
                                                 const float* __restrict__ b_g2,
                                                 float* __restrict__ gatel) {
  int m = blockIdx.x * 4 + (threadIdx.x >> 6);
  int lane = threadIdx.x & 63;
  const u16* row = h1b + (long)m * 512;
  float a0 = 0.f, a1 = 0.f;
  for (int i = lane; i < 512; i += 64) {
    float h = bf2f(row[i]);
    a0 += h * W_g2[i * 2];
    a1 += h * W_g2[i * 2 + 1];
  }
  for (int off = 32; off; off >>= 1) {
    a0 += __shfl_down(a0, off);
    a1 += __shfl_down(a1, off);
  }
  if (lane == 0) {
    a0 += b_g2[0];
    a1 += b_g2[1];
    float mx = fmaxf(a0, a1);
    float e0 = expf(a0 - mx), e1 = expf(a1 - mx);
    float inv = 1.f / (e0 + e1);
    gatel[(long)m * 2] = e0 * inv;
    gatel[(long)m * 2 + 1] = e1 * inv;
  }
}

// ---------------- mem = g0*local + g1*glob ----------------
__global__ __launch_bounds__(256) void memc_kernel(const u16* __restrict__ localB,
                                                   const u16* __restrict__ globB,
                                                   const float* __restrict__ gatel,
                                                   u16* __restrict__ memB) {
  long t = (long)blockIdx.x * 256 + threadIdx.x;  // < 33554432
  long m = t >> 9;
  float loc = bf2f(localB[t]);
  float gl = bf2f(globB[t]);
  float g0 = gatel[m * 2], g1 = gatel[m * 2 + 1];
  memB[t] = f2bf(g0 * loc + g1 * gl);
}

// ---------------- fusion head + denorm + transpose store (f32) ----------------
__global__ __launch_bounds__(256) void fusion_kernel(const float* __restrict__ mh,
                                                     const float* __restrict__ b_h,
                                                     const float* __restrict__ W_f1,
                                                     const float* __restrict__ b_f1,
                                                     const float* __restrict__ W_f2,
                                                     const float* __restrict__ b_f2,
                                                     const float* __restrict__ meanv,
                                                     const float* __restrict__ stdv,
                                                     float* __restrict__ out) {
  int bn = blockIdx.x;
  int tid = threadIdx.x;
  __shared__ float mrow[192];
  __shared__ float h1[384];
  if (tid < 192) mrow[tid] = mh[(long)bn * 192 + tid] + b_h[tid];
  __syncthreads();
  for (int j = tid; j < 384; j += 256) {
    float a = b_f1[j];
    for (int i = 0; i < 192; ++i) a += mrow[i] * W_f1[i * 384 + j];
    h1[j] = gelu_f(a);
  }
  __syncthreads();
  if (tid < 192) {
    float a = b_f2[tid];
    for (int j = 0; j < 384; ++j) a += h1[j] * W_f2[j * 192 + tid];
    float o = gelu_f(a) + mrow[tid];
    int b = bn >> 6, v = bn & 63;
    out[((long)b * 192 + tid) * 64 + v] = o * stdv[bn] + meanv[bn];
  }
}

extern "C" void kernel_launch(void* const* d_in, const int* in_sizes, int n_in,
                              void* d_out, int out_size, void* d_ws, size_t ws_size,
                              hipStream_t stream) {
  (void)in_sizes; (void)n_in; (void)out_size; (void)d_ws; (void)ws_size;
  const float* x_enc = (const float*)d_in[0];
  const float* W_val = (const float*)d_in[1];
  const float* mem_bank = (const float*)d_in[2];
  const float* W_m1 = (const float*)d_in[3];
  const float* b_m1 = (const float*)d_in[4];
  const float* W_m2 = (const float*)d_in[5];
  const float* b_m2 = (const float*)d_in[6];
  const float* W_q = (const float*)d_in[7];
  const float* b_q = (const float*)d_in[8];
  const float* W_k = (const float*)d_in[9];
  const float* b_k = (const float*)d_in[10];
  const float* W_v = (const float*)d_in[11];
  const float* b_v = (const float*)d_in[12];
  const float* W_o = (const float*)d_in[13];
  const float* b_o = (const float*)d_in[14];
  const float* W_g1 = (const float*)d_in[15];
  const float* b_g1 = (const float*)d_in[16];
  const float* W_g2 = (const float*)d_in[17];
  const float* b_g2 = (const float*)d_in[18];
  const float* W_h = (const float*)d_in[19];
  const float* b_h = (const float*)d_in[20];
  const float* W_f1 = (const float*)d_in[21];
  const float* b_f1 = (const float*)d_in[22];
  const float* W_f2 = (const float*)d_in[23];
  const float* b_f2 = (const float*)d_in[24];

  void* sp = nullptr;
  hipGetSymbolAddress(&sp, HIP_SYMBOL(g_s));
  Scratch* S = (Scratch*)sp;
  u16* qsC = S->vb;                                  // 3 MB
  float* simB = (float*)S->qb;                       // 32 MB
  u16* retrB = S->kb;                                // 8 MB
  u16* hiddenB = S->kb + (size_t)4 * 1024 * 1024;    // 16 MB

  // setup
  pos_kernel<<<64, 256, 0, stream>>>(S->POSb);
  stats_kernel<<<16, 256, 0, stream>>>(x_enc, S->meanv, S->stdv);
  zerof_kernel<<<768, 256, 0, stream>>>(S->mh, 1024 * 192);
  zerou_kernel<<<8192, 256, 0, stream>>>(S->WhT + (size_t)192 * 32768, 64 * 32768);
  transpose_kernel<<<dim3(16, 16), 256, 0, stream>>>(W_q, S->WqT, 512, 512);
  transpose_kernel<<<dim3(16, 16), 256, 0, stream>>>(W_k, S->WkT, 512, 512);
  transpose_kernel<<<dim3(16, 16), 256, 0, stream>>>(W_v, S->WvT, 512, 512);
  transpose_kernel<<<dim3(16, 16), 256, 0, stream>>>(W_o, S->WoT, 512, 512);
  transpose_kernel<<<dim3(32, 16), 256, 0, stream>>>(W_m1, S->Wm1T, 512, 1024);
  transpose_kernel<<<dim3(16, 32), 256, 0, stream>>>(W_m2, S->Wm2T, 1024, 512);
  transpose_kernel<<<dim3(16, 32), 256, 0, stream>>>(W_g1, S->Wg1T, 1024, 512);
  transpose_kernel<<<dim3(6, 1024), 256, 0, stream>>>(W_h, S->WhT, 32768, 192);
  memdup_kernel<<<16384, 256, 0, stream>>>(mem_bank, S->memdupB);

  // embedding
  emb_kernel<<<1024, 256, 0, stream>>>(x_enc, W_val, S->POSb, S->meanv, S->stdv,
                                       S->embh, S->qflat);
  // retrieval
  qsplit_kernel<<<2048, 256, 0, stream>>>(S->qflat, qsC);
  gemm_nt<3><<<dim3(8, 64), 256, 0, stream>>>(qsC, S->memdupB, nullptr, simB,
                                              1536, 1536, 1536, 8192, 8192);
  topk_kernel<<<1024, 256, 0, stream>>>(simB, S->idxB);
  gather_kernel<<<2048, 256, 0, stream>>>(mem_bank, S->idxB, retrB);
  gemm_nt<1><<<dim3(64, 8), 256, 0, stream>>>(retrB, S->Wm1T, b_m1, hiddenB,
                                              512, 512, 512, 1024, 1024);
  gmean_kernel<<<4096, 256, 0, stream>>>(hiddenB, S->gmeanB);
  gemm_nt<0><<<dim3(8, 4), 256, 0, stream>>>(S->gmeanB, S->Wm2T, b_m2, S->hmeanB,
                                             1024, 1024, 1024, 512, 512);
  // QKV (M = 65536)
  gemm_nt<0><<<dim3(512, 4), 256, 0, stream>>>(S->embh, S->WqT, b_q, S->qb,
                                               512, 512, 512, 512, 512);
  gemm_nt<0><<<dim3(512, 4), 256, 0, stream>>>(S->embh, S->WkT, b_k, S->kb,
                                               512, 512, 512, 512, 512);
  gemm_nt<0><<<dim3(512, 4), 256, 0, stream>>>(S->embh, S->WvT, b_v, S->vb,
                                               512, 512, 512, 512, 512);
  // local = emb + hmean (in place; QKV consumed emb)
  local_kernel<<<131072, 256, 0, stream>>>(S->embh, S->hmeanB);
  // attention (atto over qb)
  attn_kernel<<<dim3(1024, 4), 256, 0, stream>>>(S->qb, S->kb, S->vb);
  // glob = atto @ W_o + b_o -> kb
  gemm_nt<0><<<dim3(512, 4), 256, 0, stream>>>(S->qb, S->WoT, b_o, S->kb,
                                               512, 512, 512, 512, 512);
  // h1 = gelu([local|glob] @ W_g1 + b_g1) -> vb
  gemm_cat<<<dim3(512, 4), 256, 0, stream>>>(S->embh, S->kb, S->Wg1T, b_g1, S->vb);
  g2_kernel<<<16384, 256, 0, stream>>>(S->vb, W_g2, b_g2, S->gatel);
  // mem = g0*local + g1*glob -> qb
  memc_kernel<<<131072, 256, 0, stream>>>(S->embh, S->kb, S->gatel, S->qb);
  // mh = mem_flat [1024,32768] @ WhT^T, split-K x16, f32 atomics
  gemm_nt<2><<<dim3(8, 2, 16), 256, 0, stream>>>(S->qb, S->WhT, nullptr, S->mh,
                                                 32768, 32768, 2048, 192, 192);
  fusion_kernel<<<1024, 256, 0, stream>>>(S->mh, b_h, W_f1, b_f1, W_f2, b_f2,
                                          S->meanv, S->stdv, (float*)d_out);
}

// Round 8
// 1128.877 us; speedup vs baseline: 5.2080x; 1.1311x over previous
//
#include <hip/hip_runtime.h>
#include <stdint.h>

#define DEV __device__ __forceinline__

typedef uint16_t u16;
typedef __bf16 bf16x8 __attribute__((ext_vector_type(8)));
typedef float f32x4 __attribute__((ext_vector_type(4)));
typedef u16 u16x8 __attribute__((ext_vector_type(8)));
typedef u16 u16x4 __attribute__((ext_vector_type(4)));

DEV float bf2f(u16 v) { return __uint_as_float(((uint32_t)v) << 16); }
DEV u16 f2bf(float f) {
  uint32_t u = __float_as_uint(f);
  u += 0x7fffu + ((u >> 16) & 1u);
  return (u16)(u >> 16);
}
DEV float gelu_f(float x) { return 0.5f * x * (1.0f + erff(x * 0.7071067811865475f)); }

DEV void gload_lds16(const u16* g, u16* l) {
  __builtin_amdgcn_global_load_lds(
      (const __attribute__((address_space(1))) void*)g,
      (__attribute__((address_space(3))) void*)l, 16, 0, 0);
}

// ---- all scratch in a static device global (R4: never trust ws_size) ----
struct __align__(16) Scratch {
  float POSb[64 * 512];
  float meanv[1024];
  float stdv[1024];
  float mh[1024 * 192];
  int idxB[8192];
  float qflat[1024 * 512];
  float gatel[65536 * 2];
  u16 hmeanB[1024 * 512];
  u16 gmeanB[1024 * 1024];
  u16 WqT[512 * 512];
  u16 WkT[512 * 512];
  u16 WvT[512 * 512];
  u16 WoT[512 * 512];
  u16 Wm1T[1024 * 512];
  u16 Wm2T[512 * 1024];
  u16 Wg1T[512 * 1024];
  u16 WhT[256 * 32768];        // rows 192..255 zero-filled
  u16 memdupB[8192 * 1536];    // [mh|mh|ml] 24 MB
  u16 embh[65536 * 512];       // 64 MB (becomes `local` in place)
  u16 qb[65536 * 512];         // 64 MB (sim phase: simB f32 alias)
  u16 kb[65536 * 512];         // 64 MB (sim phase: retrB + hiddenB alias)
  u16 vb[65536 * 512];         // 64 MB (sim phase: qsC alias)
};
__device__ Scratch g_s;

// ---------------- fills ----------------
__global__ __launch_bounds__(256) void zerof_kernel(float* __restrict__ p, int n) {
  int t = blockIdx.x * 256 + threadIdx.x;
  if (t < n) p[t] = 0.f;
}
__global__ __launch_bounds__(256) void zerou_kernel(u16* __restrict__ p, int n) {
  int t = blockIdx.x * 256 + threadIdx.x;
  if (t < n) p[t] = 0;
}

// ---------------- POS embedding ----------------
__global__ __launch_bounds__(256) void pos_kernel(float* __restrict__ POS) {
  int n = blockIdx.x;
  int i = threadIdx.x;
  float div = expf((float)(2 * i) * (-9.210340371976184f / 512.0f));
  float arg = (float)n * div;
  POS[n * 512 + 2 * i] = sinf(arg);
  POS[n * 512 + 2 * i + 1] = cosf(arg);
}

// ---------------- instance-norm stats ----------------
__global__ __launch_bounds__(256) void stats_kernel(const float* __restrict__ x_enc,
                                                    float* __restrict__ meanv,
                                                    float* __restrict__ stdv) {
  int b = blockIdx.x;
  int v = threadIdx.x & 63;
  int g = threadIdx.x >> 6;
  float s = 0.f, s2 = 0.f;
  for (int l = g; l < 512; l += 4) {
    float x = x_enc[((long)b * 512 + l) * 64 + v];
    s += x; s2 += x * x;
  }
  __shared__ float sh[2][4][64];
  sh[0][g][v] = s; sh[1][g][v] = s2;
  __syncthreads();
  if (g == 0) {
    s = sh[0][0][v] + sh[0][1][v] + sh[0][2][v] + sh[0][3][v];
    s2 = sh[1][0][v] + sh[1][1][v] + sh[1][2][v] + sh[1][3][v];
    float mu = s * (1.f / 512.f);
    float var = s2 * (1.f / 512.f) - mu * mu;
    meanv[b * 64 + v] = mu;
    stdv[b * 64 + v] = sqrtf(var + 1e-5f) * 2.5f;  // sqrt(var+eps)/0.4
  }
}

// ---------------- transpose f32 [R,C] -> bf16 [C,R] ----------------
__global__ __launch_bounds__(256) void transpose_kernel(const float* __restrict__ in,
                                                        u16* __restrict__ out, int R, int C) {
  __shared__ u16 t[32][33];
  int bx = blockIdx.x * 32;
  int by = blockIdx.y * 32;
  int tx = threadIdx.x & 31, ty = threadIdx.x >> 5;
  for (int i = ty; i < 32; i += 8) t[i][tx] = f2bf(in[(long)(by + i) * C + bx + tx]);
  __syncthreads();
  for (int i = ty; i < 32; i += 8) out[(long)(bx + i) * R + by + tx] = t[tx][i];
}

// ---------------- patch embed + qflat ----------------
__global__ __launch_bounds__(256) void emb_kernel(const float* __restrict__ x_enc,
                                                  const float* __restrict__ W_val,
                                                  const float* __restrict__ POS,
                                                  const float* __restrict__ meanv,
                                                  const float* __restrict__ stdv,
                                                  u16* __restrict__ embh,
                                                  float* __restrict__ qflat) {
  int bn = blockIdx.x;
  int b = bn >> 6, v = bn & 63;
  int tid = threadIdx.x;
  __shared__ __align__(16) float wv[16 * 512];
  __shared__ __align__(16) float pt[64 * 16];
  for (int i = tid; i < 8192; i += 256) wv[i] = W_val[i];
  float mu = meanv[bn];
  float inv = 1.f / stdv[bn];
  for (int i = tid; i < 1024; i += 256) {
    int n = i >> 4, p = i & 15;
    int l = n * 8 + p; if (l > 511) l = 511;  // replication pad
    pt[i] = (x_enc[((long)b * 512 + l) * 64 + v] - mu) * inv;
  }
  __syncthreads();
  float qs0 = 0.f, qs1 = 0.f;
  int d0 = tid, d1 = tid + 256;
  for (int n = 0; n < 64; ++n) {
    float a0 = POS[n * 512 + d0], a1 = POS[n * 512 + d1];
#pragma unroll
    for (int p = 0; p < 16; ++p) {
      float pv = pt[n * 16 + p];
      a0 += pv * wv[p * 512 + d0];
      a1 += pv * wv[p * 512 + d1];
    }
    long base = ((long)bn * 64 + n) * 512;
    embh[base + d0] = f2bf(a0);
    embh[base + d1] = f2bf(a1);
    qs0 += a0; qs1 += a1;
  }
  qflat[(long)bn * 512 + d0] = qs0 * (1.f / 64.f);
  qflat[(long)bn * 512 + d1] = qs1 * (1.f / 64.f);
}

// ---------------- qflat f32 -> [qh|ql|qh] bf16 row of 1536 ----------------
__global__ __launch_bounds__(256) void qsplit_kernel(const float* __restrict__ qflat,
                                                     u16* __restrict__ qsC) {
  int t = blockIdx.x * 256 + threadIdx.x;  // < 524288
  int bn = t >> 9, d = t & 511;
  float q = qflat[t];
  u16 hi = f2bf(q);
  u16 lo = f2bf(q - bf2f(hi));
  long base = (long)bn * 1536;
  qsC[base + d] = hi;
  qsC[base + 512 + d] = lo;
  qsC[base + 1024 + d] = hi;
}

// ---------------- mem_bank f32 -> [mh|mh|ml] bf16 row of 1536 ----------------
__global__ __launch_bounds__(256) void memdup_kernel(const float* __restrict__ mb,
                                                     u16* __restrict__ md) {
  int t = blockIdx.x * 256 + threadIdx.x;  // < 4194304
  int n = t >> 9, k = t & 511;
  float m = mb[t];
  u16 hi = f2bf(m);
  u16 lo = f2bf(m - bf2f(hi));
  long base = (long)n * 1536;
  md[base + k] = hi;
  md[base + 512 + k] = hi;
  md[base + 1024 + k] = lo;
}

// ---------------- NT MFMA GEMM: BK=64, xor-swizzled LDS (conflict-free frags) ------
// LDS chunk cid (16 B) holds tile row r=cid>>3, k-group g=(cid&7)^(r&7).
// EPI: 0 bias+bf16 | 1 bias+gelu+bf16 | 2 f32 atomicAdd | 3 f32 store
template <int EPI>
__global__ __launch_bounds__(256) void gemm_nt(const u16* __restrict__ Ag,
                                               const u16* __restrict__ Bt,
                                               const float* __restrict__ bias,
                                               void* __restrict__ C,
                                               int lda, int ldb, int K, int Nreal, int ldc) {
  __shared__ __align__(16) u16 As[128 * 64];
  __shared__ __align__(16) u16 Bs[128 * 64];
  const int tid = threadIdx.x;
  const long bm = (long)blockIdx.x * 128;
  const long bnn = (long)blockIdx.y * 128;
  const long koff = (long)blockIdx.z * K;
  const int lane = tid & 63;
  const int w = tid >> 6;
  const int wm = (w & 1) * 64;
  const int wn = (w >> 1) * 64;
  const int r16 = lane & 15;
  const int q4 = lane >> 4;

  f32x4 acc[4][4] = {};

  const u16* ap[4];
  const u16* bp[4];
  u16* al[4];
  u16* bl[4];
#pragma unroll
  for (int j = 0; j < 4; ++j) {
    int cid = (j * 4 + w) * 64 + lane;
    int r = cid >> 3;
    int g = (cid & 7) ^ (r & 7);
    ap[j] = Ag + (bm + r) * lda + koff + g * 8;
    bp[j] = Bt + (bnn + r) * ldb + koff + g * 8;
    al[j] = As + cid * 8;
    bl[j] = Bs + cid * 8;
  }

  for (int k0 = 0; k0 < K; k0 += 64) {
#pragma unroll
    for (int j = 0; j < 4; ++j) gload_lds16(ap[j] + k0, al[j]);
#pragma unroll
    for (int j = 0; j < 4; ++j) gload_lds16(bp[j] + k0, bl[j]);
    __syncthreads();
#pragma unroll
    for (int sub = 0; sub < 2; ++sub) {
      const int gg = q4 + sub * 4;
      bf16x8 av[4], bv[4];
#pragma unroll
      for (int i = 0; i < 4; ++i) {
        int r = wm + i * 16 + r16;
        av[i] = *reinterpret_cast<const bf16x8*>(As + (r * 8 + (gg ^ (r & 7))) * 8);
      }
#pragma unroll
      for (int j2 = 0; j2 < 4; ++j2) {
        int r = wn + j2 * 16 + r16;
        bv[j2] = *reinterpret_cast<const bf16x8*>(Bs + (r * 8 + (gg ^ (r & 7))) * 8);
      }
#pragma unroll
      for (int i = 0; i < 4; ++i)
#pragma unroll
        for (int j2 = 0; j2 < 4; ++j2)
          acc[i][j2] = __builtin_amdgcn_mfma_f32_16x16x32_bf16(av[i], bv[j2], acc[i][j2], 0, 0, 0);
    }
    __syncthreads();
  }

#pragma unroll
  for (int i = 0; i < 4; ++i)
#pragma unroll
    for (int j = 0; j < 4; ++j)
#pragma unroll
      for (int r = 0; r < 4; ++r) {
        long grow = bm + wm + i * 16 + q4 * 4 + r;
        int gcol = (int)bnn + wn + j * 16 + r16;
        float v = acc[i][j][r];
        if (gcol < Nreal) {
          if (EPI == 0 || EPI == 1) {
            v += bias[gcol];
            if (EPI == 1) v = gelu_f(v);
            ((u16*)C)[grow * ldc + gcol] = f2bf(v);
          } else if (EPI == 2) {
            atomicAdd((float*)C + grow * ldc + gcol, v);
          } else {
            ((float*)C)[grow * ldc + gcol] = v;
          }
        }
      }
}

// ---------------- top-8 per row, parallel tree merge ----------------
DEV bool better(float v1, int i1, float v2, int i2) {
  return v1 > v2 || (v1 == v2 && i1 < i2);
}
__global__ __launch_bounds__(256) void topk_kernel(const float* __restrict__ sim,
                                                   int* __restrict__ idxout) {
  const int bn = blockIdx.x;
  const int tid = threadIdx.x;
  const float* row = sim + (long)bn * 8192;
  float bv[8]; int bi[8];
#pragma unroll
  for (int r = 0; r < 8; ++r) { bv[r] = -3.0e38f; bi[r] = 0x7fffffff; }
  for (int n = tid; n < 8192; n += 256) {
    float v = row[n];
    if (better(v, n, bv[7], bi[7])) {
      bv[7] = v; bi[7] = n;
      for (int r = 7; r > 0; --r) {
        if (!better(bv[r], bi[r], bv[r - 1], bi[r - 1])) break;
        float tv = bv[r]; bv[r] = bv[r - 1]; bv[r - 1] = tv;
        int ti = bi[r]; bi[r] = bi[r - 1]; bi[r - 1] = ti;
      }
    }
  }
  __shared__ float lv[256 * 8];
  __shared__ int li[256 * 8];
#pragma unroll
  for (int r = 0; r < 8; ++r) { lv[tid * 8 + r] = bv[r]; li[tid * 8 + r] = bi[r]; }
  __syncthreads();
  for (int step = 128; step >= 1; step >>= 1) {
    if (tid < step) {
      float av[8], xv[8]; int ai[8], xi[8];
#pragma unroll
      for (int r = 0; r < 8; ++r) {
        av[r] = lv[tid * 8 + r]; ai[r] = li[tid * 8 + r];
        xv[r] = lv[(tid + step) * 8 + r]; xi[r] = li[(tid + step) * 8 + r];
      }
      int ia = 0, ib = 0;
      float mv[8]; int mi[8];
#pragma unroll
      for (int r = 0; r < 8; ++r) {
        if (better(av[ia], ai[ia], xv[ib], xi[ib])) { mv[r] = av[ia]; mi[r] = ai[ia]; ++ia; }
        else { mv[r] = xv[ib]; mi[r] = xi[ib]; ++ib; }
      }
#pragma unroll
      for (int r = 0; r < 8; ++r) { lv[tid * 8 + r] = mv[r]; li[tid * 8 + r] = mi[r]; }
    }
    __syncthreads();
  }
  if (tid < 8) idxout[bn * 8 + tid] = li[tid];
}

// ---------------- gather retrieved rows, f32 -> bf16, clamped ----------------
__global__ __launch_bounds__(256) void gather_kernel(const float* __restrict__ mb,
                                                     const int* __restrict__ idx,
                                                     u16* __restrict__ retrB) {
  int t = blockIdx.x * 256 + threadIdx.x;  // < 524288
  int m = t >> 6;
  int c8 = (t & 63) * 8;
  long r = idx[m];
  if (r < 0) r = 0;
  if (r > 8191) r = 8191;
  const float* src = mb + r * 512 + c8;
  u16* dst = retrB + (long)m * 512 + c8;
#pragma unroll
  for (int z = 0; z < 8; ++z) dst[z] = f2bf(src[z]);
}

// ---------------- mean over K of gelu-hidden -> bf16 ----------------
__global__ __launch_bounds__(256) void gmean_kernel(const u16* __restrict__ hid,
                                                    u16* __restrict__ gmeanB) {
  int t = blockIdx.x * 256 + threadIdx.x;  // < 1048576
  int bn = t >> 10, j = t & 1023;
  float s = 0.f;
#pragma unroll
  for (int k = 0; k < 8; ++k) s += bf2f(hid[(long)(bn * 8 + k) * 1024 + j]);
  gmeanB[t] = f2bf(s * 0.125f);
}

// ---------------- MFMA attention: one block per (bn, head); atto over q ----------------
__global__ __launch_bounds__(256) void attn_kernel(u16* __restrict__ qb,
                                                   const u16* __restrict__ kb,
                                                   const u16* __restrict__ vb) {
  __shared__ __align__(16) u16 smem[26752];
  u16* Qs = smem;
  u16* Ks = smem + 8704;              // 17408 B / 2
  float* ss = (float*)(smem + 8704);  // overlay Ks
  u16* ps = smem;                     // overlay Qs
  u16* Vb = smem + 17408;             // 34816 B / 2
  float* red = (float*)(smem + 25728);// 51456 B / 2
  const int bn = blockIdx.x, h = blockIdx.y;
  const int tid = threadIdx.x;
  const int lane = tid & 63, w = tid >> 6;
  const int r16 = lane & 15, q4 = lane >> 4;
  const long base = (long)bn * 64 * 512 + h * 128;

  for (int c = tid; c < 1024; c += 256) {
    int r = c >> 4, c8 = (c & 15) * 8;
    u16x8 vq = *(const u16x8*)(qb + base + (long)r * 512 + c8);
    u16x8 vk = *(const u16x8*)(kb + base + (long)r * 512 + c8);
    u16x8 vv = *(const u16x8*)(vb + base + (long)r * 512 + c8);
    *(u16x8*)(Qs + r * 136 + c8) = vq;
    *(u16x8*)(Ks + r * 136 + c8) = vk;
    int kt = r >> 5, q4t = (r >> 3) & 3, e = r & 7;
    int nt = c8 >> 4, rb = c8 & 15;
    int vbase = (nt * 2 + kt) * 520 + (q4t * 16 + rb) * 8 + e;
#pragma unroll
    for (int z = 0; z < 8; ++z) Vb[vbase + z * 8] = vv[z];
  }
  __syncthreads();

  const int m0 = w * 16;
  f32x4 accS[4] = {};
#pragma unroll
  for (int k0 = 0; k0 < 128; k0 += 32) {
    bf16x8 av = *(const bf16x8*)(Qs + (m0 + r16) * 136 + k0 + q4 * 8);
#pragma unroll
    for (int j = 0; j < 4; ++j) {
      bf16x8 bvf = *(const bf16x8*)(Ks + (j * 16 + r16) * 136 + k0 + q4 * 8);
      accS[j] = __builtin_amdgcn_mfma_f32_16x16x32_bf16(av, bvf, accS[j], 0, 0, 0);
    }
  }
  __syncthreads();
  const float scale = 0.08838834764831845f;  // 1/sqrt(128)
#pragma unroll
  for (int j = 0; j < 4; ++j)
#pragma unroll
    for (int r = 0; r < 4; ++r)
      ss[(m0 + q4 * 4 + r) * 66 + j * 16 + r16] = accS[j][r] * scale;
  __syncthreads();

  {
    int r = tid >> 2, p = tid & 3;
    float* row = ss + r * 66 + p * 16;
    float mx = -3.0e38f;
#pragma unroll
    for (int c2 = 0; c2 < 16; ++c2) mx = fmaxf(mx, row[c2]);
    red[r * 4 + p] = mx;
    __syncthreads();
    float m4 = fmaxf(fmaxf(red[r * 4], red[r * 4 + 1]),
                     fmaxf(red[r * 4 + 2], red[r * 4 + 3]));
    float s = 0.f;
#pragma unroll
    for (int c2 = 0; c2 < 16; ++c2) {
      float e = expf(row[c2] - m4);
      row[c2] = e;
      s += e;
    }
    red[256 + r * 4 + p] = s;
    __syncthreads();
    float inv = 1.f / (red[256 + r * 4] + red[256 + r * 4 + 1] +
                       red[256 + r * 4 + 2] + red[256 + r * 4 + 3]);
    u16x8 o0, o1;
#pragma unroll
    for (int z = 0; z < 8; ++z) {
      o0[z] = f2bf(row[z] * inv);
      o1[z] = f2bf(row[8 + z] * inv);
    }
    *(u16x8*)(ps + r * 72 + p * 16) = o0;
    *(u16x8*)(ps + r * 72 + p * 16 + 8) = o1;
  }
  __syncthreads();

  bf16x8 av0 = *(const bf16x8*)(ps + (m0 + r16) * 72 + q4 * 8);
  bf16x8 av1 = *(const bf16x8*)(ps + (m0 + r16) * 72 + 32 + q4 * 8);
#pragma unroll
  for (int nt = 0; nt < 8; ++nt) {
    f32x4 accO = {};
    bf16x8 bv0 = *(const bf16x8*)(Vb + (nt * 2 + 0) * 520 + lane * 8);
    bf16x8 bv1 = *(const bf16x8*)(Vb + (nt * 2 + 1) * 520 + lane * 8);
    accO = __builtin_amdgcn_mfma_f32_16x16x32_bf16(av0, bv0, accO, 0, 0, 0);
    accO = __builtin_amdgcn_mfma_f32_16x16x32_bf16(av1, bv1, accO, 0, 0, 0);
    int d = nt * 16 + r16;
#pragma unroll
    for (int r = 0; r < 4; ++r) {
      int i = m0 + q4 * 4 + r;
      qb[base + (long)i * 512 + d] = f2bf(accO[r]);
    }
  }
}

// ---------------- local = emb + hmean (in-place over embh) ----------------
__global__ __launch_bounds__(256) void local_kernel(u16* __restrict__ embh,
                                                    const u16* __restrict__ hmeanB) {
  long t = (long)blockIdx.x * 256 + threadIdx.x;  // < 33554432
  long m = t >> 9;
  int d = (int)(t & 511);
  int bn = (int)(m >> 6);
  embh[t] = f2bf(bf2f(hmeanB[(long)bn * 512 + d]) + bf2f(embh[t]));
}

// ---------------- concat-K NT GEMM (BK=64, swizzled): C = gelu([A1|A2] @ Wg1T^T + b) ----
__global__ __launch_bounds__(256) void gemm_cat(const u16* __restrict__ A1,
                                                const u16* __restrict__ A2,
                                                const u16* __restrict__ Bt,
                                                const float* __restrict__ bias,
                                                u16* __restrict__ C) {
  __shared__ __align__(16) u16 As[128 * 64];
  __shared__ __align__(16) u16 Bs[128 * 64];
  const int tid = threadIdx.x;
  const long bm = (long)blockIdx.x * 128;
  const long bnn = (long)blockIdx.y * 128;
  const int lane = tid & 63;
  const int w = tid >> 6;
  const int wm = (w & 1) * 64;
  const int wn = (w >> 1) * 64;
  const int r16 = lane & 15;
  const int q4 = lane >> 4;

  f32x4 acc[4][4] = {};

  const u16* ap1[4];
  const u16* ap2[4];
  const u16* bp[4];
  u16* al[4];
  u16* bl[4];
#pragma unroll
  for (int j = 0; j < 4; ++j) {
    int cid = (j * 4 + w) * 64 + lane;
    int r = cid >> 3;
    int g = (cid & 7) ^ (r & 7);
    ap1[j] = A1 + (bm + r) * 512 + g * 8;
    ap2[j] = A2 + (bm + r) * 512 + g * 8;
    bp[j] = Bt + (bnn + r) * 1024 + g * 8;
    al[j] = As + cid * 8;
    bl[j] = Bs + cid * 8;
  }

  for (int k0 = 0; k0 < 1024; k0 += 64) {
    if (k0 < 512) {
#pragma unroll
      for (int j = 0; j < 4; ++j) gload_lds16(ap1[j] + k0, al[j]);
    } else {
#pragma unroll
      for (int j = 0; j < 4; ++j) gload_lds16(ap2[j] + (k0 - 512), al[j]);
    }
#pragma unroll
    for (int j = 0; j < 4; ++j) gload_lds16(bp[j] + k0, bl[j]);
    __syncthreads();
#pragma unroll
    for (int sub = 0; sub < 2; ++sub) {
      const int gg = q4 + sub * 4;
      bf16x8 av[4], bv[4];
#pragma unroll
      for (int i = 0; i < 4; ++i) {
        int r = wm + i * 16 + r16;
        av[i] = *reinterpret_cast<const bf16x8*>(As + (r * 8 + (gg ^ (r & 7))) * 8);
      }
#pragma unroll
      for (int j2 = 0; j2 < 4; ++j2) {
        int r = wn + j2 * 16 + r16;
        bv[j2] = *reinterpret_cast<const bf16x8*>(Bs + (r * 8 + (gg ^ (r & 7))) * 8);
      }
#pragma unroll
      for (int i = 0; i < 4; ++i)
#pragma unroll
        for (int j2 = 0; j2 < 4; ++j2)
          acc[i][j2] = __builtin_amdgcn_mfma_f32_16x16x32_bf16(av[i], bv[j2], acc[i][j2], 0, 0, 0);
    }
    __syncthreads();
  }

#pragma unroll
  for (int i = 0; i < 4; ++i)
#pragma unroll
    for (int j = 0; j < 4; ++j)
#pragma unroll
      for (int r = 0; r < 4; ++r) {
        long grow = bm + wm + i * 16 + q4 * 4 + r;
        int gcol = (int)bnn + wn + j * 16 + r16;
        float v = acc[i][j][r] + bias[gcol];
        C[grow * 512 + gcol] = f2bf(gelu_f(v));
      }
}

// ---------------- gate logits + softmax(2) ----------------
__global__ __launch_bounds__(256) void g2_kernel(const u16* __restrict__ h1b,
                                                 const float* __restrict__ W_g2,
                                                 const float* __restrict__ b_g2,
                                                 float* __restrict__ gatel) {
  int m = blockIdx.x * 4 + (threadIdx.x >> 6);
  int lane = threadIdx.x & 63;
  const u16* row = h1b + (long)m * 512;
  float a0 = 0.f, a1 = 0.f;
  for (int i = lane; i < 512; i += 64) {
    float h = bf2f(row[i]);
    a0 += h * W_g2[i * 2];
    a1 += h * W_g2[i * 2 + 1];
  }
  for (int off = 32; off; off >>= 1) {
    a0 += __shfl_down(a0, off);
    a1 += __shfl_down(a1, off);
  }
  if (lane == 0) {
    a0 += b_g2[0];
    a1 += b_g2[1];
    float mx = fmaxf(a0, a1);
    float e0 = expf(a0 - mx), e1 = expf(a1 - mx);
    float inv = 1.f / (e0 + e1);
    gatel[(long)m * 2] = e0 * inv;
    gatel[(long)m * 2 + 1] = e1 * inv;
  }
}

// ---------------- mem = g0*local + g1*glob ----------------
__global__ __launch_bounds__(256) void memc_kernel(const u16* __restrict__ localB,
                                                   const u16* __restrict__ globB,
                                                   const float* __restrict__ gatel,
                                                   u16* __restrict__ memB) {
  long t = (long)blockIdx.x * 256 + threadIdx.x;  // < 33554432
  long m = t >> 9;
  float loc = bf2f(localB[t]);
  float gl = bf2f(globB[t]);
  float g0 = gatel[m * 2], g1 = gatel[m * 2 + 1];
  memB[t] = f2bf(g0 * loc + g1 * gl);
}

// ---------------- fusion head + denorm + transpose store (f32) ----------------
__global__ __launch_bounds__(256) void fusion_kernel(const float* __restrict__ mh,
                                                     const float* __restrict__ b_h,
                                                     const float* __restrict__ W_f1,
                                                     const float* __restrict__ b_f1,
                                                     const float* __restrict__ W_f2,
                                                     const float* __restrict__ b_f2,
                                                     const float* __restrict__ meanv,
                                                     const float* __restrict__ stdv,
                                                     float* __restrict__ out) {
  int bn = blockIdx.x;
  int tid = threadIdx.x;
  __shared__ float mrow[192];
  __shared__ float h1[384];
  if (tid < 192) mrow[tid] = mh[(long)bn * 192 + tid] + b_h[tid];
  __syncthreads();
  for (int j = tid; j < 384; j += 256) {
    float a = b_f1[j];
    for (int i = 0; i < 192; ++i) a += mrow[i] * W_f1[i * 384 + j];
    h1[j] = gelu_f(a);
  }
  __syncthreads();
  if (tid < 192) {
    float a = b_f2[tid];
    for (int j = 0; j < 384; ++j) a += h1[j] * W_f2[j * 192 + tid];
    float o = gelu_f(a) + mrow[tid];
    int b = bn >> 6, v = bn & 63;
    out[((long)b * 192 + tid) * 64 + v] = o * stdv[bn] + meanv[bn];
  }
}

extern "C" void kernel_launch(void* const* d_in, const int* in_sizes, int n_in,
                              void* d_out, int out_size, void* d_ws, size_t ws_size,
                              hipStream_t stream) {
  (void)in_sizes; (void)n_in; (void)out_size; (void)d_ws; (void)ws_size;
  const float* x_enc = (const float*)d_in[0];
  const float* W_val = (const float*)d_in[1];
  const float* mem_bank = (const float*)d_in[2];
  const float* W_m1 = (const float*)d_in[3];
  const float* b_m1 = (const float*)d_in[4];
  const float* W_m2 = (const float*)d_in[5];
  const float* b_m2 = (const float*)d_in[6];
  const float* W_q = (const float*)d_in[7];
  const float* b_q = (const float*)d_in[8];
  const float* W_k = (const float*)d_in[9];
  const float* b_k = (const float*)d_in[10];
  const float* W_v = (const float*)d_in[11];
  const float* b_v = (const float*)d_in[12];
  const float* W_o = (const float*)d_in[13];
  const float* b_o = (const float*)d_in[14];
  const float* W_g1 = (const float*)d_in[15];
  const float* b_g1 = (const float*)d_in[16];
  const float* W_g2 = (const float*)d_in[17];
  const float* b_g2 = (const float*)d_in[18];
  const float* W_h = (const float*)d_in[19];
  const float* b_h = (const float*)d_in[20];
  const float* W_f1 = (const float*)d_in[21];
  const float* b_f1 = (const float*)d_in[22];
  const float* W_f2 = (const float*)d_in[23];
  const float* b_f2 = (const float*)d_in[24];

  void* sp = nullptr;
  hipGetSymbolAddress(&sp, HIP_SYMBOL(g_s));
  Scratch* S = (Scratch*)sp;
  u16* qsC = S->vb;
  float* simB = (float*)S->qb;
  u16* retrB = S->kb;
  u16* hiddenB = S->kb + (size_t)4 * 1024 * 1024;

  // setup
  pos_kernel<<<64, 256, 0, stream>>>(S->POSb);
  stats_kernel<<<16, 256, 0, stream>>>(x_enc, S->meanv, S->stdv);
  zerof_kernel<<<768, 256, 0, stream>>>(S->mh, 1024 * 192);
  zerou_kernel<<<8192, 256, 0, stream>>>(S->WhT + (size_t)192 * 32768, 64 * 32768);
  transpose_kernel<<<dim3(16, 16), 256, 0, stream>>>(W_q, S->WqT, 512, 512);
  transpose_kernel<<<dim3(16, 16), 256, 0, stream>>>(W_k, S->WkT, 512, 512);
  transpose_kernel<<<dim3(16, 16), 256, 0, stream>>>(W_v, S->WvT, 512, 512);
  transpose_kernel<<<dim3(16, 16), 256, 0, stream>>>(W_o, S->WoT, 512, 512);
  transpose_kernel<<<dim3(32, 16), 256, 0, stream>>>(W_m1, S->Wm1T, 512, 1024);
  transpose_kernel<<<dim3(16, 32), 256, 0, stream>>>(W_m2, S->Wm2T, 1024, 512);
  transpose_kernel<<<dim3(16, 32), 256, 0, stream>>>(W_g1, S->Wg1T, 1024, 512);
  transpose_kernel<<<dim3(6, 1024), 256, 0, stream>>>(W_h, S->WhT, 32768, 192);
  memdup_kernel<<<16384, 256, 0, stream>>>(mem_bank, S->memdupB);

  // embedding
  emb_kernel<<<1024, 256, 0, stream>>>(x_enc, W_val, S->POSb, S->meanv, S->stdv,
                                       S->embh, S->qflat);
  // retrieval
  qsplit_kernel<<<2048, 256, 0, stream>>>(S->qflat, qsC);
  gemm_nt<3><<<dim3(8, 64), 256, 0, stream>>>(qsC, S->memdupB, nullptr, simB,
                                              1536, 1536, 1536, 8192, 8192);
  topk_kernel<<<1024, 256, 0, stream>>>(simB, S->idxB);
  gather_kernel<<<2048, 256, 0, stream>>>(mem_bank, S->idxB, retrB);
  gemm_nt<1><<<dim3(64, 8), 256, 0, stream>>>(retrB, S->Wm1T, b_m1, hiddenB,
                                              512, 512, 512, 1024, 1024);
  gmean_kernel<<<4096, 256, 0, stream>>>(hiddenB, S->gmeanB);
  gemm_nt<0><<<dim3(8, 4), 256, 0, stream>>>(S->gmeanB, S->Wm2T, b_m2, S->hmeanB,
                                             1024, 1024, 1024, 512, 512);
  // QKV (M = 65536)
  gemm_nt<0><<<dim3(512, 4), 256, 0, stream>>>(S->embh, S->WqT, b_q, S->qb,
                                               512, 512, 512, 512, 512);
  gemm_nt<0><<<dim3(512, 4), 256, 0, stream>>>(S->embh, S->WkT, b_k, S->kb,
                                               512, 512, 512, 512, 512);
  gemm_nt<0><<<dim3(512, 4), 256, 0, stream>>>(S->embh, S->WvT, b_v, S->vb,
                                               512, 512, 512, 512, 512);
  // local = emb + hmean (in place; QKV consumed emb)
  local_kernel<<<131072, 256, 0, stream>>>(S->embh, S->hmeanB);
  // attention (atto over qb)
  attn_kernel<<<dim3(1024, 4), 256, 0, stream>>>(S->qb, S->kb, S->vb);
  // glob = atto @ W_o + b_o -> kb
  gemm_nt<0><<<dim3(512, 4), 256, 0, stream>>>(S->qb, S->WoT, b_o, S->kb,
                                               512, 512, 512, 512, 512);
  // h1 = gelu([local|glob] @ W_g1 + b_g1) -> vb
  gemm_cat<<<dim3(512, 4), 256, 0, stream>>>(S->embh, S->kb, S->Wg1T, b_g1, S->vb);
  g2_kernel<<<16384, 256, 0, stream>>>(S->vb, W_g2, b_g2, S->gatel);
  // mem = g0*local + g1*glob -> qb
  memc_kernel<<<131072, 256, 0, stream>>>(S->embh, S->kb, S->gatel, S->qb);
  // mh = mem_flat [1024,32768] @ WhT^T, split-K x16, f32 atomics
  gemm_nt<2><<<dim3(8, 2, 16), 256, 0, stream>>>(S->qb, S->WhT, nullptr, S->mh,
                                                 32768, 32768, 2048, 192, 192);
  fusion_kernel<<<1024, 256, 0, stream>>>(S->mh, b_h, W_f1, b_f1, W_f2, b_f2,
                                          S->meanv, S->stdv, (float*)d_out);
}

// Round 9
// 1103.401 us; speedup vs baseline: 5.3282x; 1.0231x over previous
//
#include <hip/hip_runtime.h>
#include <stdint.h>

#define DEV __device__ __forceinline__

typedef uint16_t u16;
typedef __bf16 bf16x8 __attribute__((ext_vector_type(8)));
typedef float f32x4 __attribute__((ext_vector_type(4)));
typedef u16 u16x8 __attribute__((ext_vector_type(8)));

DEV float bf2f(u16 v) { return __uint_as_float(((uint32_t)v) << 16); }
DEV u16 f2bf(float f) {
  uint32_t u = __float_as_uint(f);
  u += 0x7fffu + ((u >> 16) & 1u);
  return (u16)(u >> 16);
}
DEV float gelu_f(float x) { return 0.5f * x * (1.0f + erff(x * 0.7071067811865475f)); }

DEV void gload_lds16(const u16* g, u16* l) {
  __builtin_amdgcn_global_load_lds(
      (const __attribute__((address_space(1))) void*)g,
      (__attribute__((address_space(3))) void*)l, 16, 0, 0);
}

// ---- all scratch in a static device global (R4: never trust ws_size) ----
struct __align__(16) Scratch {
  float POSb[64 * 512];
  float meanv[1024];
  float stdv[1024];
  float mh[1024 * 192];
  int idxB[8192];
  float qflat[1024 * 512];
  float gatel[65536 * 2];
  float bqkv[1536];
  u16 hmeanB[1024 * 512];
  u16 gmeanB[1024 * 1024];
  u16 WqkvT[1536 * 512];       // rows 0-511 Wq^T, 512-1023 Wk^T, 1024-1535 Wv^T
  u16 WoT[512 * 512];
  u16 Wm1T[1024 * 512];
  u16 Wm2T[512 * 1024];
  u16 Wg1T[512 * 1024];
  u16 WhT[256 * 32768];        // rows 192..255 zero-filled
  u16 memdupB[8192 * 1536];    // [mh|mh|ml] 24 MB
  u16 embh[65536 * 512];       // 64 MB: emb -> local -> mem (all in place)
  u16 qkvb[65536 * 1536];      // 192 MB: Q|K|V -> O|glob|h1 (cols reused)
};
__device__ Scratch g_s;

// ---------------- fills / small setup ----------------
__global__ __launch_bounds__(256) void zerof_kernel(float* __restrict__ p, int n) {
  int t = blockIdx.x * 256 + threadIdx.x;
  if (t < n) p[t] = 0.f;
}
__global__ __launch_bounds__(256) void zerou_kernel(u16* __restrict__ p, int n) {
  int t = blockIdx.x * 256 + threadIdx.x;
  if (t < n) p[t] = 0;
}
__global__ __launch_bounds__(256) void biasqkv_kernel(const float* __restrict__ bq,
                                                      const float* __restrict__ bk,
                                                      const float* __restrict__ bv,
                                                      float* __restrict__ o) {
  int t = blockIdx.x * 256 + threadIdx.x;  // < 1536
  o[t] = t < 512 ? bq[t] : (t < 1024 ? bk[t - 512] : bv[t - 1024]);
}

// ---------------- POS embedding ----------------
__global__ __launch_bounds__(256) void pos_kernel(float* __restrict__ POS) {
  int n = blockIdx.x;
  int i = threadIdx.x;
  float div = expf((float)(2 * i) * (-9.210340371976184f / 512.0f));
  float arg = (float)n * div;
  POS[n * 512 + 2 * i] = sinf(arg);
  POS[n * 512 + 2 * i + 1] = cosf(arg);
}

// ---------------- instance-norm stats ----------------
__global__ __launch_bounds__(256) void stats_kernel(const float* __restrict__ x_enc,
                                                    float* __restrict__ meanv,
                                                    float* __restrict__ stdv) {
  int b = blockIdx.x;
  int v = threadIdx.x & 63;
  int g = threadIdx.x >> 6;
  float s = 0.f, s2 = 0.f;
  for (int l = g; l < 512; l += 4) {
    float x = x_enc[((long)b * 512 + l) * 64 + v];
    s += x; s2 += x * x;
  }
  __shared__ float sh[2][4][64];
  sh[0][g][v] = s; sh[1][g][v] = s2;
  __syncthreads();
  if (g == 0) {
    s = sh[0][0][v] + sh[0][1][v] + sh[0][2][v] + sh[0][3][v];
    s2 = sh[1][0][v] + sh[1][1][v] + sh[1][2][v] + sh[1][3][v];
    float mu = s * (1.f / 512.f);
    float var = s2 * (1.f / 512.f) - mu * mu;
    meanv[b * 64 + v] = mu;
    stdv[b * 64 + v] = sqrtf(var + 1e-5f) * 2.5f;  // sqrt(var+eps)/0.4
  }
}

// ---------------- transpose f32 [R,C] -> bf16 [C,R] ----------------
__global__ __launch_bounds__(256) void transpose_kernel(const float* __restrict__ in,
                                                        u16* __restrict__ out, int R, int C) {
  __shared__ u16 t[32][33];
  int bx = blockIdx.x * 32;
  int by = blockIdx.y * 32;
  int tx = threadIdx.x & 31, ty = threadIdx.x >> 5;
  for (int i = ty; i < 32; i += 8) t[i][tx] = f2bf(in[(long)(by + i) * C + bx + tx]);
  __syncthreads();
  for (int i = ty; i < 32; i += 8) out[(long)(bx + i) * R + by + tx] = t[tx][i];
}

// ---------------- patch embed + qflat ----------------
__global__ __launch_bounds__(256) void emb_kernel(const float* __restrict__ x_enc,
                                                  const float* __restrict__ W_val,
                                                  const float* __restrict__ POS,
                                                  const float* __restrict__ meanv,
                                                  const float* __restrict__ stdv,
                                                  u16* __restrict__ embh,
                                                  float* __restrict__ qflat) {
  int bn = blockIdx.x;
  int b = bn >> 6, v = bn & 63;
  int tid = threadIdx.x;
  __shared__ __align__(16) float wv[16 * 512];
  __shared__ __align__(16) float pt[64 * 16];
  for (int i = tid; i < 8192; i += 256) wv[i] = W_val[i];
  float mu = meanv[bn];
  float inv = 1.f / stdv[bn];
  for (int i = tid; i < 1024; i += 256) {
    int n = i >> 4, p = i & 15;
    int l = n * 8 + p; if (l > 511) l = 511;  // replication pad
    pt[i] = (x_enc[((long)b * 512 + l) * 64 + v] - mu) * inv;
  }
  __syncthreads();
  float qs0 = 0.f, qs1 = 0.f;
  int d0 = tid, d1 = tid + 256;
  for (int n = 0; n < 64; ++n) {
    float a0 = POS[n * 512 + d0], a1 = POS[n * 512 + d1];
#pragma unroll
    for (int p = 0; p < 16; ++p) {
      float pv = pt[n * 16 + p];
      a0 += pv * wv[p * 512 + d0];
      a1 += pv * wv[p * 512 + d1];
    }
    long base = ((long)bn * 64 + n) * 512;
    embh[base + d0] = f2bf(a0);
    embh[base + d1] = f2bf(a1);
    qs0 += a0; qs1 += a1;
  }
  qflat[(long)bn * 512 + d0] = qs0 * (1.f / 64.f);
  qflat[(long)bn * 512 + d1] = qs1 * (1.f / 64.f);
}

// ---------------- qflat f32 -> [qh|ql|qh] bf16 row of 1536 ----------------
__global__ __launch_bounds__(256) void qsplit_kernel(const float* __restrict__ qflat,
                                                     u16* __restrict__ qsC) {
  int t = blockIdx.x * 256 + threadIdx.x;  // < 524288
  int bn = t >> 9, d = t & 511;
  float q = qflat[t];
  u16 hi = f2bf(q);
  u16 lo = f2bf(q - bf2f(hi));
  long base = (long)bn * 1536;
  qsC[base + d] = hi;
  qsC[base + 512 + d] = lo;
  qsC[base + 1024 + d] = hi;
}

// ---------------- mem_bank f32 -> [mh|mh|ml] bf16 row of 1536 ----------------
__global__ __launch_bounds__(256) void memdup_kernel(const float* __restrict__ mb,
                                                     u16* __restrict__ md) {
  int t = blockIdx.x * 256 + threadIdx.x;  // < 4194304
  int n = t >> 9, k = t & 511;
  float m = mb[t];
  u16 hi = f2bf(m);
  u16 lo = f2bf(m - bf2f(hi));
  long base = (long)n * 1536;
  md[base + k] = hi;
  md[base + 512 + k] = hi;
  md[base + 1024 + k] = lo;
}

// ---------------- NT MFMA GEMM: BK=64, xor-swizzled LDS, N-minor grid ----------------
// blockIdx.x = N tile (small), blockIdx.y = M tile -> consecutive blocks share A tile.
// EPI: 0 bias+bf16 | 1 bias+gelu+bf16 | 2 f32 atomicAdd | 3 f32 store
template <int EPI>
__global__ __launch_bounds__(256) void gemm_nt(const u16* __restrict__ Ag,
                                               const u16* __restrict__ Bt,
                                               const float* __restrict__ bias,
                                               void* __restrict__ C,
                                               int lda, int ldb, int K, int Nreal, int ldc) {
  __shared__ __align__(16) u16 As[128 * 64];
  __shared__ __align__(16) u16 Bs[128 * 64];
  const int tid = threadIdx.x;
  const long bnn = (long)blockIdx.x * 128;
  const long bm = (long)blockIdx.y * 128;
  const long koff = (long)blockIdx.z * K;
  const int lane = tid & 63;
  const int w = tid >> 6;
  const int wm = (w & 1) * 64;
  const int wn = (w >> 1) * 64;
  const int r16 = lane & 15;
  const int q4 = lane >> 4;

  f32x4 acc[4][4] = {};

  const u16* ap[4];
  const u16* bp[4];
  u16* al[4];
  u16* bl[4];
#pragma unroll
  for (int j = 0; j < 4; ++j) {
    int cid = (j * 4 + w) * 64 + lane;
    int r = cid >> 3;
    int g = (cid & 7) ^ (r & 7);
    ap[j] = Ag + (bm + r) * lda + koff + g * 8;
    bp[j] = Bt + (bnn + r) * ldb + koff + g * 8;
    al[j] = As + cid * 8;
    bl[j] = Bs + cid * 8;
  }

  for (int k0 = 0; k0 < K; k0 += 64) {
#pragma unroll
    for (int j = 0; j < 4; ++j) gload_lds16(ap[j] + k0, al[j]);
#pragma unroll
    for (int j = 0; j < 4; ++j) gload_lds16(bp[j] + k0, bl[j]);
    __syncthreads();
#pragma unroll
    for (int sub = 0; sub < 2; ++sub) {
      const int gg = q4 + sub * 4;
      bf16x8 av[4], bv[4];
#pragma unroll
      for (int i = 0; i < 4; ++i) {
        int r = wm + i * 16 + r16;
        av[i] = *reinterpret_cast<const bf16x8*>(As + (r * 8 + (gg ^ (r & 7))) * 8);
      }
#pragma unroll
      for (int j2 = 0; j2 < 4; ++j2) {
        int r = wn + j2 * 16 + r16;
        bv[j2] = *reinterpret_cast<const bf16x8*>(Bs + (r * 8 + (gg ^ (r & 7))) * 8);
      }
#pragma unroll
      for (int i = 0; i < 4; ++i)
#pragma unroll
        for (int j2 = 0; j2 < 4; ++j2)
          acc[i][j2] = __builtin_amdgcn_mfma_f32_16x16x32_bf16(av[i], bv[j2], acc[i][j2], 0, 0, 0);
    }
    __syncthreads();
  }

#pragma unroll
  for (int i = 0; i < 4; ++i)
#pragma unroll
    for (int j = 0; j < 4; ++j)
#pragma unroll
      for (int r = 0; r < 4; ++r) {
        long grow = bm + wm + i * 16 + q4 * 4 + r;
        int gcol = (int)bnn + wn + j * 16 + r16;
        float v = acc[i][j][r];
        if (gcol < Nreal) {
          if (EPI == 0 || EPI == 1) {
            v += bias[gcol];
            if (EPI == 1) v = gelu_f(v);
            ((u16*)C)[grow * ldc + gcol] = f2bf(v);
          } else if (EPI == 2) {
            atomicAdd((float*)C + grow * ldc + gcol, v);
          } else {
            ((float*)C)[grow * ldc + gcol] = v;
          }
        }
      }
}

// ---------------- top-8 per row, parallel tree merge ----------------
DEV bool better(float v1, int i1, float v2, int i2) {
  return v1 > v2 || (v1 == v2 && i1 < i2);
}
__global__ __launch_bounds__(256) void topk_kernel(const float* __restrict__ sim,
                                                   int* __restrict__ idxout) {
  const int bn = blockIdx.x;
  const int tid = threadIdx.x;
  const float* row = sim + (long)bn * 8192;
  float bv[8]; int bi[8];
#pragma unroll
  for (int r = 0; r < 8; ++r) { bv[r] = -3.0e38f; bi[r] = 0x7fffffff; }
  for (int n = tid; n < 8192; n += 256) {
    float v = row[n];
    if (better(v, n, bv[7], bi[7])) {
      bv[7] = v; bi[7] = n;
      for (int r = 7; r > 0; --r) {
        if (!better(bv[r], bi[r], bv[r - 1], bi[r - 1])) break;
        float tv = bv[r]; bv[r] = bv[r - 1]; bv[r - 1] = tv;
        int ti = bi[r]; bi[r] = bi[r - 1]; bi[r - 1] = ti;
      }
    }
  }
  __shared__ float lv[256 * 8];
  __shared__ int li[256 * 8];
#pragma unroll
  for (int r = 0; r < 8; ++r) { lv[tid * 8 + r] = bv[r]; li[tid * 8 + r] = bi[r]; }
  __syncthreads();
  for (int step = 128; step >= 1; step >>= 1) {
    if (tid < step) {
      float av[8], xv[8]; int ai[8], xi[8];
#pragma unroll
      for (int r = 0; r < 8; ++r) {
        av[r] = lv[tid * 8 + r]; ai[r] = li[tid * 8 + r];
        xv[r] = lv[(tid + step) * 8 + r]; xi[r] = li[(tid + step) * 8 + r];
      }
      int ia = 0, ib = 0;
      float mv[8]; int mi[8];
#pragma unroll
      for (int r = 0; r < 8; ++r) {
        if (better(av[ia], ai[ia], xv[ib], xi[ib])) { mv[r] = av[ia]; mi[r] = ai[ia]; ++ia; }
        else { mv[r] = xv[ib]; mi[r] = xi[ib]; ++ib; }
      }
#pragma unroll
      for (int r = 0; r < 8; ++r) { lv[tid * 8 + r] = mv[r]; li[tid * 8 + r] = mi[r]; }
    }
    __syncthreads();
  }
  if (tid < 8) idxout[bn * 8 + tid] = li[tid];
}

// ---------------- gather retrieved rows, f32 -> bf16, clamped ----------------
__global__ __launch_bounds__(256) void gather_kernel(const float* __restrict__ mb,
                                                     const int* __restrict__ idx,
                                                     u16* __restrict__ retrB) {
  int t = blockIdx.x * 256 + threadIdx.x;  // < 524288
  int m = t >> 6;
  int c8 = (t & 63) * 8;
  long r = idx[m];
  if (r < 0) r = 0;
  if (r > 8191) r = 8191;
  const float* src = mb + r * 512 + c8;
  u16* dst = retrB + (long)m * 512 + c8;
#pragma unroll
  for (int z = 0; z < 8; ++z) dst[z] = f2bf(src[z]);
}

// ---------------- mean over K of gelu-hidden -> bf16 ----------------
__global__ __launch_bounds__(256) void gmean_kernel(const u16* __restrict__ hid,
                                                    u16* __restrict__ gmeanB) {
  int t = blockIdx.x * 256 + threadIdx.x;  // < 1048576
  int bn = t >> 10, j = t & 1023;
  float s = 0.f;
#pragma unroll
  for (int k = 0; k < 8; ++k) s += bf2f(hid[(long)(bn * 8 + k) * 1024 + j]);
  gmeanB[t] = f2bf(s * 0.125f);
}

// ---------------- MFMA attention over fused qkvb (stride 1536); O over Q cols ----
__global__ __launch_bounds__(256) void attn_kernel(u16* __restrict__ qkvb) {
  __shared__ __align__(16) u16 smem[26752];
  u16* Qs = smem;
  u16* Ks = smem + 8704;
  float* ss = (float*)(smem + 8704);   // overlay Ks
  u16* ps = smem;                      // overlay Qs
  u16* Vb = smem + 17408;
  float* red = (float*)(smem + 25728);
  const int bn = blockIdx.x, h = blockIdx.y;
  const int tid = threadIdx.x;
  const int lane = tid & 63, w = tid >> 6;
  const int r16 = lane & 15, q4 = lane >> 4;
  const long base = (long)bn * 64 * 1536 + h * 128;

  for (int c = tid; c < 1024; c += 256) {
    int r = c >> 4, c8 = (c & 15) * 8;
    u16x8 vq = *(const u16x8*)(qkvb + base + (long)r * 1536 + c8);
    u16x8 vk = *(const u16x8*)(qkvb + base + (long)r * 1536 + 512 + c8);
    u16x8 vv = *(const u16x8*)(qkvb + base + (long)r * 1536 + 1024 + c8);
    *(u16x8*)(Qs + r * 136 + c8) = vq;
    *(u16x8*)(Ks + r * 136 + c8) = vk;
    int kt = r >> 5, q4t = (r >> 3) & 3, e = r & 7;
    int nt = c8 >> 4, rb = c8 & 15;
    int vbase = (nt * 2 + kt) * 520 + (q4t * 16 + rb) * 8 + e;
#pragma unroll
    for (int z = 0; z < 8; ++z) Vb[vbase + z * 8] = vv[z];
  }
  __syncthreads();

  const int m0 = w * 16;
  f32x4 accS[4] = {};
#pragma unroll
  for (int k0 = 0; k0 < 128; k0 += 32) {
    bf16x8 av = *(const bf16x8*)(Qs + (m0 + r16) * 136 + k0 + q4 * 8);
#pragma unroll
    for (int j = 0; j < 4; ++j) {
      bf16x8 bvf = *(const bf16x8*)(Ks + (j * 16 + r16) * 136 + k0 + q4 * 8);
      accS[j] = __builtin_amdgcn_mfma_f32_16x16x32_bf16(av, bvf, accS[j], 0, 0, 0);
    }
  }
  __syncthreads();
  const float scale = 0.08838834764831845f;  // 1/sqrt(128)
#pragma unroll
  for (int j = 0; j < 4; ++j)
#pragma unroll
    for (int r = 0; r < 4; ++r)
      ss[(m0 + q4 * 4 + r) * 66 + j * 16 + r16] = accS[j][r] * scale;
  __syncthreads();

  {
    int r = tid >> 2, p = tid & 3;
    float* row = ss + r * 66 + p * 16;
    float mx = -3.0e38f;
#pragma unroll
    for (int c2 = 0; c2 < 16; ++c2) mx = fmaxf(mx, row[c2]);
    red[r * 4 + p] = mx;
    __syncthreads();
    float m4 = fmaxf(fmaxf(red[r * 4], red[r * 4 + 1]),
                     fmaxf(red[r * 4 + 2], red[r * 4 + 3]));
    float s = 0.f;
#pragma unroll
    for (int c2 = 0; c2 < 16; ++c2) {
      float e = expf(row[c2] - m4);
      row[c2] = e;
      s += e;
    }
    red[256 + r * 4 + p] = s;
    __syncthreads();
    float inv = 1.f / (red[256 + r * 4] + red[256 + r * 4 + 1] +
                       red[256 + r * 4 + 2] + red[256 + r * 4 + 3]);
    u16x8 o0, o1;
#pragma unroll
    for (int z = 0; z < 8; ++z) {
      o0[z] = f2bf(row[z] * inv);
      o1[z] = f2bf(row[8 + z] * inv);
    }
    *(u16x8*)(ps + r * 72 + p * 16) = o0;
    *(u16x8*)(ps + r * 72 + p * 16 + 8) = o1;
  }
  __syncthreads();

  bf16x8 av0 = *(const bf16x8*)(ps + (m0 + r16) * 72 + q4 * 8);
  bf16x8 av1 = *(const bf16x8*)(ps + (m0 + r16) * 72 + 32 + q4 * 8);
#pragma unroll
  for (int nt = 0; nt < 8; ++nt) {
    f32x4 accO = {};
    bf16x8 bv0 = *(const bf16x8*)(Vb + (nt * 2 + 0) * 520 + lane * 8);
    bf16x8 bv1 = *(const bf16x8*)(Vb + (nt * 2 + 1) * 520 + lane * 8);
    accO = __builtin_amdgcn_mfma_f32_16x16x32_bf16(av0, bv0, accO, 0, 0, 0);
    accO = __builtin_amdgcn_mfma_f32_16x16x32_bf16(av1, bv1, accO, 0, 0, 0);
    int d = nt * 16 + r16;
#pragma unroll
    for (int r = 0; r < 4; ++r) {
      int i = m0 + q4 * 4 + r;
      qkvb[base + (long)i * 1536 + d] = f2bf(accO[r]);  // O over dead Q cols
    }
  }
}

// ---------------- local = emb + hmean (in-place over embh) ----------------
__global__ __launch_bounds__(256) void local_kernel(u16* __restrict__ embh,
                                                    const u16* __restrict__ hmeanB) {
  long t = (long)blockIdx.x * 256 + threadIdx.x;  // < 33554432
  long m = t >> 9;
  int d = (int)(t & 511);
  int bn = (int)(m >> 6);
  embh[t] = f2bf(bf2f(hmeanB[(long)bn * 512 + d]) + bf2f(embh[t]));
}

// ---------------- concat-K NT GEMM (BK=64, swizzled, N-minor grid, strided) ----------
__global__ __launch_bounds__(256) void gemm_cat(const u16* __restrict__ A1,
                                                const u16* __restrict__ A2,
                                                const u16* __restrict__ Bt,
                                                const float* __restrict__ bias,
                                                u16* __restrict__ C,
                                                int lda1, int lda2, int ldc) {
  __shared__ __align__(16) u16 As[128 * 64];
  __shared__ __align__(16) u16 Bs[128 * 64];
  const int tid = threadIdx.x;
  const long bnn = (long)blockIdx.x * 128;
  const long bm = (long)blockIdx.y * 128;
  const int lane = tid & 63;
  const int w = tid >> 6;
  const int wm = (w & 1) * 64;
  const int wn = (w >> 1) * 64;
  const int r16 = lane & 15;
  const int q4 = lane >> 4;

  f32x4 acc[4][4] = {};

  const u16* ap1[4];
  const u16* ap2[4];
  const u16* bp[4];
  u16* al[4];
  u16* bl[4];
#pragma unroll
  for (int j = 0; j < 4; ++j) {
    int cid = (j * 4 + w) * 64 + lane;
    int r = cid >> 3;
    int g = (cid & 7) ^ (r & 7);
    ap1[j] = A1 + (bm + r) * lda1 + g * 8;
    ap2[j] = A2 + (bm + r) * lda2 + g * 8;
    bp[j] = Bt + (bnn + r) * 1024 + g * 8;
    al[j] = As + cid * 8;
    bl[j] = Bs + cid * 8;
  }

  for (int k0 = 0; k0 < 1024; k0 += 64) {
    if (k0 < 512) {
#pragma unroll
      for (int j = 0; j < 4; ++j) gload_lds16(ap1[j] + k0, al[j]);
    } else {
#pragma unroll
      for (int j = 0; j < 4; ++j) gload_lds16(ap2[j] + (k0 - 512), al[j]);
    }
#pragma unroll
    for (int j = 0; j < 4; ++j) gload_lds16(bp[j] + k0, bl[j]);
    __syncthreads();
#pragma unroll
    for (int sub = 0; sub < 2; ++sub) {
      const int gg = q4 + sub * 4;
      bf16x8 av[4], bv[4];
#pragma unroll
      for (int i = 0; i < 4; ++i) {
        int r = wm + i * 16 + r16;
        av[i] = *reinterpret_cast<const bf16x8*>(As + (r * 8 + (gg ^ (r & 7))) * 8);
      }
#pragma unroll
      for (int j2 = 0; j2 < 4; ++j2) {
        int r = wn + j2 * 16 + r16;
        bv[j2] = *reinterpret_cast<const bf16x8*>(Bs + (r * 8 + (gg ^ (r & 7))) * 8);
      }
#pragma unroll
      for (int i = 0; i < 4; ++i)
#pragma unroll
        for (int j2 = 0; j2 < 4; ++j2)
          acc[i][j2] = __builtin_amdgcn_mfma_f32_16x16x32_bf16(av[i], bv[j2], acc[i][j2], 0, 0, 0);
    }
    __syncthreads();
  }

#pragma unroll
  for (int i = 0; i < 4; ++i)
#pragma unroll
    for (int j = 0; j < 4; ++j)
#pragma unroll
      for (int r = 0; r < 4; ++r) {
        long grow = bm + wm + i * 16 + q4 * 4 + r;
        int gcol = (int)bnn + wn + j * 16 + r16;
        float v = acc[i][j][r] + bias[gcol];
        C[grow * ldc + gcol] = f2bf(gelu_f(v));
      }
}

// ---------------- gate logits + softmax(2); h1 at stride ld ----------------
__global__ __launch_bounds__(256) void g2_kernel(const u16* __restrict__ h1b,
                                                 const float* __restrict__ W_g2,
                                                 const float* __restrict__ b_g2,
                                                 float* __restrict__ gatel, int ld) {
  int m = blockIdx.x * 4 + (threadIdx.x >> 6);
  int lane = threadIdx.x & 63;
  const u16* row = h1b + (long)m * ld;
  float a0 = 0.f, a1 = 0.f;
  for (int i = lane; i < 512; i += 64) {
    float h = bf2f(row[i]);
    a0 += h * W_g2[i * 2];
    a1 += h * W_g2[i * 2 + 1];
  }
  for (int off = 32; off; off >>= 1) {
    a0 += __shfl_down(a0, off);
    a1 += __shfl_down(a1, off);
  }
  if (lane == 0) {
    a0 += b_g2[0];
    a1 += b_g2[1];
    float mx = fmaxf(a0, a1);
    float e0 = expf(a0 - mx), e1 = expf(a1 - mx);
    float inv = 1.f / (e0 + e1);
    gatel[(long)m * 2] = e0 * inv;
    gatel[(long)m * 2 + 1] = e1 * inv;
  }
}

// ---------------- mem = g0*local + g1*glob (in place over embh) ----------------
__global__ __launch_bounds__(256) void memc_kernel(u16* __restrict__ embh,
                                                   const u16* __restrict__ qkvb,
                                                   const float* __restrict__ gatel) {
  long t = (long)blockIdx.x * 256 + threadIdx.x;  // < 33554432
  long m = t >> 9;
  int d = (int)(t & 511);
  float loc = bf2f(embh[t]);
  float gl = bf2f(qkvb[m * 1536 + 512 + d]);
  float g0 = gatel[m * 2], g1 = gatel[m * 2 + 1];
  embh[t] = f2bf(g0 * loc + g1 * gl);
}

// ---------------- fusion head + denorm + transpose store (f32) ----------------
__global__ __launch_bounds__(256) void fusion_kernel(const float* __restrict__ mh,
                                                     const float* __restrict__ b_h,
                                                     const float* __restrict__ W_f1,
                                                     const float* __restrict__ b_f1,
                                                     const float* __restrict__ W_f2,
                                                     const float* __restrict__ b_f2,
                                                     const float* __restrict__ meanv,
                                                     const float* __restrict__ stdv,
                                                     float* __restrict__ out) {
  int bn = blockIdx.x;
  int tid = threadIdx.x;
  __shared__ float mrow[192];
  __shared__ float h1[384];
  if (tid < 192) mrow[tid] = mh[(long)bn * 192 + tid] + b_h[tid];
  __syncthreads();
  for (int j = tid; j < 384; j += 256) {
    float a = b_f1[j];
    for (int i = 0; i < 192; ++i) a += mrow[i] * W_f1[i * 384 + j];
    h1[j] = gelu_f(a);
  }
  __syncthreads();
  if (tid < 192) {
    float a = b_f2[tid];
    for (int j = 0; j < 384; ++j) a += h1[j] * W_f2[j * 192 + tid];
    float o = gelu_f(a) + mrow[tid];
    int b = bn >> 6, v = bn & 63;
    out[((long)b * 192 + tid) * 64 + v] = o * stdv[bn] + meanv[bn];
  }
}

extern "C" void kernel_launch(void* const* d_in, const int* in_sizes, int n_in,
                              void* d_out, int out_size, void* d_ws, size_t ws_size,
                              hipStream_t stream) {
  (void)in_sizes; (void)n_in; (void)out_size; (void)d_ws; (void)ws_size;
  const float* x_enc = (const float*)d_in[0];
  const float* W_val = (const float*)d_in[1];
  const float* mem_bank = (const float*)d_in[2];
  const float* W_m1 = (const float*)d_in[3];
  const float* b_m1 = (const float*)d_in[4];
  const float* W_m2 = (const float*)d_in[5];
  const float* b_m2 = (const float*)d_in[6];
  const float* W_q = (const float*)d_in[7];
  const float* b_q = (const float*)d_in[8];
  const float* W_k = (const float*)d_in[9];
  const float* b_k = (const float*)d_in[10];
  const float* W_v = (const float*)d_in[11];
  const float* b_v = (const float*)d_in[12];
  const float* W_o = (const float*)d_in[13];
  const float* b_o = (const float*)d_in[14];
  const float* W_g1 = (const float*)d_in[15];
  const float* b_g1 = (const float*)d_in[16];
  const float* W_g2 = (const float*)d_in[17];
  const float* b_g2 = (const float*)d_in[18];
  const float* W_h = (const float*)d_in[19];
  const float* b_h = (const float*)d_in[20];
  const float* W_f1 = (const float*)d_in[21];
  const float* b_f1 = (const float*)d_in[22];
  const float* W_f2 = (const float*)d_in[23];
  const float* b_f2 = (const float*)d_in[24];

  void* sp = nullptr;
  hipGetSymbolAddress(&sp, HIP_SYMBOL(g_s));
  Scratch* S = (Scratch*)sp;
  // sim-phase aliases inside qkvb (all dead before fused QKV writes it)
  float* simB = (float*)S->qkvb;                            // 32 MB
  u16* qsC = S->qkvb + (size_t)16 * 1024 * 1024;            // 3 MB
  u16* retrB = S->qkvb + (size_t)18 * 1024 * 1024;          // 8 MB
  u16* hiddenB = S->qkvb + (size_t)24 * 1024 * 1024;        // 16 MB

  // setup
  pos_kernel<<<64, 256, 0, stream>>>(S->POSb);
  stats_kernel<<<16, 256, 0, stream>>>(x_enc, S->meanv, S->stdv);
  zerof_kernel<<<768, 256, 0, stream>>>(S->mh, 1024 * 192);
  zerou_kernel<<<8192, 256, 0, stream>>>(S->WhT + (size_t)192 * 32768, 64 * 32768);
  biasqkv_kernel<<<6, 256, 0, stream>>>(b_q, b_k, b_v, S->bqkv);
  transpose_kernel<<<dim3(16, 16), 256, 0, stream>>>(W_q, S->WqkvT, 512, 512);
  transpose_kernel<<<dim3(16, 16), 256, 0, stream>>>(W_k, S->WqkvT + 512 * 512, 512, 512);
  transpose_kernel<<<dim3(16, 16), 256, 0, stream>>>(W_v, S->WqkvT + 2 * 512 * 512, 512, 512);
  transpose_kernel<<<dim3(16, 16), 256, 0, stream>>>(W_o, S->WoT, 512, 512);
  transpose_kernel<<<dim3(32, 16), 256, 0, stream>>>(W_m1, S->Wm1T, 512, 1024);
  transpose_kernel<<<dim3(16, 32), 256, 0, stream>>>(W_m2, S->Wm2T, 1024, 512);
  transpose_kernel<<<dim3(16, 32), 256, 0, stream>>>(W_g1, S->Wg1T, 1024, 512);
  transpose_kernel<<<dim3(6, 1024), 256, 0, stream>>>(W_h, S->WhT, 32768, 192);
  memdup_kernel<<<16384, 256, 0, stream>>>(mem_bank, S->memdupB);

  // embedding
  emb_kernel<<<1024, 256, 0, stream>>>(x_enc, W_val, S->POSb, S->meanv, S->stdv,
                                       S->embh, S->qflat);
  // retrieval
  qsplit_kernel<<<2048, 256, 0, stream>>>(S->qflat, qsC);
  gemm_nt<3><<<dim3(64, 8), 256, 0, stream>>>(qsC, S->memdupB, nullptr, simB,
                                              1536, 1536, 1536, 8192, 8192);
  topk_kernel<<<1024, 256, 0, stream>>>(simB, S->idxB);
  gather_kernel<<<2048, 256, 0, stream>>>(mem_bank, S->idxB, retrB);
  gemm_nt<1><<<dim3(8, 64), 256, 0, stream>>>(retrB, S->Wm1T, b_m1, hiddenB,
                                              512, 512, 512, 1024, 1024);
  gmean_kernel<<<4096, 256, 0, stream>>>(hiddenB, S->gmeanB);
  gemm_nt<0><<<dim3(4, 8), 256, 0, stream>>>(S->gmeanB, S->Wm2T, b_m2, S->hmeanB,
                                             1024, 1024, 1024, 512, 512);
  // fused QKV: [65536,512] @ WqkvT^T -> qkvb [65536,1536]
  gemm_nt<0><<<dim3(12, 512), 256, 0, stream>>>(S->embh, S->WqkvT, S->bqkv, S->qkvb,
                                                512, 512, 512, 1536, 1536);
  // local = emb + hmean (in place; QKV consumed emb)
  local_kernel<<<131072, 256, 0, stream>>>(S->embh, S->hmeanB);
  // attention (O over Q cols of qkvb)
  attn_kernel<<<dim3(1024, 4), 256, 0, stream>>>(S->qkvb);
  // glob = O @ W_o + b_o -> K cols of qkvb
  gemm_nt<0><<<dim3(4, 512), 256, 0, stream>>>(S->qkvb, S->WoT, b_o, S->qkvb + 512,
                                               1536, 512, 512, 512, 1536);
  // h1 = gelu([local|glob] @ W_g1 + b_g1) -> V cols of qkvb
  gemm_cat<<<dim3(4, 512), 256, 0, stream>>>(S->embh, S->qkvb + 512, S->Wg1T, b_g1,
                                             S->qkvb + 1024, 512, 1536, 1536);
  g2_kernel<<<16384, 256, 0, stream>>>(S->qkvb + 1024, W_g2, b_g2, S->gatel, 1536);
  // mem = g0*local + g1*glob (in place over embh)
  memc_kernel<<<131072, 256, 0, stream>>>(S->embh, S->qkvb, S->gatel);
  // mh = mem_flat [1024,32768] @ WhT^T, split-K x16, f32 atomics
  gemm_nt<2><<<dim3(2, 8, 16), 256, 0, stream>>>(S->embh, S->WhT, nullptr, S->mh,
                                                 32768, 32768, 2048, 192, 192);
  fusion_kernel<<<1024, 256, 0, stream>>>(S->mh, b_h, W_f1, b_f1, W_f2, b_f2,
                                          S->meanv, S->stdv, (float*)d_out);
}

// Round 10
// 1053.296 us; speedup vs baseline: 5.5817x; 1.0476x over previous
//
#include <hip/hip_runtime.h>
#include <stdint.h>

#define DEV __device__ __forceinline__

typedef uint16_t u16;
typedef __bf16 bf16x8 __attribute__((ext_vector_type(8)));
typedef float f32x4 __attribute__((ext_vector_type(4)));
typedef u16 u16x8 __attribute__((ext_vector_type(8)));

DEV float bf2f(u16 v) { return __uint_as_float(((uint32_t)v) << 16); }
DEV u16 f2bf(float f) {
  uint32_t u = __float_as_uint(f);
  u += 0x7fffu + ((u >> 16) & 1u);
  return (u16)(u >> 16);
}
DEV float gelu_f(float x) { return 0.5f * x * (1.0f + erff(x * 0.7071067811865475f)); }

DEV void gload_lds16(const u16* g, u16* l) {
  __builtin_amdgcn_global_load_lds(
      (const __attribute__((address_space(1))) void*)g,
      (__attribute__((address_space(3))) void*)l, 16, 0, 0);
}

// ---- all scratch in a static device global (R4: never trust ws_size) ----
struct __align__(16) Scratch {
  float POSb[64 * 512];
  float meanv[1024];
  float stdv[1024];
  float mh[1024 * 192];
  int idxB[8192];
  float qflat[1024 * 512];
  float gatel[65536 * 2];
  float bqkv[1536];
  u16 hmeanB[1024 * 512];
  u16 gmeanB[1024 * 1024];
  u16 WqkvT[1536 * 512];       // rows 0-511 Wq^T, 512-1023 Wk^T, 1024-1535 Wv^T
  u16 WoT[512 * 512];
  u16 Wm1T[1024 * 512];
  u16 Wm2T[512 * 1024];
  u16 Wg1T[512 * 1024];
  u16 WhT[256 * 32768];        // rows 192..255 zero-filled
  u16 memdupB[8192 * 1536];    // [mh|mh|ml] 24 MB
  u16 embh[65536 * 512];       // 64 MB: emb -> local -> mem (all in place)
  u16 qkvb[65536 * 1536];      // 192 MB: Q|K|V -> O|glob|h1 (cols reused)
};
__device__ Scratch g_s;

// ---------------- fills / small setup ----------------
__global__ __launch_bounds__(256) void zerof_kernel(float* __restrict__ p, int n) {
  int t = blockIdx.x * 256 + threadIdx.x;
  if (t < n) p[t] = 0.f;
}
__global__ __launch_bounds__(256) void zerou_kernel(u16* __restrict__ p, int n) {
  int t = blockIdx.x * 256 + threadIdx.x;
  if (t < n) p[t] = 0;
}
__global__ __launch_bounds__(256) void biasqkv_kernel(const float* __restrict__ bq,
                                                      const float* __restrict__ bk,
                                                      const float* __restrict__ bv,
                                                      float* __restrict__ o) {
  int t = blockIdx.x * 256 + threadIdx.x;  // < 1536
  o[t] = t < 512 ? bq[t] : (t < 1024 ? bk[t - 512] : bv[t - 1024]);
}

// ---------------- POS embedding ----------------
__global__ __launch_bounds__(256) void pos_kernel(float* __restrict__ POS) {
  int n = blockIdx.x;
  int i = threadIdx.x;
  float div = expf((float)(2 * i) * (-9.210340371976184f / 512.0f));
  float arg = (float)n * div;
  POS[n * 512 + 2 * i] = sinf(arg);
  POS[n * 512 + 2 * i + 1] = cosf(arg);
}

// ---------------- instance-norm stats ----------------
__global__ __launch_bounds__(256) void stats_kernel(const float* __restrict__ x_enc,
                                                    float* __restrict__ meanv,
                                                    float* __restrict__ stdv) {
  int b = blockIdx.x;
  int v = threadIdx.x & 63;
  int g = threadIdx.x >> 6;
  float s = 0.f, s2 = 0.f;
  for (int l = g; l < 512; l += 4) {
    float x = x_enc[((long)b * 512 + l) * 64 + v];
    s += x; s2 += x * x;
  }
  __shared__ float sh[2][4][64];
  sh[0][g][v] = s; sh[1][g][v] = s2;
  __syncthreads();
  if (g == 0) {
    s = sh[0][0][v] + sh[0][1][v] + sh[0][2][v] + sh[0][3][v];
    s2 = sh[1][0][v] + sh[1][1][v] + sh[1][2][v] + sh[1][3][v];
    float mu = s * (1.f / 512.f);
    float var = s2 * (1.f / 512.f) - mu * mu;
    meanv[b * 64 + v] = mu;
    stdv[b * 64 + v] = sqrtf(var + 1e-5f) * 2.5f;  // sqrt(var+eps)/0.4
  }
}

// ---------------- transpose f32 [R,C] -> bf16 [C,R] ----------------
__global__ __launch_bounds__(256) void transpose_kernel(const float* __restrict__ in,
                                                        u16* __restrict__ out, int R, int C) {
  __shared__ u16 t[32][33];
  int bx = blockIdx.x * 32;
  int by = blockIdx.y * 32;
  int tx = threadIdx.x & 31, ty = threadIdx.x >> 5;
  for (int i = ty; i < 32; i += 8) t[i][tx] = f2bf(in[(long)(by + i) * C + bx + tx]);
  __syncthreads();
  for (int i = ty; i < 32; i += 8) out[(long)(bx + i) * R + by + tx] = t[tx][i];
}

// ---------------- patch embed + qflat ----------------
__global__ __launch_bounds__(256) void emb_kernel(const float* __restrict__ x_enc,
                                                  const float* __restrict__ W_val,
                                                  const float* __restrict__ POS,
                                                  const float* __restrict__ meanv,
                                                  const float* __restrict__ stdv,
                                                  u16* __restrict__ embh,
                                                  float* __restrict__ qflat) {
  int bn = blockIdx.x;
  int b = bn >> 6, v = bn & 63;
  int tid = threadIdx.x;
  __shared__ __align__(16) float wv[16 * 512];
  __shared__ __align__(16) float pt[64 * 16];
  for (int i = tid; i < 8192; i += 256) wv[i] = W_val[i];
  float mu = meanv[bn];
  float inv = 1.f / stdv[bn];
  for (int i = tid; i < 1024; i += 256) {
    int n = i >> 4, p = i & 15;
    int l = n * 8 + p; if (l > 511) l = 511;  // replication pad
    pt[i] = (x_enc[((long)b * 512 + l) * 64 + v] - mu) * inv;
  }
  __syncthreads();
  float qs0 = 0.f, qs1 = 0.f;
  int d0 = tid, d1 = tid + 256;
  for (int n = 0; n < 64; ++n) {
    float a0 = POS[n * 512 + d0], a1 = POS[n * 512 + d1];
#pragma unroll
    for (int p = 0; p < 16; ++p) {
      float pv = pt[n * 16 + p];
      a0 += pv * wv[p * 512 + d0];
      a1 += pv * wv[p * 512 + d1];
    }
    long base = ((long)bn * 64 + n) * 512;
    embh[base + d0] = f2bf(a0);
    embh[base + d1] = f2bf(a1);
    qs0 += a0; qs1 += a1;
  }
  qflat[(long)bn * 512 + d0] = qs0 * (1.f / 64.f);
  qflat[(long)bn * 512 + d1] = qs1 * (1.f / 64.f);
}

// ---------------- qflat f32 -> [qh|ql|qh] bf16 row of 1536 ----------------
__global__ __launch_bounds__(256) void qsplit_kernel(const float* __restrict__ qflat,
                                                     u16* __restrict__ qsC) {
  int t = blockIdx.x * 256 + threadIdx.x;  // < 524288
  int bn = t >> 9, d = t & 511;
  float q = qflat[t];
  u16 hi = f2bf(q);
  u16 lo = f2bf(q - bf2f(hi));
  long base = (long)bn * 1536;
  qsC[base + d] = hi;
  qsC[base + 512 + d] = lo;
  qsC[base + 1024 + d] = hi;
}

// ---------------- mem_bank f32 -> [mh|mh|ml] bf16 row of 1536 ----------------
__global__ __launch_bounds__(256) void memdup_kernel(const float* __restrict__ mb,
                                                     u16* __restrict__ md) {
  int t = blockIdx.x * 256 + threadIdx.x;  // < 4194304
  int n = t >> 9, k = t & 511;
  float m = mb[t];
  u16 hi = f2bf(m);
  u16 lo = f2bf(m - bf2f(hi));
  long base = (long)n * 1536;
  md[base + k] = hi;
  md[base + 512 + k] = hi;
  md[base + 1024 + k] = lo;
}

// ---------------- NT MFMA GEMM: BK=64, xor-swizzled LDS, XCD-aware 1-D grid --------
// id&7 = XCD slot; each XCD owns M-tiles bmi ≡ xcd (mod 8) and runs that tile's
// nT N-blocks consecutively -> A tile stays in local L2 for its whole reuse window.
// Requires Mtiles % 8 == 0, grid.x = Mtiles*nT.
// EPI: 0 bias+bf16 | 1 bias+gelu+bf16 | 2 f32 atomicAdd | 3 f32 store
template <int EPI>
__global__ __launch_bounds__(256) void gemm_nt(const u16* __restrict__ Ag,
                                               const u16* __restrict__ Bt,
                                               const float* __restrict__ bias,
                                               void* __restrict__ C,
                                               int lda, int ldb, int K, int Nreal, int ldc,
                                               int nT) {
  __shared__ __align__(16) u16 As[128 * 64];
  __shared__ __align__(16) u16 Bs[128 * 64];
  const int tid = threadIdx.x;
  const int id = blockIdx.x;
  const int xcd = id & 7;
  const int kk = id >> 3;
  const long bm = (long)((kk / nT) * 8 + xcd) * 128;
  const long bnn = (long)(kk % nT) * 128;
  const long koff = (long)blockIdx.z * K;
  const int lane = tid & 63;
  const int w = tid >> 6;
  const int wm = (w & 1) * 64;
  const int wn = (w >> 1) * 64;
  const int r16 = lane & 15;
  const int q4 = lane >> 4;

  f32x4 acc[4][4] = {};

  const u16* ap[4];
  const u16* bp[4];
  u16* al[4];
  u16* bl[4];
#pragma unroll
  for (int j = 0; j < 4; ++j) {
    int cid = (j * 4 + w) * 64 + lane;
    int r = cid >> 3;
    int g = (cid & 7) ^ (r & 7);
    ap[j] = Ag + (bm + r) * lda + koff + g * 8;
    bp[j] = Bt + (bnn + r) * ldb + koff + g * 8;
    al[j] = As + cid * 8;
    bl[j] = Bs + cid * 8;
  }

  for (int k0 = 0; k0 < K; k0 += 64) {
#pragma unroll
    for (int j = 0; j < 4; ++j) gload_lds16(ap[j] + k0, al[j]);
#pragma unroll
    for (int j = 0; j < 4; ++j) gload_lds16(bp[j] + k0, bl[j]);
    __syncthreads();
#pragma unroll
    for (int sub = 0; sub < 2; ++sub) {
      const int gg = q4 + sub * 4;
      bf16x8 av[4], bv[4];
#pragma unroll
      for (int i = 0; i < 4; ++i) {
        int r = wm + i * 16 + r16;
        av[i] = *reinterpret_cast<const bf16x8*>(As + (r * 8 + (gg ^ (r & 7))) * 8);
      }
#pragma unroll
      for (int j2 = 0; j2 < 4; ++j2) {
        int r = wn + j2 * 16 + r16;
        bv[j2] = *reinterpret_cast<const bf16x8*>(Bs + (r * 8 + (gg ^ (r & 7))) * 8);
      }
#pragma unroll
      for (int i = 0; i < 4; ++i)
#pragma unroll
        for (int j2 = 0; j2 < 4; ++j2)
          acc[i][j2] = __builtin_amdgcn_mfma_f32_16x16x32_bf16(av[i], bv[j2], acc[i][j2], 0, 0, 0);
    }
    __syncthreads();
  }

#pragma unroll
  for (int i = 0; i < 4; ++i)
#pragma unroll
    for (int j = 0; j < 4; ++j)
#pragma unroll
      for (int r = 0; r < 4; ++r) {
        long grow = bm + wm + i * 16 + q4 * 4 + r;
        int gcol = (int)bnn + wn + j * 16 + r16;
        float v = acc[i][j][r];
        if (gcol < Nreal) {
          if (EPI == 0 || EPI == 1) {
            v += bias[gcol];
            if (EPI == 1) v = gelu_f(v);
            ((u16*)C)[grow * ldc + gcol] = f2bf(v);
          } else if (EPI == 2) {
            atomicAdd((float*)C + grow * ldc + gcol, v);
          } else {
            ((float*)C)[grow * ldc + gcol] = v;
          }
        }
      }
}

// ---------------- top-8 per row, parallel tree merge ----------------
DEV bool better(float v1, int i1, float v2, int i2) {
  return v1 > v2 || (v1 == v2 && i1 < i2);
}
__global__ __launch_bounds__(256) void topk_kernel(const float* __restrict__ sim,
                                                   int* __restrict__ idxout) {
  const int bn = blockIdx.x;
  const int tid = threadIdx.x;
  const float* row = sim + (long)bn * 8192;
  float bv[8]; int bi[8];
#pragma unroll
  for (int r = 0; r < 8; ++r) { bv[r] = -3.0e38f; bi[r] = 0x7fffffff; }
  for (int n = tid; n < 8192; n += 256) {
    float v = row[n];
    if (better(v, n, bv[7], bi[7])) {
      bv[7] = v; bi[7] = n;
      for (int r = 7; r > 0; --r) {
        if (!better(bv[r], bi[r], bv[r - 1], bi[r - 1])) break;
        float tv = bv[r]; bv[r] = bv[r - 1]; bv[r - 1] = tv;
        int ti = bi[r]; bi[r] = bi[r - 1]; bi[r - 1] = ti;
      }
    }
  }
  __shared__ float lv[256 * 8];
  __shared__ int li[256 * 8];
#pragma unroll
  for (int r = 0; r < 8; ++r) { lv[tid * 8 + r] = bv[r]; li[tid * 8 + r] = bi[r]; }
  __syncthreads();
  for (int step = 128; step >= 1; step >>= 1) {
    if (tid < step) {
      float av[8], xv[8]; int ai[8], xi[8];
#pragma unroll
      for (int r = 0; r < 8; ++r) {
        av[r] = lv[tid * 8 + r]; ai[r] = li[tid * 8 + r];
        xv[r] = lv[(tid + step) * 8 + r]; xi[r] = li[(tid + step) * 8 + r];
      }
      int ia = 0, ib = 0;
      float mv[8]; int mi[8];
#pragma unroll
      for (int r = 0; r < 8; ++r) {
        if (better(av[ia], ai[ia], xv[ib], xi[ib])) { mv[r] = av[ia]; mi[r] = ai[ia]; ++ia; }
        else { mv[r] = xv[ib]; mi[r] = xi[ib]; ++ib; }
      }
#pragma unroll
      for (int r = 0; r < 8; ++r) { lv[tid * 8 + r] = mv[r]; li[tid * 8 + r] = mi[r]; }
    }
    __syncthreads();
  }
  if (tid < 8) idxout[bn * 8 + tid] = li[tid];
}

// ---------------- gather retrieved rows, f32 -> bf16, clamped ----------------
__global__ __launch_bounds__(256) void gather_kernel(const float* __restrict__ mb,
                                                     const int* __restrict__ idx,
                                                     u16* __restrict__ retrB) {
  int t = blockIdx.x * 256 + threadIdx.x;  // < 524288
  int m = t >> 6;
  int c8 = (t & 63) * 8;
  long r = idx[m];
  if (r < 0) r = 0;
  if (r > 8191) r = 8191;
  const float* src = mb + r * 512 + c8;
  u16* dst = retrB + (long)m * 512 + c8;
#pragma unroll
  for (int z = 0; z < 8; ++z) dst[z] = f2bf(src[z]);
}

// ---------------- mean over K of gelu-hidden -> bf16 ----------------
__global__ __launch_bounds__(256) void gmean_kernel(const u16* __restrict__ hid,
                                                    u16* __restrict__ gmeanB) {
  int t = blockIdx.x * 256 + threadIdx.x;  // < 1048576
  int bn = t >> 10, j = t & 1023;
  float s = 0.f;
#pragma unroll
  for (int k = 0; k < 8; ++k) s += bf2f(hid[(long)(bn * 8 + k) * 1024 + j]);
  gmeanB[t] = f2bf(s * 0.125f);
}

// ---------------- MFMA attention over fused qkvb (stride 1536); O over Q cols ----
__global__ __launch_bounds__(256) void attn_kernel(u16* __restrict__ qkvb) {
  __shared__ __align__(16) u16 smem[26752];
  u16* Qs = smem;
  u16* Ks = smem + 8704;
  float* ss = (float*)(smem + 8704);   // overlay Ks
  u16* ps = smem;                      // overlay Qs
  u16* Vb = smem + 17408;
  float* red = (float*)(smem + 25728);
  const int bn = blockIdx.x, h = blockIdx.y;
  const int tid = threadIdx.x;
  const int lane = tid & 63, w = tid >> 6;
  const int r16 = lane & 15, q4 = lane >> 4;
  const long base = (long)bn * 64 * 1536 + h * 128;

  for (int c = tid; c < 1024; c += 256) {
    int r = c >> 4, c8 = (c & 15) * 8;
    u16x8 vq = *(const u16x8*)(qkvb + base + (long)r * 1536 + c8);
    u16x8 vk = *(const u16x8*)(qkvb + base + (long)r * 1536 + 512 + c8);
    u16x8 vv = *(const u16x8*)(qkvb + base + (long)r * 1536 + 1024 + c8);
    *(u16x8*)(Qs + r * 136 + c8) = vq;
    *(u16x8*)(Ks + r * 136 + c8) = vk;
    int kt = r >> 5, q4t = (r >> 3) & 3, e = r & 7;
    int nt = c8 >> 4, rb = c8 & 15;
    int vbase = (nt * 2 + kt) * 520 + (q4t * 16 + rb) * 8 + e;
#pragma unroll
    for (int z = 0; z < 8; ++z) Vb[vbase + z * 8] = vv[z];
  }
  __syncthreads();

  const int m0 = w * 16;
  f32x4 accS[4] = {};
#pragma unroll
  for (int k0 = 0; k0 < 128; k0 += 32) {
    bf16x8 av = *(const bf16x8*)(Qs + (m0 + r16) * 136 + k0 + q4 * 8);
#pragma unroll
    for (int j = 0; j < 4; ++j) {
      bf16x8 bvf = *(const bf16x8*)(Ks + (j * 16 + r16) * 136 + k0 + q4 * 8);
      accS[j] = __builtin_amdgcn_mfma_f32_16x16x32_bf16(av, bvf, accS[j], 0, 0, 0);
    }
  }
  __syncthreads();
  const float scale = 0.08838834764831845f;  // 1/sqrt(128)
#pragma unroll
  for (int j = 0; j < 4; ++j)
#pragma unroll
    for (int r = 0; r < 4; ++r)
      ss[(m0 + q4 * 4 + r) * 66 + j * 16 + r16] = accS[j][r] * scale;
  __syncthreads();

  {
    int r = tid >> 2, p = tid & 3;
    float* row = ss + r * 66 + p * 16;
    float mx = -3.0e38f;
#pragma unroll
    for (int c2 = 0; c2 < 16; ++c2) mx = fmaxf(mx, row[c2]);
    red[r * 4 + p] = mx;
    __syncthreads();
    float m4 = fmaxf(fmaxf(red[r * 4], red[r * 4 + 1]),
                     fmaxf(red[r * 4 + 2], red[r * 4 + 3]));
    float s = 0.f;
#pragma unroll
    for (int c2 = 0; c2 < 16; ++c2) {
      float e = expf(row[c2] - m4);
      row[c2] = e;
      s += e;
    }
    red[256 + r * 4 + p] = s;
    __syncthreads();
    float inv = 1.f / (red[256 + r * 4] + red[256 + r * 4 + 1] +
                       red[256 + r * 4 + 2] + red[256 + r * 4 + 3]);
    u16x8 o0, o1;
#pragma unroll
    for (int z = 0; z < 8; ++z) {
      o0[z] = f2bf(row[z] * inv);
      o1[z] = f2bf(row[8 + z] * inv);
    }
    *(u16x8*)(ps + r * 72 + p * 16) = o0;
    *(u16x8*)(ps + r * 72 + p * 16 + 8) = o1;
  }
  __syncthreads();

  bf16x8 av0 = *(const bf16x8*)(ps + (m0 + r16) * 72 + q4 * 8);
  bf16x8 av1 = *(const bf16x8*)(ps + (m0 + r16) * 72 + 32 + q4 * 8);
#pragma unroll
  for (int nt = 0; nt < 8; ++nt) {
    f32x4 accO = {};
    bf16x8 bv0 = *(const bf16x8*)(Vb + (nt * 2 + 0) * 520 + lane * 8);
    bf16x8 bv1 = *(const bf16x8*)(Vb + (nt * 2 + 1) * 520 + lane * 8);
    accO = __builtin_amdgcn_mfma_f32_16x16x32_bf16(av0, bv0, accO, 0, 0, 0);
    accO = __builtin_amdgcn_mfma_f32_16x16x32_bf16(av1, bv1, accO, 0, 0, 0);
    int d = nt * 16 + r16;
#pragma unroll
    for (int r = 0; r < 4; ++r) {
      int i = m0 + q4 * 4 + r;
      qkvb[base + (long)i * 1536 + d] = f2bf(accO[r]);  // O over dead Q cols
    }
  }
}

// ---------------- local = emb + hmean (in-place over embh) ----------------
__global__ __launch_bounds__(256) void local_kernel(u16* __restrict__ embh,
                                                    const u16* __restrict__ hmeanB) {
  long t = (long)blockIdx.x * 256 + threadIdx.x;  // < 33554432
  long m = t >> 9;
  int d = (int)(t & 511);
  int bn = (int)(m >> 6);
  embh[t] = f2bf(bf2f(hmeanB[(long)bn * 512 + d]) + bf2f(embh[t]));
}

// ---------------- concat-K NT GEMM (BK=64, swizzled LDS, XCD-aware grid) ----------
__global__ __launch_bounds__(256) void gemm_cat(const u16* __restrict__ A1,
                                                const u16* __restrict__ A2,
                                                const u16* __restrict__ Bt,
                                                const float* __restrict__ bias,
                                                u16* __restrict__ C,
                                                int lda1, int lda2, int ldc, int nT) {
  __shared__ __align__(16) u16 As[128 * 64];
  __shared__ __align__(16) u16 Bs[128 * 64];
  const int tid = threadIdx.x;
  const int id = blockIdx.x;
  const int xcd = id & 7;
  const int kk = id >> 3;
  const long bm = (long)((kk / nT) * 8 + xcd) * 128;
  const long bnn = (long)(kk % nT) * 128;
  const int lane = tid & 63;
  const int w = tid >> 6;
  const int wm = (w & 1) * 64;
  const int wn = (w >> 1) * 64;
  const int r16 = lane & 15;
  const int q4 = lane >> 4;

  f32x4 acc[4][4] = {};

  const u16* ap1[4];
  const u16* ap2[4];
  const u16* bp[4];
  u16* al[4];
  u16* bl[4];
#pragma unroll
  for (int j = 0; j < 4; ++j) {
    int cid = (j * 4 + w) * 64 + lane;
    int r = cid >> 3;
    int g = (cid & 7) ^ (r & 7);
    ap1[j] = A1 + (bm + r) * lda1 + g * 8;
    ap2[j] = A2 + (bm + r) * lda2 + g * 8;
    bp[j] = Bt + (bnn + r) * 1024 + g * 8;
    al[j] = As + cid * 8;
    bl[j] = Bs + cid * 8;
  }

  for (int k0 = 0; k0 < 1024; k0 += 64) {
    if (k0 < 512) {
#pragma unroll
      for (int j = 0; j < 4; ++j) gload_lds16(ap1[j] + k0, al[j]);
    } else {
#pragma unroll
      for (int j = 0; j < 4; ++j) gload_lds16(ap2[j] + (k0 - 512), al[j]);
    }
#pragma unroll
    for (int j = 0; j < 4; ++j) gload_lds16(bp[j] + k0, bl[j]);
    __syncthreads();
#pragma unroll
    for (int sub = 0; sub < 2; ++sub) {
      const int gg = q4 + sub * 4;
      bf16x8 av[4], bv[4];
#pragma unroll
      for (int i = 0; i < 4; ++i) {
        int r = wm + i * 16 + r16;
        av[i] = *reinterpret_cast<const bf16x8*>(As + (r * 8 + (gg ^ (r & 7))) * 8);
      }
#pragma unroll
      for (int j2 = 0; j2 < 4; ++j2) {
        int r = wn + j2 * 16 + r16;
        bv[j2] = *reinterpret_cast<const bf16x8*>(Bs + (r * 8 + (gg ^ (r & 7))) * 8);
      }
#pragma unroll
      for (int i = 0; i < 4; ++i)
#pragma unroll
        for (int j2 = 0; j2 < 4; ++j2)
          acc[i][j2] = __builtin_amdgcn_mfma_f32_16x16x32_bf16(av[i], bv[j2], acc[i][j2], 0, 0, 0);
    }
    __syncthreads();
  }

#pragma unroll
  for (int i = 0; i < 4; ++i)
#pragma unroll
    for (int j = 0; j < 4; ++j)
#pragma unroll
      for (int r = 0; r < 4; ++r) {
        long grow = bm + wm + i * 16 + q4 * 4 + r;
        int gcol = (int)bnn + wn + j * 16 + r16;
        float v = acc[i][j][r] + bias[gcol];
        C[grow * ldc + gcol] = f2bf(gelu_f(v));
      }
}

// ---------------- gate logits + softmax(2); h1 at stride ld ----------------
__global__ __launch_bounds__(256) void g2_kernel(const u16* __restrict__ h1b,
                                                 const float* __restrict__ W_g2,
                                                 const float* __restrict__ b_g2,
                                                 float* __restrict__ gatel, int ld) {
  int m = blockIdx.x * 4 + (threadIdx.x >> 6);
  int lane = threadIdx.x & 63;
  const u16* row = h1b + (long)m * ld;
  float a0 = 0.f, a1 = 0.f;
  for (int i = lane; i < 512; i += 64) {
    float h = bf2f(row[i]);
    a0 += h * W_g2[i * 2];
    a1 += h * W_g2[i * 2 + 1];
  }
  for (int off = 32; off; off >>= 1) {
    a0 += __shfl_down(a0, off);
    a1 += __shfl_down(a1, off);
  }
  if (lane == 0) {
    a0 += b_g2[0];
    a1 += b_g2[1];
    float mx = fmaxf(a0, a1);
    float e0 = expf(a0 - mx), e1 = expf(a1 - mx);
    float inv = 1.f / (e0 + e1);
    gatel[(long)m * 2] = e0 * inv;
    gatel[(long)m * 2 + 1] = e1 * inv;
  }
}

// ---------------- mem = g0*local + g1*glob (in place over embh) ----------------
__global__ __launch_bounds__(256) void memc_kernel(u16* __restrict__ embh,
                                                   const u16* __restrict__ qkvb,
                                                   const float* __restrict__ gatel) {
  long t = (long)blockIdx.x * 256 + threadIdx.x;  // < 33554432
  long m = t >> 9;
  int d = (int)(t & 511);
  float loc = bf2f(embh[t]);
  float gl = bf2f(qkvb[m * 1536 + 512 + d]);
  float g0 = gatel[m * 2], g1 = gatel[m * 2 + 1];
  embh[t] = f2bf(g0 * loc + g1 * gl);
}

// ---------------- fusion head + denorm + transpose store (f32) ----------------
__global__ __launch_bounds__(256) void fusion_kernel(const float* __restrict__ mh,
                                                     const float* __restrict__ b_h,
                                                     const float* __restrict__ W_f1,
                                                     const float* __restrict__ b_f1,
                                                     const float* __restrict__ W_f2,
                                                     const float* __restrict__ b_f2,
                                                     const float* __restrict__ meanv,
                                                     const float* __restrict__ stdv,
                                                     float* __restrict__ out) {
  int bn = blockIdx.x;
  int tid = threadIdx.x;
  __shared__ float mrow[192];
  __shared__ float h1[384];
  if (tid < 192) mrow[tid] = mh[(long)bn * 192 + tid] + b_h[tid];
  __syncthreads();
  for (int j = tid; j < 384; j += 256) {
    float a = b_f1[j];
    for (int i = 0; i < 192; ++i) a += mrow[i] * W_f1[i * 384 + j];
    h1[j] = gelu_f(a);
  }
  __syncthreads();
  if (tid < 192) {
    float a = b_f2[tid];
    for (int j = 0; j < 384; ++j) a += h1[j] * W_f2[j * 192 + tid];
    float o = gelu_f(a) + mrow[tid];
    int b = bn >> 6, v = bn & 63;
    out[((long)b * 192 + tid) * 64 + v] = o * stdv[bn] + meanv[bn];
  }
}

extern "C" void kernel_launch(void* const* d_in, const int* in_sizes, int n_in,
                              void* d_out, int out_size, void* d_ws, size_t ws_size,
                              hipStream_t stream) {
  (void)in_sizes; (void)n_in; (void)out_size; (void)d_ws; (void)ws_size;
  const float* x_enc = (const float*)d_in[0];
  const float* W_val = (const float*)d_in[1];
  const float* mem_bank = (const float*)d_in[2];
  const float* W_m1 = (const float*)d_in[3];
  const float* b_m1 = (const float*)d_in[4];
  const float* W_m2 = (const float*)d_in[5];
  const float* b_m2 = (const float*)d_in[6];
  const float* W_q = (const float*)d_in[7];
  const float* b_q = (const float*)d_in[8];
  const float* W_k = (const float*)d_in[9];
  const float* b_k = (const float*)d_in[10];
  const float* W_v = (const float*)d_in[11];
  const float* b_v = (const float*)d_in[12];
  const float* W_o = (const float*)d_in[13];
  const float* b_o = (const float*)d_in[14];
  const float* W_g1 = (const float*)d_in[15];
  const float* b_g1 = (const float*)d_in[16];
  const float* W_g2 = (const float*)d_in[17];
  const float* b_g2 = (const float*)d_in[18];
  const float* W_h = (const float*)d_in[19];
  const float* b_h = (const float*)d_in[20];
  const float* W_f1 = (const float*)d_in[21];
  const float* b_f1 = (const float*)d_in[22];
  const float* W_f2 = (const float*)d_in[23];
  const float* b_f2 = (const float*)d_in[24];

  void* sp = nullptr;
  hipGetSymbolAddress(&sp, HIP_SYMBOL(g_s));
  Scratch* S = (Scratch*)sp;
  // sim-phase aliases inside qkvb (all dead before fused QKV writes it)
  float* simB = (float*)S->qkvb;                            // 32 MB
  u16* qsC = S->qkvb + (size_t)16 * 1024 * 1024;            // 3 MB
  u16* retrB = S->qkvb + (size_t)18 * 1024 * 1024;          // 8 MB
  u16* hiddenB = S->qkvb + (size_t)24 * 1024 * 1024;        // 16 MB

  // setup
  pos_kernel<<<64, 256, 0, stream>>>(S->POSb);
  stats_kernel<<<16, 256, 0, stream>>>(x_enc, S->meanv, S->stdv);
  zerof_kernel<<<768, 256, 0, stream>>>(S->mh, 1024 * 192);
  zerou_kernel<<<8192, 256, 0, stream>>>(S->WhT + (size_t)192 * 32768, 64 * 32768);
  biasqkv_kernel<<<6, 256, 0, stream>>>(b_q, b_k, b_v, S->bqkv);
  transpose_kernel<<<dim3(16, 16), 256, 0, stream>>>(W_q, S->WqkvT, 512, 512);
  transpose_kernel<<<dim3(16, 16), 256, 0, stream>>>(W_k, S->WqkvT + 512 * 512, 512, 512);
  transpose_kernel<<<dim3(16, 16), 256, 0, stream>>>(W_v, S->WqkvT + 2 * 512 * 512, 512, 512);
  transpose_kernel<<<dim3(16, 16), 256, 0, stream>>>(W_o, S->WoT, 512, 512);
  transpose_kernel<<<dim3(32, 16), 256, 0, stream>>>(W_m1, S->Wm1T, 512, 1024);
  transpose_kernel<<<dim3(16, 32), 256, 0, stream>>>(W_m2, S->Wm2T, 1024, 512);
  transpose_kernel<<<dim3(16, 32), 256, 0, stream>>>(W_g1, S->Wg1T, 1024, 512);
  transpose_kernel<<<dim3(6, 1024), 256, 0, stream>>>(W_h, S->WhT, 32768, 192);
  memdup_kernel<<<16384, 256, 0, stream>>>(mem_bank, S->memdupB);

  // embedding
  emb_kernel<<<1024, 256, 0, stream>>>(x_enc, W_val, S->POSb, S->meanv, S->stdv,
                                       S->embh, S->qflat);
  // retrieval (sim: Mtiles=8, nT=64 -> grid 512)
  qsplit_kernel<<<2048, 256, 0, stream>>>(S->qflat, qsC);
  gemm_nt<3><<<512, 256, 0, stream>>>(qsC, S->memdupB, nullptr, simB,
                                      1536, 1536, 1536, 8192, 8192, 64);
  topk_kernel<<<1024, 256, 0, stream>>>(simB, S->idxB);
  gather_kernel<<<2048, 256, 0, stream>>>(mem_bank, S->idxB, retrB);
  // Wm1: Mtiles=64, nT=8 -> grid 512
  gemm_nt<1><<<512, 256, 0, stream>>>(retrB, S->Wm1T, b_m1, hiddenB,
                                      512, 512, 512, 1024, 1024, 8);
  gmean_kernel<<<4096, 256, 0, stream>>>(hiddenB, S->gmeanB);
  // hmean: Mtiles=8, nT=4 -> grid 32
  gemm_nt<0><<<32, 256, 0, stream>>>(S->gmeanB, S->Wm2T, b_m2, S->hmeanB,
                                     1024, 1024, 1024, 512, 512, 4);
  // fused QKV: Mtiles=512, nT=12 -> grid 6144
  gemm_nt<0><<<6144, 256, 0, stream>>>(S->embh, S->WqkvT, S->bqkv, S->qkvb,
                                       512, 512, 512, 1536, 1536, 12);
  // local = emb + hmean (in place; QKV consumed emb)
  local_kernel<<<131072, 256, 0, stream>>>(S->embh, S->hmeanB);
  // attention (O over Q cols of qkvb)
  attn_kernel<<<dim3(1024, 4), 256, 0, stream>>>(S->qkvb);
  // glob = O @ W_o + b_o -> K cols of qkvb (Mtiles=512, nT=4 -> grid 2048)
  gemm_nt<0><<<2048, 256, 0, stream>>>(S->qkvb, S->WoT, b_o, S->qkvb + 512,
                                       1536, 512, 512, 512, 1536, 4);
  // h1 = gelu([local|glob] @ W_g1 + b_g1) -> V cols of qkvb
  gemm_cat<<<2048, 256, 0, stream>>>(S->embh, S->qkvb + 512, S->Wg1T, b_g1,
                                     S->qkvb + 1024, 512, 1536, 1536, 4);
  g2_kernel<<<16384, 256, 0, stream>>>(S->qkvb + 1024, W_g2, b_g2, S->gatel, 1536);
  // mem = g0*local + g1*glob (in place over embh)
  memc_kernel<<<131072, 256, 0, stream>>>(S->embh, S->qkvb, S->gatel);
  // mh = mem_flat [1024,32768] @ WhT^T (Mtiles=8, nT=2 -> grid x 16, z 16 split-K)
  gemm_nt<2><<<dim3(16, 1, 16), 256, 0, stream>>>(S->embh, S->WhT, nullptr, S->mh,
                                                  32768, 32768, 2048, 192, 192, 2);
  fusion_kernel<<<1024, 256, 0, stream>>>(S->mh, b_h, W_f1, b_f1, W_f2, b_f2,
                                          S->meanv, S->stdv, (float*)d_out);
}